// Round 2
// baseline (1555.388 us; speedup 1.0000x reference)
//
#include <hip/hip_runtime.h>
#include <hip/hip_bf16.h>
#include <cmath>

using bf16 = __hip_bfloat16;
typedef __attribute__((ext_vector_type(8))) short short8;
typedef __attribute__((ext_vector_type(4))) float floatx4;

__device__ __forceinline__ float bu2f(ushort u) { return __uint_as_float((unsigned)u << 16); }
__device__ __forceinline__ ushort f2bu(float f) {
  union { bf16 b; ushort u; } cv; cv.b = __float2bfloat16(f); return cv.u;
}
__device__ __forceinline__ void gl_lds16(const ushort* g, ushort* l) {
  __builtin_amdgcn_global_load_lds((const __attribute__((address_space(1))) unsigned*)g,
                                   (__attribute__((address_space(3))) unsigned*)l, 16, 0, 0);
}
// tanh-form GELU via hw exp; |err vs erf-GELU| ~2e-4, below bf16 output quantization
__device__ __forceinline__ float fast_gelu(float x) {
  float z = 0.7978845608028654f * (x + 0.044715f * x * x * x);
  z = fmaxf(fminf(z, 10.f), -10.f);
  float e = __expf(2.f * z);
  float t = (e - 1.f) / (e + 1.f);
  return 0.5f * x * (1.f + t);
}

static constexpr int kT   = 4096;
static constexpr int kDim = 1024;
static constexpr float kScale   = 0.08838834764831845f;  // 1/sqrt(128)
static constexpr float kSelfVal = -5.0e4f;

// ---------------- dtype detector: bf16 vs fp32 inputs ----------------
__device__ __forceinline__ int sane_v(float f) { float a = fabsf(f); return (a > 1e-4f && a < 1e4f) ? 1 : 0; }

__global__ __launch_bounds__(256) void k_detect(const unsigned* __restrict__ x, int* __restrict__ flag) {
  __shared__ int cnt;
  int tid = threadIdx.x;
  if (tid == 0) cnt = 0;
  __syncthreads();
  int my = 0;
  const uint4* p = (const uint4*)x;
  for (int q = 0; q < 16; q++) {
    uint4 u = p[tid * 16 + q];
    my += sane_v(__uint_as_float(u.x << 16)) + sane_v(__uint_as_float(u.x & 0xffff0000u));
    my += sane_v(__uint_as_float(u.y << 16)) + sane_v(__uint_as_float(u.y & 0xffff0000u));
    my += sane_v(__uint_as_float(u.z << 16)) + sane_v(__uint_as_float(u.z & 0xffff0000u));
    my += sane_v(__uint_as_float(u.w << 16)) + sane_v(__uint_as_float(u.w & 0xffff0000u));
  }
  atomicAdd(&cnt, my);
  __syncthreads();
  if (tid == 0) flag[0] = (cnt >= 24576) ? 1 : 0;
}

__global__ __launch_bounds__(256) void k_cvt(const int* __restrict__ flag, const void* __restrict__ src,
                                             ushort* __restrict__ dst, int n) {
  int i = blockIdx.x * 256 + threadIdx.x;
  if (i >= n) return;
  dst[i] = (*flag) ? ((const ushort*)src)[i] : f2bu(((const float*)src)[i]);
}

__global__ __launch_bounds__(256) void k_init_any(const int* __restrict__ flag, const void* __restrict__ x,
                                                  float* __restrict__ x1, float* __restrict__ x2) {
  int i = blockIdx.x * 1024 + threadIdx.x * 4;
  float4 f;
  if (*flag) {
    ushort4 u = *(const ushort4*)((const ushort*)x + i);
    f.x = bu2f(u.x); f.y = bu2f(u.y); f.z = bu2f(u.z); f.w = bu2f(u.w);
  } else {
    f = *(const float4*)((const float*)x + i);
  }
  *(float4*)(x1 + i) = f;
  *(float4*)(x2 + i) = f;
}

__global__ __launch_bounds__(256) void k_final_any(const int* __restrict__ flag, const float* __restrict__ x1,
                                                   const float* __restrict__ x2, void* __restrict__ out) {
  int i = blockIdx.x * 1024 + threadIdx.x * 4;
  float4 a = *(const float4*)(x1 + i);
  float4 b = *(const float4*)(x2 + i);
  float4 s; s.x = a.x + b.x; s.y = a.y + b.y; s.z = a.z + b.z; s.w = a.w + b.w;
  if (*flag) {
    ushort4 u; u.x = f2bu(s.x); u.y = f2bu(s.y); u.z = f2bu(s.z); u.w = f2bu(s.w);
    *(ushort4*)((ushort*)out + i) = u;
  } else {
    *(float4*)((float*)out + i) = s;
  }
}

// ---------------- layernorm: fp32 in -> bf16 out ----------------
__global__ __launch_bounds__(256) void k_ln(const float* __restrict__ x, const ushort* __restrict__ g,
                                            const ushort* __restrict__ be, ushort* __restrict__ out) {
  __shared__ float ws[4], ws2[4];
  int row = blockIdx.x, tid = threadIdx.x;
  const float* xr = x + (size_t)row * kDim + tid * 4;
  float4 v = *(const float4*)xr;
  float s  = v.x + v.y + v.z + v.w;
  float s2 = v.x*v.x + v.y*v.y + v.z*v.z + v.w*v.w;
  #pragma unroll
  for (int off = 32; off; off >>= 1) { s += __shfl_down(s, off); s2 += __shfl_down(s2, off); }
  int wave = tid >> 6, lane = tid & 63;
  if (lane == 0) { ws[wave] = s; ws2[wave] = s2; }
  __syncthreads();
  s  = ws[0] + ws[1] + ws[2] + ws[3];
  s2 = ws2[0] + ws2[1] + ws2[2] + ws2[3];
  float mean = s * (1.f/1024.f);
  float var  = fmaxf(s2 * (1.f/1024.f) - mean*mean, 0.f);
  float rstd = rsqrtf(var + 1e-5f);
  int cb = tid * 4;
  ushort* o = out + (size_t)row * kDim + cb;
  o[0] = f2bu((v.x - mean) * rstd * bu2f(g[cb+0]) + bu2f(be[cb+0]));
  o[1] = f2bu((v.y - mean) * rstd * bu2f(g[cb+1]) + bu2f(be[cb+1]));
  o[2] = f2bu((v.z - mean) * rstd * bu2f(g[cb+2]) + bu2f(be[cb+2]));
  o[3] = f2bu((v.w - mean) * rstd * bu2f(g[cb+3]) + bu2f(be[cb+3]));
}

// ---------------- dual-dtype weight transpose: in[K,N] -> out[N,K] ----------------
__global__ __launch_bounds__(256) void k_transpose2(const int* __restrict__ flag, const void* __restrict__ src_bf,
                                                    const void* __restrict__ src_f, ushort* __restrict__ out,
                                                    int K, int N) {
  __shared__ ushort tile[32][33];
  int isbf = *flag;
  int nb = blockIdx.x * 32, kb = blockIdx.y * 32;
  int tx = threadIdx.x & 31, ty = threadIdx.x >> 5;
  for (int r = ty; r < 32; r += 8) {
    size_t idx = (size_t)(kb + r) * N + nb + tx;
    tile[r][tx] = isbf ? ((const ushort*)src_bf)[idx] : f2bu(((const float*)src_f)[idx]);
  }
  __syncthreads();
  for (int r = ty; r < 32; r += 8) out[(size_t)(nb + r) * K + kb + tx] = tile[tx][r];
}

// ---------------- rot transpose: rot[k=128][n=128] -> rotT[n=128][k=128] ----------------
__global__ __launch_bounds__(256) void k_rot_t(const ushort* __restrict__ rot, ushort* __restrict__ rotT) {
  int tid = threadIdx.x;
  for (int idx = tid; idx < 16384; idx += 256) {
    int n = idx >> 7, k = idx & 127;
    rotT[idx] = rot[k * 128 + n];
  }
}

// ---------------- pipelined GEMM (T1+T2+T3+T4+T5) ----------------
// BN=256, BK=32, 512 threads = 8 waves (2M x 4N). MW = M-fragments per wave:
//   MW=8 -> BM=256 (wave tile 128x64), MW=4 -> BM=128 (wave tile 64x64).
// 4 LDS buffers, prefetch distance 3 K-tiles, counted vmcnt (never 0 in steady state),
// raw s_barrier (no __syncthreads -> no forced vmcnt(0) drain).
// Staging via global_load_lds with SOURCE-side chunk swizzle cs = c ^ ((row>>1)&3):
//   read-side slot g^((row>>1)&3) recovers global k-chunk g; collective wave read is a
//   dense contiguous 1 KB region -> conflict-free.
// Race safety per phase t: stage(t+3) targets buf[(t-1)&3], whose reads completed
// before phase t-1's trailing barrier; issued after it in program order.
// sched_barrier(0) pins keep the ds_read+MFMA cluster (and its lgkmcnt waits)
// strictly between the two barriers (guide rule #18: register-only MFMAs may
// otherwise be scheduled across asm memory fences / s_barrier).
// mode 1: Cf += A@B + bias   mode 2: Cb = bf16(gelu(A@B+bias))
// mode 3: Cb = bf16(A@B)     mode 5: Cb = hi(A@B), Cb2 = lo(A@B)
template <int MW>
__global__ __launch_bounds__(512, 2) void k_gemm2(const ushort* __restrict__ A, const ushort* __restrict__ Bt,
                                                  const ushort* __restrict__ bias, float* __restrict__ Cf,
                                                  ushort* __restrict__ Cb, ushort* __restrict__ Cb2,
                                                  int M, int N, int K, int mode) {
  constexpr int BM  = MW * 32;   // 256 or 128
  constexpr int LA  = MW / 4;    // A-loads per thread per K-tile: 2 or 1
  __shared__ alignas(16) ushort SA[4][BM * 32];
  __shared__ alignas(16) ushort SB[4][256 * 32];

  const int tid  = threadIdx.x;
  const int lane = tid & 63, wave = tid >> 6;
  const int lr = lane & 15, g = lane >> 4;       // g = k-chunk index 0..3
  const int wm = wave >> 2, wn = wave & 3;

  // XCD-aware bijective block swizzle (all grids here have nwg % 8 == 0)
  const int nbx = gridDim.x;
  const int nwg = nbx * gridDim.y;
  const int bid = blockIdx.y * nbx + blockIdx.x;
  const int swz = (bid & 7) * (nwg >> 3) + (bid >> 3);
  const int m0 = (swz / nbx) * BM;
  const int n0 = (swz % nbx) * 256;

  const int NT = K >> 5;

  // per-thread staging sources (global col-chunk pre-swizzled, LDS dest linear)
  const ushort* srcA[LA];
  #pragma unroll
  for (int j = 0; j < LA; j++) {
    int chunk = wave * (64 * LA) + j * 64 + lane;
    int row = chunk >> 2, c = chunk & 3;
    int cs = c ^ ((row >> 1) & 3);
    srcA[j] = A + (size_t)(m0 + row) * K + cs * 8;
  }
  const ushort* srcB[2];
  #pragma unroll
  for (int j = 0; j < 2; j++) {
    int chunk = wave * 128 + j * 64 + lane;
    int row = chunk >> 2, c = chunk & 3;
    int cs = c ^ ((row >> 1) & 3);
    srcB[j] = Bt + (size_t)(n0 + row) * K + cs * 8;
  }

  // fragment read offsets (loop-invariant; ushort units)
  int offA[MW], offB[4];
  #pragma unroll
  for (int mi = 0; mi < MW; mi++) {
    int row = wm * (MW * 16) + mi * 16 + lr;
    offA[mi] = row * 32 + ((g ^ ((row >> 1) & 3)) * 8);
  }
  #pragma unroll
  for (int ni = 0; ni < 4; ni++) {
    int row = wn * 64 + ni * 16 + lr;
    offB[ni] = row * 32 + ((g ^ ((row >> 1) & 3)) * 8);
  }

  floatx4 acc[MW][4];
  #pragma unroll
  for (int mi = 0; mi < MW; mi++)
    #pragma unroll
    for (int ni = 0; ni < 4; ni++) acc[mi][ni] = (floatx4){0.f, 0.f, 0.f, 0.f};

  // prologue: stage K-tiles 0,1,2 (NT >= 32 always here)
  #pragma unroll
  for (int p = 0; p < 3; p++) {
    #pragma unroll
    for (int j = 0; j < LA; j++) gl_lds16(srcA[j] + p * 32, &SA[p][(wave * (64 * LA) + j * 64) * 8]);
    #pragma unroll
    for (int j = 0; j < 2; j++)  gl_lds16(srcB[j] + p * 32, &SB[p][(wave * 128 + j * 64) * 8]);
  }

  for (int t = 0; t < NT; t++) {
    asm volatile("" ::: "memory");                 // fence A: keep stage below prior barrier
    if (t + 3 < NT) {
      const int kp = (t + 3) * 32, pb = (t + 3) & 3;
      #pragma unroll
      for (int j = 0; j < LA; j++) gl_lds16(srcA[j] + kp, &SA[pb][(wave * (64 * LA) + j * 64) * 8]);
      #pragma unroll
      for (int j = 0; j < 2; j++)  gl_lds16(srcB[j] + kp, &SB[pb][(wave * 128 + j * 64) * 8]);
      // counted wait: tiles t+1..t+3 may stay in flight; guarantees tile t landed
      if constexpr (MW == 8) asm volatile("s_waitcnt vmcnt(12)" ::: "memory");
      else                   asm volatile("s_waitcnt vmcnt(9)"  ::: "memory");
    } else {
      asm volatile("s_waitcnt vmcnt(0)" ::: "memory");   // 3-tile tail only
    }
    __builtin_amdgcn_s_barrier();
    __builtin_amdgcn_sched_barrier(0);             // pin: nothing from below crosses up

    const ushort* sa = SA[t & 3];
    const ushort* sb = SB[t & 3];
    short8 a[MW], b[4];
    #pragma unroll
    for (int mi = 0; mi < MW; mi++) a[mi] = *(const short8*)&sa[offA[mi]];
    #pragma unroll
    for (int ni = 0; ni < 4; ni++)  b[ni] = *(const short8*)&sb[offB[ni]];
    __builtin_amdgcn_s_setprio(1);
    #pragma unroll
    for (int mi = 0; mi < MW; mi++)
      #pragma unroll
      for (int ni = 0; ni < 4; ni++)
        acc[mi][ni] = __builtin_amdgcn_mfma_f32_16x16x32_bf16(a[mi], b[ni], acc[mi][ni], 0, 0, 0);
    __builtin_amdgcn_s_setprio(0);

    __builtin_amdgcn_sched_barrier(0);             // pin: MFMAs + lgkm waits stay above
    __builtin_amdgcn_s_barrier();
  }

  #pragma unroll
  for (int mi = 0; mi < MW; mi++) {
    #pragma unroll
    for (int ni = 0; ni < 4; ni++) {
      int col = n0 + wn * 64 + ni * 16 + lr;
      float bv = (mode == 1 || mode == 2) ? bu2f(bias[col]) : 0.f;
      #pragma unroll
      for (int q = 0; q < 4; q++) {
        int r2 = m0 + wm * (MW * 16) + mi * 16 + (lane >> 4) * 4 + q;
        float val = acc[mi][ni][q];
        if (mode == 1) {
          Cf[(size_t)r2 * N + col] += val + bv;
        } else if (mode == 2) {
          Cb[(size_t)r2 * N + col] = f2bu(fast_gelu(val + bv));
        } else if (mode == 3) {
          Cb[(size_t)r2 * N + col] = f2bu(val);
        } else {
          ushort h = f2bu(val);
          Cb [(size_t)r2 * N + col] = h;
          Cb2[(size_t)r2 * N + col] = f2bu(val - bu2f(h));
        }
      }
    }
  }
  (void)M;
}

// ---------------- MFMA bucket: consumes qk hi/lo bf16 planes; in-register first-max argmax ----------------
__global__ __launch_bounds__(256) void k_bucket_mfma(const ushort* __restrict__ qkh, const ushort* __restrict__ qkl,
                                                     const ushort* __restrict__ rotT, int* __restrict__ bkt) {
  __shared__ alignas(16) ushort Bs[128*128];  // rotT [n][k]  32 KB
  __shared__ alignas(16) ushort Ah[64*128];   // Q hi         16 KB
  __shared__ alignas(16) ushort Al[64*128];   // Q lo         16 KB
  const int tid = threadIdx.x;
  const int lane = tid & 63, wave = tid >> 6;
  const int lr = lane & 15, lk = (lane >> 4) * 8;
  const int tt = blockIdx.x * 64;
  const int bh = blockIdx.y;
  const int b = bh >> 3, hh = bh & 7;

  {
    int r = tid >> 2, c0 = (tid & 3) * 32;
    size_t base = ((size_t)(b * kT + tt + r)) * kDim + hh * 128 + c0;
    const uint4* sh = (const uint4*)(qkh + base);
    const uint4* sl = (const uint4*)(qkl + base);
    uint4* dh = (uint4*)&Ah[r * 128 + c0];
    uint4* dl = (uint4*)&Al[r * 128 + c0];
    #pragma unroll
    for (int i = 0; i < 4; i++) { dh[i] = sh[i]; dl[i] = sl[i]; }
  }
  {
    const uint4* src = (const uint4*)rotT;
    uint4* dst = (uint4*)Bs;
    for (int i = tid; i < 2048; i += 256) dst[i] = src[i];
  }
  __syncthreads();

  floatx4 acc[4][2];
  #pragma unroll
  for (int mi = 0; mi < 4; mi++) { acc[mi][0] = (floatx4){0,0,0,0}; acc[mi][1] = (floatx4){0,0,0,0}; }
  #pragma unroll
  for (int ks = 0; ks < 4; ks++) {
    short8 a[4], bb[2];
    #pragma unroll
    for (int ni = 0; ni < 2; ni++) bb[ni] = *(const short8*)&Bs[(wave*32 + ni*16 + lr)*128 + ks*32 + lk];
    #pragma unroll
    for (int mi = 0; mi < 4; mi++) a[mi] = *(const short8*)&Ah[(mi*16 + lr)*128 + ks*32 + lk];
    #pragma unroll
    for (int mi = 0; mi < 4; mi++)
      #pragma unroll
      for (int ni = 0; ni < 2; ni++)
        acc[mi][ni] = __builtin_amdgcn_mfma_f32_16x16x32_bf16(a[mi], bb[ni], acc[mi][ni], 0, 0, 0);
  }
  #pragma unroll
  for (int ks = 0; ks < 4; ks++) {
    short8 a[4], bb[2];
    #pragma unroll
    for (int ni = 0; ni < 2; ni++) bb[ni] = *(const short8*)&Bs[(wave*32 + ni*16 + lr)*128 + ks*32 + lk];
    #pragma unroll
    for (int mi = 0; mi < 4; mi++) a[mi] = *(const short8*)&Al[(mi*16 + lr)*128 + ks*32 + lk];
    #pragma unroll
    for (int mi = 0; mi < 4; mi++)
      #pragma unroll
      for (int ni = 0; ni < 2; ni++)
        acc[mi][ni] = __builtin_amdgcn_mfma_f32_16x16x32_bf16(a[mi], bb[ni], acc[mi][ni], 0, 0, 0);
  }

  #pragma unroll
  for (int mi = 0; mi < 4; mi++) {
    #pragma unroll
    for (int q = 0; q < 4; q++) {
      float v0 = acc[mi][0][q];
      float v1 = acc[mi][1][q];
      float best = v0; int bidx = lr;
      if (v1  > best) { best = v1;  bidx = 16 + lr; }
      if (-v0 > best) { best = -v0; bidx = 32 + lr; }
      if (-v1 > best) { best = -v1; bidx = 48 + lr; }
      #pragma unroll
      for (int m = 1; m <= 8; m <<= 1) {
        float ov = __shfl_xor(best, m);
        int   oi = __shfl_xor(bidx, m);
        if (ov > best || (ov == best && oi < bidx)) { best = ov; bidx = oi; }
      }
      if (lr == 0) {
        int row = mi*16 + ((lane >> 4) & 3)*4 + q;
        bkt[(bh*4 + wave)*4096 + tt + row] = bidx;
      }
    }
  }
}

// ---------------- stable counting sort per (bh,hash) ----------------
__global__ __launch_bounds__(256) void k_sort(const int* __restrict__ bkt, int* __restrict__ st) {
  __shared__ unsigned char  hist[64*256];
  __shared__ unsigned short offs[64*256];
  __shared__ int base[64];
  int tid = threadIdx.x, grp = blockIdx.x;
  const int* bk = bkt + grp * 4096;
  for (int i = tid; i < 64*256; i += 256) hist[i] = 0;
  __syncthreads();
  int myb[16];
  #pragma unroll
  for (int j = 0; j < 16; j++) {
    myb[j] = bk[tid*16 + j];
    hist[myb[j]*256 + tid] += 1;
  }
  __syncthreads();
  if (tid < 64) {
    int run = 0;
    for (int t = 0; t < 256; t++) { offs[tid*256 + t] = (unsigned short)run; run += hist[tid*256 + t]; }
    base[tid] = run;
  }
  __syncthreads();
  if (tid == 0) {
    int run = 0;
    for (int b2 = 0; b2 < 64; b2++) { int c = base[b2]; base[b2] = run; run += c; }
  }
  __syncthreads();
  #pragma unroll
  for (int j = 0; j < 16; j++) {
    int b2 = myb[j];
    int r = 0;
    for (int jj = 0; jj < j; jj++) r += (myb[jj] == b2) ? 1 : 0;
    st[grp*4096 + base[b2] + (int)offs[b2*256 + tid] + r] = tid*16 + j;
  }
}

// ---------------- chunked LSH attention (bf16 qk hi-plane input) ----------------
__global__ __launch_bounds__(256) void k_attn(const ushort* __restrict__ qkh, const ushort* __restrict__ vbuf,
                                              const int* __restrict__ st, ushort* __restrict__ o_r,
                                              float* __restrict__ lse_r) {
  __shared__ alignas(16) ushort KV[128*136];
  __shared__ alignas(16) ushort Ps[64*136];
  __shared__ float rnorm[128];
  __shared__ int   kposs[128];
  __shared__ float red1[64*4];
  __shared__ float red2[64*4];
  __shared__ float lrow[64];

  const int tid = threadIdx.x;
  const int bid = blockIdx.x;
  const int bh = bid >> 8;
  const int c  = bid & 255;
  const int h  = c >> 6;
  const int cprev = (c + 255) & 255;
  const int b  = bh >> 3, hh = bh & 7;
  const int lane = tid & 63, wave = tid >> 6;
  const int lr = lane & 15, lk = (lane >> 4) * 8;

  {
    int j = tid >> 1, half = tid & 1;
    int slot = (j < 64) ? (c*64 + j) : (cprev*64 + (j - 64));
    int pos = st[bh*16384 + slot];
    if (half == 0) kposs[j] = pos;
    const ushort* src = qkh + ((size_t)(b * kT + pos)) * kDim + hh*128 + half*64;
    float ss = 0.f;
    #pragma unroll
    for (int i2 = 0; i2 < 64; i2 += 8) {
      uint4 u = *(const uint4*)(src + i2);
      *(uint4*)&KV[j*136 + half*64 + i2] = u;
      float f0 = bu2f((ushort)(u.x & 0xffffu)), f1 = bu2f((ushort)(u.x >> 16));
      float f2 = bu2f((ushort)(u.y & 0xffffu)), f3 = bu2f((ushort)(u.y >> 16));
      float f4 = bu2f((ushort)(u.z & 0xffffu)), f5 = bu2f((ushort)(u.z >> 16));
      float f6 = bu2f((ushort)(u.w & 0xffffu)), f7 = bu2f((ushort)(u.w >> 16));
      ss += f0*f0 + f1*f1 + f2*f2 + f3*f3 + f4*f4 + f5*f5 + f6*f6 + f7*f7;
    }
    ss += __shfl_xor(ss, 1);
    if (half == 0) rnorm[j] = 1.f / fmaxf(sqrtf(ss), 1e-12f);
  }
  __syncthreads();

  {
    floatx4 acc[4][2];
    #pragma unroll
    for (int mi = 0; mi < 4; mi++) { acc[mi][0] = (floatx4){0,0,0,0}; acc[mi][1] = (floatx4){0,0,0,0}; }
    #pragma unroll
    for (int ks = 0; ks < 4; ks++) {
      short8 a[4], bb[2];
      #pragma unroll
      for (int mi = 0; mi < 4; mi++) a[mi]  = *(const short8*)&KV[(mi*16 + lr)*136 + ks*32 + lk];
      #pragma unroll
      for (int ni = 0; ni < 2; ni++) bb[ni] = *(const short8*)&KV[(wave*32 + ni*16 + lr)*136 + ks*32 + lk];
      #pragma unroll
      for (int mi = 0; mi < 4; mi++)
        #pragma unroll
        for (int ni = 0; ni < 2; ni++)
          acc[mi][ni] = __builtin_amdgcn_mfma_f32_16x16x32_bf16(a[mi], bb[ni], acc[mi][ni], 0, 0, 0);
    }
    #pragma unroll
    for (int mi = 0; mi < 4; mi++) {
      #pragma unroll
      for (int ni = 0; ni < 2; ni++) {
        int col = wave*32 + ni*16 + lr;
        float rn = rnorm[col] * kScale;
        int cpos = kposs[col];
        #pragma unroll
        for (int q = 0; q < 4; q++) {
          int row = mi*16 + (lane >> 4)*4 + q;
          float val = acc[mi][ni][q] * rn;
          if (cpos == kposs[row]) val = kSelfVal;
          Ps[row*136 + col] = f2bu(val);
        }
      }
    }
  }
  __syncthreads();

  {
    int j = tid >> 1, half = tid & 1;
    int pos = kposs[j];
    const ushort* src = vbuf + ((size_t)(b * kT + pos)) * kDim + hh*128 + half*64;
    #pragma unroll
    for (int i2 = 0; i2 < 64; i2 += 8) {
      uint4 u = *(const uint4*)(src + i2);
      int d0 = half*64 + i2;
      KV[(d0+0)*136 + j] = (ushort)(u.x & 0xffffu); KV[(d0+1)*136 + j] = (ushort)(u.x >> 16);
      KV[(d0+2)*136 + j] = (ushort)(u.y & 0xffffu); KV[(d0+3)*136 + j] = (ushort)(u.y >> 16);
      KV[(d0+4)*136 + j] = (ushort)(u.z & 0xffffu); KV[(d0+5)*136 + j] = (ushort)(u.z >> 16);
      KV[(d0+6)*136 + j] = (ushort)(u.w & 0xffffu); KV[(d0+7)*136 + j] = (ushort)(u.w >> 16);
    }
  }

  {
    int i = tid >> 2, part = tid & 3;
    const int jb = part * 32;
    float m = -1e30f;
    for (int j2 = 0; j2 < 32; j2++) m = fmaxf(m, bu2f(Ps[i*136 + jb + j2]));
    red1[i*4 + part] = m;
    __syncthreads();
    m = fmaxf(fmaxf(red1[i*4+0], red1[i*4+1]), fmaxf(red1[i*4+2], red1[i*4+3]));
    float ssum = 0.f;
    for (int j2 = 0; j2 < 32; j2++) {
      float arg = fmaxf(fminf(bu2f(Ps[i*136 + jb + j2]) - m, 0.f), -80.f);
      float p = __expf(arg);
      ssum += p;
      Ps[i*136 + jb + j2] = f2bu(p);
    }
    red2[i*4 + part] = ssum;
    __syncthreads();
    if (part == 0) {
      float l = fmaxf(red2[i*4+0] + red2[i*4+1] + red2[i*4+2] + red2[i*4+3], 1e-20f);
      lrow[i] = 1.f / l;
      lse_r[(size_t)(bh*4 + h)*4096 + kposs[i]] = m + __logf(l);
    }
  }
  __syncthreads();

  {
    floatx4 acc[4][2];
    #pragma unroll
    for (int mi = 0; mi < 4; mi++) { acc[mi][0] = (floatx4){0,0,0,0}; acc[mi][1] = (floatx4){0,0,0,0}; }
    #pragma unroll
    for (int ks = 0; ks < 4; ks++) {
      short8 a[4], bb[2];
      #pragma unroll
      for (int mi = 0; mi < 4; mi++) a[mi]  = *(const short8*)&Ps[(mi*16 + lr)*136 + ks*32 + lk];
      #pragma unroll
      for (int ni = 0; ni < 2; ni++) bb[ni] = *(const short8*)&KV[(wave*32 + ni*16 + lr)*136 + ks*32 + lk];
      #pragma unroll
      for (int mi = 0; mi < 4; mi++)
        #pragma unroll
        for (int ni = 0; ni < 2; ni++)
          acc[mi][ni] = __builtin_amdgcn_mfma_f32_16x16x32_bf16(a[mi], bb[ni], acc[mi][ni], 0, 0, 0);
    }
    #pragma unroll
    for (int mi = 0; mi < 4; mi++) {
      #pragma unroll
      for (int ni = 0; ni < 2; ni++) {
        int d = wave*32 + ni*16 + lr;
        #pragma unroll
        for (int q = 0; q < 4; q++) {
          int row = mi*16 + (lane >> 4)*4 + q;
          float o = acc[mi][ni][q] * lrow[row];
          o_r[((size_t)(bh*4 + h)*4096 + kposs[row])*128 + d] = f2bu(o);
        }
      }
    }
  }
}

// ---------------- combine hash rounds ----------------
__global__ __launch_bounds__(256) void k_combine(const ushort* __restrict__ o_r, const float* __restrict__ lse_r,
                                                 ushort* __restrict__ attnbf) {
  int rid = blockIdx.x * 2 + (threadIdx.x >> 7);
  int d = threadIdx.x & 127;
  int bh = rid >> 12, t = rid & 4095;
  int b = bh >> 3, hh = bh & 7;
  size_t base = (size_t)bh * 16384 + t;
  float l0 = lse_r[base], l1 = lse_r[base + 4096], l2 = lse_r[base + 8192], l3 = lse_r[base + 12288];
  float M = fmaxf(fmaxf(l0, l1), fmaxf(l2, l3));
  float e0 = __expf(fmaxf(fminf(l0 - M, 0.f), -80.f));
  float e1 = __expf(fmaxf(fminf(l1 - M, 0.f), -80.f));
  float e2 = __expf(fmaxf(fminf(l2 - M, 0.f), -80.f));
  float e3 = __expf(fmaxf(fminf(l3 - M, 0.f), -80.f));
  float inv = 1.f / (e0 + e1 + e2 + e3);
  float o = e0 * bu2f(o_r[(base         )*128 + d]) + e1 * bu2f(o_r[(base +  4096)*128 + d])
          + e2 * bu2f(o_r[(base +  8192)*128 + d]) + e3 * bu2f(o_r[(base + 12288)*128 + d]);
  attnbf[((size_t)b * kT + t) * kDim + hh*128 + d] = f2bu(o * inv);
}

extern "C" void kernel_launch(void* const* d_in, const int* in_sizes, int n_in,
                              void* d_out, int out_size, void* d_ws, size_t ws_size,
                              hipStream_t stream) {
  (void)in_sizes; (void)n_in; (void)out_size; (void)ws_size;
  const void* x     = d_in[0];
  const void* ln1_g = d_in[1];
  const void* ln1_b = d_in[2];
  const void* Wqk   = d_in[3];
  const void* Wv    = d_in[4];
  const void* Wo    = d_in[5];
  const void* bo    = d_in[6];
  const void* ln2_g = d_in[7];
  const void* ln2_b = d_in[8];
  const void* W1    = d_in[9];
  const void* b1    = d_in[10];
  const void* W2    = d_in[11];
  const void* b2    = d_in[12];
  const void* rot   = d_in[13];

  char* w = (char*)d_ws;
  int*    flag = (int*)w;    w += 256;
  ushort* prm  = (ushort*)w; w += 131072;
  float* x1  = (float*)w;  w += 33554432;
  float* x2  = (float*)w;  w += 33554432;
  ushort* qkh = (ushort*)w; w += 16777216;
  ushort* qkl = (ushort*)w; w += 16777216;
  ushort* vbb = (ushort*)w; w += 16777216;
  ushort* xbf = (ushort*)w; w += 16777216;
  ushort* orb = (ushort*)w; w += 67108864;
  float* lse = (float*)w;  w += 1048576;
  int*   bkt = (int*)w;    w += 1048576;
  int*   stb = (int*)w;    w += 1048576;
  ushort* wtA = (ushort*)w; w += 2097152;
  ushort* wtB = (ushort*)w; w += 2097152;
  ushort* wtC = (ushort*)w; w += 2097152;
  ushort* wt1 = (ushort*)w; w += 8388608;
  ushort* wt2 = (ushort*)w; w += 8388608;
  ushort* rtT = (ushort*)w; w += 32768;

  ushort* pLN1G = prm + 0;     ushort* pLN1B = prm + 2048;
  ushort* pBO   = prm + 4096;  ushort* pLN2G = prm + 6144;
  ushort* pLN2B = prm + 8192;  ushort* pB1   = prm + 10240;
  ushort* pB2   = prm + 18432; ushort* pROT  = prm + 20480;

  k_detect<<<1, 256, 0, stream>>>((const unsigned*)x, flag);
  k_cvt<<<8,   256, 0, stream>>>(flag, ln1_g, pLN1G, 2048);
  k_cvt<<<8,   256, 0, stream>>>(flag, ln1_b, pLN1B, 2048);
  k_cvt<<<8,   256, 0, stream>>>(flag, bo,    pBO,   2048);
  k_cvt<<<8,   256, 0, stream>>>(flag, ln2_g, pLN2G, 2048);
  k_cvt<<<8,   256, 0, stream>>>(flag, ln2_b, pLN2B, 2048);
  k_cvt<<<32,  256, 0, stream>>>(flag, b1,    pB1,   8192);
  k_cvt<<<8,   256, 0, stream>>>(flag, b2,    pB2,   2048);
  k_cvt<<<128, 256, 0, stream>>>(flag, rot,   pROT,  32768);
  k_init_any<<<8192, 256, 0, stream>>>(flag, x, x1, x2);

  for (int d = 0; d < 2; d++) {
    k_transpose2<<<dim3(32, 32),  256, 0, stream>>>(flag,
        (const char*)Wqk + (size_t)d*1048576*2, (const char*)Wqk + (size_t)d*1048576*4, wtA, 1024, 1024);
    k_transpose2<<<dim3(32, 32),  256, 0, stream>>>(flag,
        (const char*)Wv  + (size_t)d*1048576*2, (const char*)Wv  + (size_t)d*1048576*4, wtB, 1024, 1024);
    k_transpose2<<<dim3(32, 32),  256, 0, stream>>>(flag,
        (const char*)Wo  + (size_t)d*1048576*2, (const char*)Wo  + (size_t)d*1048576*4, wtC, 1024, 1024);
    k_transpose2<<<dim3(128, 32), 256, 0, stream>>>(flag,
        (const char*)W1  + (size_t)d*4194304*2, (const char*)W1  + (size_t)d*4194304*4, wt1, 1024, 4096);
    k_transpose2<<<dim3(32, 128), 256, 0, stream>>>(flag,
        (const char*)W2  + (size_t)d*4194304*2, (const char*)W2  + (size_t)d*4194304*4, wt2, 4096, 1024);
    k_rot_t<<<1, 256, 0, stream>>>(pROT + (size_t)d * 16384, rtT);

    k_ln<<<8192, 256, 0, stream>>>(x2, pLN1G + d*1024, pLN1B + d*1024, xbf);
    k_gemm2<4><<<dim3(4, 64), 512, 0, stream>>>(xbf, wtA, nullptr, nullptr, qkh, qkl, 8192, 1024, 1024, 5);
    k_gemm2<4><<<dim3(4, 64), 512, 0, stream>>>(xbf, wtB, nullptr, nullptr, vbb, nullptr, 8192, 1024, 1024, 3);
    k_bucket_mfma<<<dim3(64, 16), 256, 0, stream>>>(qkh, qkl, rtT, bkt);
    k_sort<<<64, 256, 0, stream>>>(bkt, stb);
    k_attn<<<4096, 256, 0, stream>>>(qkh, vbb, stb, orb, lse);
    k_combine<<<32768, 256, 0, stream>>>(orb, lse, xbf);
    k_gemm2<4><<<dim3(4, 64), 512, 0, stream>>>(xbf, wtC, pBO + d*1024, x1, nullptr, nullptr, 8192, 1024, 1024, 1);
    k_ln<<<8192, 256, 0, stream>>>(x1, pLN2G + d*1024, pLN2B + d*1024, xbf);
    k_gemm2<8><<<dim3(16, 32), 512, 0, stream>>>(xbf, wt1, pB1 + d*4096, nullptr, orb, nullptr, 8192, 4096, 1024, 2);
    k_gemm2<4><<<dim3(4, 64), 512, 0, stream>>>(orb, wt2, pB2 + d*1024, x2, nullptr, nullptr, 8192, 1024, 4096, 1);
  }
  k_final_any<<<8192, 256, 0, stream>>>(flag, x1, x2, d_out);
}

// Round 3
// 1181.673 us; speedup vs baseline: 1.3163x; 1.3163x over previous
//
#include <hip/hip_runtime.h>
#include <hip/hip_bf16.h>
#include <cmath>

using bf16 = __hip_bfloat16;
typedef __attribute__((ext_vector_type(8))) short short8;
typedef __attribute__((ext_vector_type(4))) float floatx4;

__device__ __forceinline__ float bu2f(ushort u) { return __uint_as_float((unsigned)u << 16); }
__device__ __forceinline__ ushort f2bu(float f) {
  union { bf16 b; ushort u; } cv; cv.b = __float2bfloat16(f); return cv.u;
}
__device__ __forceinline__ void gl_lds16(const ushort* g, ushort* l) {
  __builtin_amdgcn_global_load_lds((const __attribute__((address_space(1))) unsigned*)g,
                                   (__attribute__((address_space(3))) unsigned*)l, 16, 0, 0);
}
// tanh-form GELU via hw exp; |err vs erf-GELU| ~2e-4, below bf16 output quantization
__device__ __forceinline__ float fast_gelu(float x) {
  float z = 0.7978845608028654f * (x + 0.044715f * x * x * x);
  z = fmaxf(fminf(z, 10.f), -10.f);
  float e = __expf(2.f * z);
  float t = (e - 1.f) / (e + 1.f);
  return 0.5f * x * (1.f + t);
}

static constexpr int kT   = 4096;
static constexpr int kDim = 1024;
static constexpr float kScale   = 0.08838834764831845f;  // 1/sqrt(128)
static constexpr float kSelfVal = -5.0e4f;

// ---------------- dtype detector: bf16 vs fp32 inputs ----------------
__device__ __forceinline__ int sane_v(float f) { float a = fabsf(f); return (a > 1e-4f && a < 1e4f) ? 1 : 0; }

__global__ __launch_bounds__(256) void k_detect(const unsigned* __restrict__ x, int* __restrict__ flag) {
  __shared__ int cnt;
  int tid = threadIdx.x;
  if (tid == 0) cnt = 0;
  __syncthreads();
  int my = 0;
  const uint4* p = (const uint4*)x;
  for (int q = 0; q < 16; q++) {
    uint4 u = p[tid * 16 + q];
    my += sane_v(__uint_as_float(u.x << 16)) + sane_v(__uint_as_float(u.x & 0xffff0000u));
    my += sane_v(__uint_as_float(u.y << 16)) + sane_v(__uint_as_float(u.y & 0xffff0000u));
    my += sane_v(__uint_as_float(u.z << 16)) + sane_v(__uint_as_float(u.z & 0xffff0000u));
    my += sane_v(__uint_as_float(u.w << 16)) + sane_v(__uint_as_float(u.w & 0xffff0000u));
  }
  atomicAdd(&cnt, my);
  __syncthreads();
  if (tid == 0) flag[0] = (cnt >= 24576) ? 1 : 0;
}

__global__ __launch_bounds__(256) void k_cvt(const int* __restrict__ flag, const void* __restrict__ src,
                                             ushort* __restrict__ dst, int n) {
  int i = blockIdx.x * 256 + threadIdx.x;
  if (i >= n) return;
  dst[i] = (*flag) ? ((const ushort*)src)[i] : f2bu(((const float*)src)[i]);
}

__global__ __launch_bounds__(256) void k_init_any(const int* __restrict__ flag, const void* __restrict__ x,
                                                  float* __restrict__ x1, float* __restrict__ x2) {
  int i = blockIdx.x * 1024 + threadIdx.x * 4;
  float4 f;
  if (*flag) {
    ushort4 u = *(const ushort4*)((const ushort*)x + i);
    f.x = bu2f(u.x); f.y = bu2f(u.y); f.z = bu2f(u.z); f.w = bu2f(u.w);
  } else {
    f = *(const float4*)((const float*)x + i);
  }
  *(float4*)(x1 + i) = f;
  *(float4*)(x2 + i) = f;
}

__global__ __launch_bounds__(256) void k_final_any(const int* __restrict__ flag, const float* __restrict__ x1,
                                                   const float* __restrict__ x2, void* __restrict__ out) {
  int i = blockIdx.x * 1024 + threadIdx.x * 4;
  float4 a = *(const float4*)(x1 + i);
  float4 b = *(const float4*)(x2 + i);
  float4 s; s.x = a.x + b.x; s.y = a.y + b.y; s.z = a.z + b.z; s.w = a.w + b.w;
  if (*flag) {
    ushort4 u; u.x = f2bu(s.x); u.y = f2bu(s.y); u.z = f2bu(s.z); u.w = f2bu(s.w);
    *(ushort4*)((ushort*)out + i) = u;
  } else {
    *(float4*)((float*)out + i) = s;
  }
}

// ---------------- layernorm: fp32 in -> bf16 out ----------------
__global__ __launch_bounds__(256) void k_ln(const float* __restrict__ x, const ushort* __restrict__ g,
                                            const ushort* __restrict__ be, ushort* __restrict__ out) {
  __shared__ float ws[4], ws2[4];
  int row = blockIdx.x, tid = threadIdx.x;
  const float* xr = x + (size_t)row * kDim + tid * 4;
  float4 v = *(const float4*)xr;
  float s  = v.x + v.y + v.z + v.w;
  float s2 = v.x*v.x + v.y*v.y + v.z*v.z + v.w*v.w;
  #pragma unroll
  for (int off = 32; off; off >>= 1) { s += __shfl_down(s, off); s2 += __shfl_down(s2, off); }
  int wave = tid >> 6, lane = tid & 63;
  if (lane == 0) { ws[wave] = s; ws2[wave] = s2; }
  __syncthreads();
  s  = ws[0] + ws[1] + ws[2] + ws[3];
  s2 = ws2[0] + ws2[1] + ws2[2] + ws2[3];
  float mean = s * (1.f/1024.f);
  float var  = fmaxf(s2 * (1.f/1024.f) - mean*mean, 0.f);
  float rstd = rsqrtf(var + 1e-5f);
  int cb = tid * 4;
  ushort* o = out + (size_t)row * kDim + cb;
  o[0] = f2bu((v.x - mean) * rstd * bu2f(g[cb+0]) + bu2f(be[cb+0]));
  o[1] = f2bu((v.y - mean) * rstd * bu2f(g[cb+1]) + bu2f(be[cb+1]));
  o[2] = f2bu((v.z - mean) * rstd * bu2f(g[cb+2]) + bu2f(be[cb+2]));
  o[3] = f2bu((v.w - mean) * rstd * bu2f(g[cb+3]) + bu2f(be[cb+3]));
}

// ---------------- dual-dtype weight transpose: in[K,N] -> out[N,K] ----------------
__global__ __launch_bounds__(256) void k_transpose2(const int* __restrict__ flag, const void* __restrict__ src_bf,
                                                    const void* __restrict__ src_f, ushort* __restrict__ out,
                                                    int K, int N) {
  __shared__ ushort tile[32][33];
  int isbf = *flag;
  int nb = blockIdx.x * 32, kb = blockIdx.y * 32;
  int tx = threadIdx.x & 31, ty = threadIdx.x >> 5;
  for (int r = ty; r < 32; r += 8) {
    size_t idx = (size_t)(kb + r) * N + nb + tx;
    tile[r][tx] = isbf ? ((const ushort*)src_bf)[idx] : f2bu(((const float*)src_f)[idx]);
  }
  __syncthreads();
  for (int r = ty; r < 32; r += 8) out[(size_t)(nb + r) * K + kb + tx] = tile[tx][r];
}

// ---------------- rot transpose: rot[k=128][n=128] -> rotT[n=128][k=128] ----------------
__global__ __launch_bounds__(256) void k_rot_t(const ushort* __restrict__ rot, ushort* __restrict__ rotT) {
  int tid = threadIdx.x;
  for (int idx = tid; idx < 16384; idx += 256) {
    int n = idx >> 7, k = idx & 127;
    rotT[idx] = rot[k * 128 + n];
  }
}

// ---------------- fine-phased pipelined GEMM ----------------
// BN=256, BK=32, 512 threads = 8 waves (2M x 4N). MW = M-fragments per wave:
//   MW=8 -> BM=256 (wave tile 128x64), MW=4 -> BM=128 (wave tile 64x64).
// 4 LDS buffers; prefetch distance 3 K-tiles; TWO phases per K-tile:
//   phase = { ds_read half the fragments || stage ~half of kt+3's loads;
//             [counted vmcnt at K-tile boundary]; s_barrier;
//             setprio(1); 16/8 MFMA; setprio(0); sched_barrier(0); s_barrier }
// (fine interleave per m196/m201; never vmcnt(0) in steady state).
// Race safety: stage(kt+3) writes buf[(kt+3)&3] = buf[(kt-1)&3]; all reads of
// kt-1 were consumed by its MFMAs (pinned before its trailing barrier), and the
// stage is issued after that barrier in program order.
// vmcnt accounting (L = loads/thread/kt = LA+2): validate kt+1 at end of kt's
// phase B -> allowed = L*[kt+2<NT] + L*[kt+3<NT]  (8/4/0 for MW=8, 6/3/0 for MW=4).
// Staging via global_load_lds with SOURCE-side chunk swizzle cs = c ^ ((row>>1)&3);
// read-side slot g^((row>>1)&3) recovers it; quarter-wave aliasing is 2-way (free).
// Epilogue (modes 2/3/5): LDS-bounce -> fully coalesced dwordx4 row stores
// (fixes round-2's 5x partial-line write amplification). Mode 1 keeps scalar RMW.
// mode 1: Cf += A@B + bias   mode 2: Cb = bf16(gelu(A@B+bias))
// mode 3: Cb = bf16(A@B)     mode 5: Cb = hi(A@B), Cb2 = lo(A@B)
template <int MW>
__global__ __launch_bounds__(512, 2) void k_gemm2(const ushort* __restrict__ A, const ushort* __restrict__ Bt,
                                                  const ushort* __restrict__ bias, float* __restrict__ Cf,
                                                  ushort* __restrict__ Cb, ushort* __restrict__ Cb2,
                                                  int M, int N, int K, int mode) {
  constexpr int BM  = MW * 32;       // 256 or 128
  constexpr int LA  = MW / 4;        // A-loads per thread per K-tile: 2 or 1
  constexpr int AHI = (MW == 8) ? 4 : 2;   // m-frags in phase A
  __shared__ alignas(16) ushort SAu[4 * BM * 32];    // 64 KB / 32 KB
  __shared__ alignas(16) ushort SBu[4 * 256 * 32];   // 64 KB

  const int tid  = threadIdx.x;
  const int lane = tid & 63, wave = tid >> 6;
  const int lr = lane & 15, g = lane >> 4;       // g = k-chunk index 0..3
  const int wm = wave >> 2, wn = wave & 3;

  // XCD-aware bijective block swizzle (all grids here have nwg % 8 == 0)
  const int nbx = gridDim.x;
  const int nwg = nbx * gridDim.y;
  const int bid = blockIdx.y * nbx + blockIdx.x;
  const int swz = (bid & 7) * (nwg >> 3) + (bid >> 3);
  const int m0 = (swz / nbx) * BM;
  const int n0 = (swz % nbx) * 256;

  const int NT = K >> 5;

  // per-thread staging sources (global col-chunk pre-swizzled, LDS dest linear)
  const ushort* srcA[LA];
  #pragma unroll
  for (int j = 0; j < LA; j++) {
    int chunk = wave * (64 * LA) + j * 64 + lane;
    int row = chunk >> 2, c = chunk & 3;
    int cs = c ^ ((row >> 1) & 3);
    srcA[j] = A + (size_t)(m0 + row) * K + cs * 8;
  }
  const ushort* srcB[2];
  #pragma unroll
  for (int j = 0; j < 2; j++) {
    int chunk = wave * 128 + j * 64 + lane;
    int row = chunk >> 2, c = chunk & 3;
    int cs = c ^ ((row >> 1) & 3);
    srcB[j] = Bt + (size_t)(n0 + row) * K + cs * 8;
  }

  // fragment read offsets (loop-invariant; ushort units)
  int offA[MW], offB[4];
  #pragma unroll
  for (int mi = 0; mi < MW; mi++) {
    int row = wm * (MW * 16) + mi * 16 + lr;
    offA[mi] = row * 32 + ((g ^ ((row >> 1) & 3)) * 8);
  }
  #pragma unroll
  for (int ni = 0; ni < 4; ni++) {
    int row = wn * 64 + ni * 16 + lr;
    offB[ni] = row * 32 + ((g ^ ((row >> 1) & 3)) * 8);
  }

  floatx4 acc[MW][4];
  #pragma unroll
  for (int mi = 0; mi < MW; mi++)
    #pragma unroll
    for (int ni = 0; ni < 4; ni++) acc[mi][ni] = (floatx4){0.f, 0.f, 0.f, 0.f};

  // prologue: stage K-tiles 0,1,2 (NT >= 32 always here)
  #pragma unroll
  for (int p = 0; p < 3; p++) {
    #pragma unroll
    for (int j = 0; j < LA; j++) gl_lds16(srcA[j] + p * 32, SAu + p * (BM * 32) + (wave * (64 * LA) + j * 64) * 8);
    #pragma unroll
    for (int j = 0; j < 2; j++)  gl_lds16(srcB[j] + p * 32, SBu + p * (256 * 32) + (wave * 128 + j * 64) * 8);
  }
  if constexpr (MW == 8) asm volatile("s_waitcnt vmcnt(8)" ::: "memory");
  else                   asm volatile("s_waitcnt vmcnt(6)" ::: "memory");
  __builtin_amdgcn_s_barrier();
  asm volatile("" ::: "memory");

  for (int kt = 0; kt < NT; kt++) {
    const ushort* sa = SAu + (kt & 3) * (BM * 32);
    const ushort* sb = SBu + (kt & 3) * (256 * 32);
    const bool pf = (kt + 3 < NT);
    const int kp = (kt + 3) * 32, pb = (kt + 3) & 3;

    // ---------- phase A ----------
    short8 aA[AHI], bb[4];
    #pragma unroll
    for (int i = 0; i < AHI; i++) aA[i] = *(const short8*)&sa[offA[i]];
    #pragma unroll
    for (int ni = 0; ni < 4; ni++) bb[ni] = *(const short8*)&sb[offB[ni]];
    if (pf) {
      if constexpr (MW == 8) {
        gl_lds16(srcA[0] + kp, SAu + pb * (BM * 32) + (wave * 128 + 0) * 8);
        gl_lds16(srcA[1] + kp, SAu + pb * (BM * 32) + (wave * 128 + 64) * 8);
      } else {
        gl_lds16(srcA[0] + kp, SAu + pb * (BM * 32) + (wave * 64) * 8);
        gl_lds16(srcB[0] + kp, SBu + pb * (256 * 32) + (wave * 128 + 0) * 8);
      }
    }
    __builtin_amdgcn_s_barrier();
    asm volatile("" ::: "memory");
    __builtin_amdgcn_s_setprio(1);
    #pragma unroll
    for (int mi = 0; mi < AHI; mi++)
      #pragma unroll
      for (int ni = 0; ni < 4; ni++)
        acc[mi][ni] = __builtin_amdgcn_mfma_f32_16x16x32_bf16(aA[mi], bb[ni], acc[mi][ni], 0, 0, 0);
    __builtin_amdgcn_s_setprio(0);
    __builtin_amdgcn_sched_barrier(0);
    __builtin_amdgcn_s_barrier();
    asm volatile("" ::: "memory");

    // ---------- phase B ----------
    short8 aB[MW - AHI];
    #pragma unroll
    for (int i = 0; i < MW - AHI; i++) aB[i] = *(const short8*)&sa[offA[AHI + i]];
    if (pf) {
      if constexpr (MW == 8) {
        gl_lds16(srcB[0] + kp, SBu + pb * (256 * 32) + (wave * 128 + 0) * 8);
        gl_lds16(srcB[1] + kp, SBu + pb * (256 * 32) + (wave * 128 + 64) * 8);
      } else {
        gl_lds16(srcB[1] + kp, SBu + pb * (256 * 32) + (wave * 128 + 64) * 8);
      }
    }
    // counted wait validating kt+1 (allowed = L*[kt+2<NT] + L*[kt+3<NT])
    if (kt + 3 < NT) {
      if constexpr (MW == 8) asm volatile("s_waitcnt vmcnt(8)" ::: "memory");
      else                   asm volatile("s_waitcnt vmcnt(6)" ::: "memory");
    } else if (kt + 2 < NT) {
      if constexpr (MW == 8) asm volatile("s_waitcnt vmcnt(4)" ::: "memory");
      else                   asm volatile("s_waitcnt vmcnt(3)" ::: "memory");
    } else if (kt + 1 < NT) {
      asm volatile("s_waitcnt vmcnt(0)" ::: "memory");
    }
    __builtin_amdgcn_s_barrier();
    asm volatile("" ::: "memory");
    __builtin_amdgcn_s_setprio(1);
    #pragma unroll
    for (int mi = 0; mi < MW - AHI; mi++)
      #pragma unroll
      for (int ni = 0; ni < 4; ni++)
        acc[AHI + mi][ni] = __builtin_amdgcn_mfma_f32_16x16x32_bf16(aB[mi], bb[ni], acc[AHI + mi][ni], 0, 0, 0);
    __builtin_amdgcn_s_setprio(0);
    __builtin_amdgcn_sched_barrier(0);
    __builtin_amdgcn_s_barrier();
    asm volatile("" ::: "memory");
  }

  const int hi4 = (lane >> 4) * 4;

  if (mode == 1) {
    // scalar float RMW (64 B contiguous per quarter-wave; was clean in baseline)
    #pragma unroll
    for (int mi = 0; mi < MW; mi++) {
      #pragma unroll
      for (int ni = 0; ni < 4; ni++) {
        int col = n0 + wn * 64 + ni * 16 + lr;
        float bv = bu2f(bias[col]);
        #pragma unroll
        for (int q = 0; q < 4; q++) {
          int r2 = m0 + wm * (MW * 16) + mi * 16 + hi4 + q;
          Cf[(size_t)r2 * N + col] += acc[mi][ni][q] + bv;
        }
      }
    }
  } else {
    // LDS-bounce epilogue: acc -> swizzled LDS -> coalesced dwordx4 stores.
    // region0 = rows 0..127, region1 = rows 128..255 (MW=8 only).
    ushort* reg0 = (MW == 8) ? SAu : SBu;
    ushort* reg1 = SBu;
    // plane 0: primary bf16 output
    #pragma unroll
    for (int mi = 0; mi < MW; mi++) {
      #pragma unroll
      for (int ni = 0; ni < 4; ni++) {
        int colw = wn * 64 + ni * 16 + lr;            // 0..255
        float bv = (mode == 2) ? bu2f(bias[n0 + colw]) : 0.f;
        #pragma unroll
        for (int q = 0; q < 4; q++) {
          int grow = wm * (MW * 16) + mi * 16 + hi4 + q;   // 0..BM-1
          ushort* reg = (grow < 128) ? reg0 : reg1;
          int rl = grow & 127;
          float val = acc[mi][ni][q];
          ushort h = (mode == 2) ? f2bu(fast_gelu(val + bv)) : f2bu(val);
          reg[rl * 256 + (((colw >> 3) ^ (rl & 7)) * 8) + (colw & 7)] = h;
        }
      }
    }
    __syncthreads();
    {
      const int j = tid & 31;
      const int rsub = tid >> 5;     // 0..15
      #pragma unroll
      for (int p = 0; p < BM / 16; p++) {
        int row = p * 16 + rsub;
        const ushort* reg = (row < 128) ? reg0 : reg1;
        int rl = row & 127;
        short8 v = *(const short8*)&reg[rl * 256 + ((j ^ (rl & 7)) * 8)];
        *(short8*)&Cb[(size_t)(m0 + row) * N + n0 + j * 8] = v;
      }
    }
    if (mode == 5) {
      __syncthreads();
      // plane 1: residual lo = val - bu2f(hi)
      #pragma unroll
      for (int mi = 0; mi < MW; mi++) {
        #pragma unroll
        for (int ni = 0; ni < 4; ni++) {
          int colw = wn * 64 + ni * 16 + lr;
          #pragma unroll
          for (int q = 0; q < 4; q++) {
            int grow = wm * (MW * 16) + mi * 16 + hi4 + q;
            ushort* reg = (grow < 128) ? reg0 : reg1;
            int rl = grow & 127;
            float val = acc[mi][ni][q];
            ushort h = f2bu(val);
            reg[rl * 256 + (((colw >> 3) ^ (rl & 7)) * 8) + (colw & 7)] = f2bu(val - bu2f(h));
          }
        }
      }
      __syncthreads();
      const int j = tid & 31;
      const int rsub = tid >> 5;
      #pragma unroll
      for (int p = 0; p < BM / 16; p++) {
        int row = p * 16 + rsub;
        const ushort* reg = (row < 128) ? reg0 : reg1;
        int rl = row & 127;
        short8 v = *(const short8*)&reg[rl * 256 + ((j ^ (rl & 7)) * 8)];
        *(short8*)&Cb2[(size_t)(m0 + row) * N + n0 + j * 8] = v;
      }
    }
  }
  (void)M;
}

// ---------------- MFMA bucket: consumes qk hi/lo bf16 planes; in-register first-max argmax ----------------
__global__ __launch_bounds__(256) void k_bucket_mfma(const ushort* __restrict__ qkh, const ushort* __restrict__ qkl,
                                                     const ushort* __restrict__ rotT, int* __restrict__ bkt) {
  __shared__ alignas(16) ushort Bs[128*128];  // rotT [n][k]  32 KB
  __shared__ alignas(16) ushort Ah[64*128];   // Q hi         16 KB
  __shared__ alignas(16) ushort Al[64*128];   // Q lo         16 KB
  const int tid = threadIdx.x;
  const int lane = tid & 63, wave = tid >> 6;
  const int lr = lane & 15, lk = (lane >> 4) * 8;
  const int tt = blockIdx.x * 64;
  const int bh = blockIdx.y;
  const int b = bh >> 3, hh = bh & 7;

  {
    int r = tid >> 2, c0 = (tid & 3) * 32;
    size_t base = ((size_t)(b * kT + tt + r)) * kDim + hh * 128 + c0;
    const uint4* sh = (const uint4*)(qkh + base);
    const uint4* sl = (const uint4*)(qkl + base);
    uint4* dh = (uint4*)&Ah[r * 128 + c0];
    uint4* dl = (uint4*)&Al[r * 128 + c0];
    #pragma unroll
    for (int i = 0; i < 4; i++) { dh[i] = sh[i]; dl[i] = sl[i]; }
  }
  {
    const uint4* src = (const uint4*)rotT;
    uint4* dst = (uint4*)Bs;
    for (int i = tid; i < 2048; i += 256) dst[i] = src[i];
  }
  __syncthreads();

  floatx4 acc[4][2];
  #pragma unroll
  for (int mi = 0; mi < 4; mi++) { acc[mi][0] = (floatx4){0,0,0,0}; acc[mi][1] = (floatx4){0,0,0,0}; }
  #pragma unroll
  for (int ks = 0; ks < 4; ks++) {
    short8 a[4], bb[2];
    #pragma unroll
    for (int ni = 0; ni < 2; ni++) bb[ni] = *(const short8*)&Bs[(wave*32 + ni*16 + lr)*128 + ks*32 + lk];
    #pragma unroll
    for (int mi = 0; mi < 4; mi++) a[mi] = *(const short8*)&Ah[(mi*16 + lr)*128 + ks*32 + lk];
    #pragma unroll
    for (int mi = 0; mi < 4; mi++)
      #pragma unroll
      for (int ni = 0; ni < 2; ni++)
        acc[mi][ni] = __builtin_amdgcn_mfma_f32_16x16x32_bf16(a[mi], bb[ni], acc[mi][ni], 0, 0, 0);
  }
  #pragma unroll
  for (int ks = 0; ks < 4; ks++) {
    short8 a[4], bb[2];
    #pragma unroll
    for (int ni = 0; ni < 2; ni++) bb[ni] = *(const short8*)&Bs[(wave*32 + ni*16 + lr)*128 + ks*32 + lk];
    #pragma unroll
    for (int mi = 0; mi < 4; mi++) a[mi] = *(const short8*)&Al[(mi*16 + lr)*128 + ks*32 + lk];
    #pragma unroll
    for (int mi = 0; mi < 4; mi++)
      #pragma unroll
      for (int ni = 0; ni < 2; ni++)
        acc[mi][ni] = __builtin_amdgcn_mfma_f32_16x16x32_bf16(a[mi], bb[ni], acc[mi][ni], 0, 0, 0);
  }

  #pragma unroll
  for (int mi = 0; mi < 4; mi++) {
    #pragma unroll
    for (int q = 0; q < 4; q++) {
      float v0 = acc[mi][0][q];
      float v1 = acc[mi][1][q];
      float best = v0; int bidx = lr;
      if (v1  > best) { best = v1;  bidx = 16 + lr; }
      if (-v0 > best) { best = -v0; bidx = 32 + lr; }
      if (-v1 > best) { best = -v1; bidx = 48 + lr; }
      #pragma unroll
      for (int m = 1; m <= 8; m <<= 1) {
        float ov = __shfl_xor(best, m);
        int   oi = __shfl_xor(bidx, m);
        if (ov > best || (ov == best && oi < bidx)) { best = ov; bidx = oi; }
      }
      if (lr == 0) {
        int row = mi*16 + ((lane >> 4) & 3)*4 + q;
        bkt[(bh*4 + wave)*4096 + tt + row] = bidx;
      }
    }
  }
}

// ---------------- stable counting sort per (bh,hash) ----------------
__global__ __launch_bounds__(256) void k_sort(const int* __restrict__ bkt, int* __restrict__ st) {
  __shared__ unsigned char  hist[64*256];
  __shared__ unsigned short offs[64*256];
  __shared__ int base[64];
  int tid = threadIdx.x, grp = blockIdx.x;
  const int* bk = bkt + grp * 4096;
  for (int i = tid; i < 64*256; i += 256) hist[i] = 0;
  __syncthreads();
  int myb[16];
  #pragma unroll
  for (int j = 0; j < 16; j++) {
    myb[j] = bk[tid*16 + j];
    hist[myb[j]*256 + tid] += 1;
  }
  __syncthreads();
  if (tid < 64) {
    int run = 0;
    for (int t = 0; t < 256; t++) { offs[tid*256 + t] = (unsigned short)run; run += hist[tid*256 + t]; }
    base[tid] = run;
  }
  __syncthreads();
  if (tid == 0) {
    int run = 0;
    for (int b2 = 0; b2 < 64; b2++) { int c = base[b2]; base[b2] = run; run += c; }
  }
  __syncthreads();
  #pragma unroll
  for (int j = 0; j < 16; j++) {
    int b2 = myb[j];
    int r = 0;
    for (int jj = 0; jj < j; jj++) r += (myb[jj] == b2) ? 1 : 0;
    st[grp*4096 + base[b2] + (int)offs[b2*256 + tid] + r] = tid*16 + j;
  }
}

// ---------------- chunked LSH attention (bf16 qk hi-plane input) ----------------
__global__ __launch_bounds__(256) void k_attn(const ushort* __restrict__ qkh, const ushort* __restrict__ vbuf,
                                              const int* __restrict__ st, ushort* __restrict__ o_r,
                                              float* __restrict__ lse_r) {
  __shared__ alignas(16) ushort KV[128*136];
  __shared__ alignas(16) ushort Ps[64*136];
  __shared__ float rnorm[128];
  __shared__ int   kposs[128];
  __shared__ float red1[64*4];
  __shared__ float red2[64*4];
  __shared__ float lrow[64];

  const int tid = threadIdx.x;
  const int bid = blockIdx.x;
  const int bh = bid >> 8;
  const int c  = bid & 255;
  const int h  = c >> 6;
  const int cprev = (c + 255) & 255;
  const int b  = bh >> 3, hh = bh & 7;
  const int lane = tid & 63, wave = tid >> 6;
  const int lr = lane & 15, lk = (lane >> 4) * 8;

  {
    int j = tid >> 1, half = tid & 1;
    int slot = (j < 64) ? (c*64 + j) : (cprev*64 + (j - 64));
    int pos = st[bh*16384 + slot];
    if (half == 0) kposs[j] = pos;
    const ushort* src = qkh + ((size_t)(b * kT + pos)) * kDim + hh*128 + half*64;
    float ss = 0.f;
    #pragma unroll
    for (int i2 = 0; i2 < 64; i2 += 8) {
      uint4 u = *(const uint4*)(src + i2);
      *(uint4*)&KV[j*136 + half*64 + i2] = u;
      float f0 = bu2f((ushort)(u.x & 0xffffu)), f1 = bu2f((ushort)(u.x >> 16));
      float f2 = bu2f((ushort)(u.y & 0xffffu)), f3 = bu2f((ushort)(u.y >> 16));
      float f4 = bu2f((ushort)(u.z & 0xffffu)), f5 = bu2f((ushort)(u.z >> 16));
      float f6 = bu2f((ushort)(u.w & 0xffffu)), f7 = bu2f((ushort)(u.w >> 16));
      ss += f0*f0 + f1*f1 + f2*f2 + f3*f3 + f4*f4 + f5*f5 + f6*f6 + f7*f7;
    }
    ss += __shfl_xor(ss, 1);
    if (half == 0) rnorm[j] = 1.f / fmaxf(sqrtf(ss), 1e-12f);
  }
  __syncthreads();

  {
    floatx4 acc[4][2];
    #pragma unroll
    for (int mi = 0; mi < 4; mi++) { acc[mi][0] = (floatx4){0,0,0,0}; acc[mi][1] = (floatx4){0,0,0,0}; }
    #pragma unroll
    for (int ks = 0; ks < 4; ks++) {
      short8 a[4], bb[2];
      #pragma unroll
      for (int mi = 0; mi < 4; mi++) a[mi]  = *(const short8*)&KV[(mi*16 + lr)*136 + ks*32 + lk];
      #pragma unroll
      for (int ni = 0; ni < 2; ni++) bb[ni] = *(const short8*)&KV[(wave*32 + ni*16 + lr)*136 + ks*32 + lk];
      #pragma unroll
      for (int mi = 0; mi < 4; mi++)
        #pragma unroll
        for (int ni = 0; ni < 2; ni++)
          acc[mi][ni] = __builtin_amdgcn_mfma_f32_16x16x32_bf16(a[mi], bb[ni], acc[mi][ni], 0, 0, 0);
    }
    #pragma unroll
    for (int mi = 0; mi < 4; mi++) {
      #pragma unroll
      for (int ni = 0; ni < 2; ni++) {
        int col = wave*32 + ni*16 + lr;
        float rn = rnorm[col] * kScale;
        int cpos = kposs[col];
        #pragma unroll
        for (int q = 0; q < 4; q++) {
          int row = mi*16 + (lane >> 4)*4 + q;
          float val = acc[mi][ni][q] * rn;
          if (cpos == kposs[row]) val = kSelfVal;
          Ps[row*136 + col] = f2bu(val);
        }
      }
    }
  }
  __syncthreads();

  {
    int j = tid >> 1, half = tid & 1;
    int pos = kposs[j];
    const ushort* src = vbuf + ((size_t)(b * kT + pos)) * kDim + hh*128 + half*64;
    #pragma unroll
    for (int i2 = 0; i2 < 64; i2 += 8) {
      uint4 u = *(const uint4*)(src + i2);
      int d0 = half*64 + i2;
      KV[(d0+0)*136 + j] = (ushort)(u.x & 0xffffu); KV[(d0+1)*136 + j] = (ushort)(u.x >> 16);
      KV[(d0+2)*136 + j] = (ushort)(u.y & 0xffffu); KV[(d0+3)*136 + j] = (ushort)(u.y >> 16);
      KV[(d0+4)*136 + j] = (ushort)(u.z & 0xffffu); KV[(d0+5)*136 + j] = (ushort)(u.z >> 16);
      KV[(d0+6)*136 + j] = (ushort)(u.w & 0xffffu); KV[(d0+7)*136 + j] = (ushort)(u.w >> 16);
    }
  }

  {
    int i = tid >> 2, part = tid & 3;
    const int jb = part * 32;
    float m = -1e30f;
    for (int j2 = 0; j2 < 32; j2++) m = fmaxf(m, bu2f(Ps[i*136 + jb + j2]));
    red1[i*4 + part] = m;
    __syncthreads();
    m = fmaxf(fmaxf(red1[i*4+0], red1[i*4+1]), fmaxf(red1[i*4+2], red1[i*4+3]));
    float ssum = 0.f;
    for (int j2 = 0; j2 < 32; j2++) {
      float arg = fmaxf(fminf(bu2f(Ps[i*136 + jb + j2]) - m, 0.f), -80.f);
      float p = __expf(arg);
      ssum += p;
      Ps[i*136 + jb + j2] = f2bu(p);
    }
    red2[i*4 + part] = ssum;
    __syncthreads();
    if (part == 0) {
      float l = fmaxf(red2[i*4+0] + red2[i*4+1] + red2[i*4+2] + red2[i*4+3], 1e-20f);
      lrow[i] = 1.f / l;
      lse_r[(size_t)(bh*4 + h)*4096 + kposs[i]] = m + __logf(l);
    }
  }
  __syncthreads();

  {
    floatx4 acc[4][2];
    #pragma unroll
    for (int mi = 0; mi < 4; mi++) { acc[mi][0] = (floatx4){0,0,0,0}; acc[mi][1] = (floatx4){0,0,0,0}; }
    #pragma unroll
    for (int ks = 0; ks < 4; ks++) {
      short8 a[4], bb[2];
      #pragma unroll
      for (int mi = 0; mi < 4; mi++) a[mi]  = *(const short8*)&Ps[(mi*16 + lr)*136 + ks*32 + lk];
      #pragma unroll
      for (int ni = 0; ni < 2; ni++) bb[ni] = *(const short8*)&KV[(wave*32 + ni*16 + lr)*136 + ks*32 + lk];
      #pragma unroll
      for (int mi = 0; mi < 4; mi++)
        #pragma unroll
        for (int ni = 0; ni < 2; ni++)
          acc[mi][ni] = __builtin_amdgcn_mfma_f32_16x16x32_bf16(a[mi], bb[ni], acc[mi][ni], 0, 0, 0);
    }
    #pragma unroll
    for (int mi = 0; mi < 4; mi++) {
      #pragma unroll
      for (int ni = 0; ni < 2; ni++) {
        int d = wave*32 + ni*16 + lr;
        #pragma unroll
        for (int q = 0; q < 4; q++) {
          int row = mi*16 + (lane >> 4)*4 + q;
          float o = acc[mi][ni][q] * lrow[row];
          o_r[((size_t)(bh*4 + h)*4096 + kposs[row])*128 + d] = f2bu(o);
        }
      }
    }
  }
}

// ---------------- combine hash rounds ----------------
__global__ __launch_bounds__(256) void k_combine(const ushort* __restrict__ o_r, const float* __restrict__ lse_r,
                                                 ushort* __restrict__ attnbf) {
  int rid = blockIdx.x * 2 + (threadIdx.x >> 7);
  int d = threadIdx.x & 127;
  int bh = rid >> 12, t = rid & 4095;
  int b = bh >> 3, hh = bh & 7;
  size_t base = (size_t)bh * 16384 + t;
  float l0 = lse_r[base], l1 = lse_r[base + 4096], l2 = lse_r[base + 8192], l3 = lse_r[base + 12288];
  float M = fmaxf(fmaxf(l0, l1), fmaxf(l2, l3));
  float e0 = __expf(fmaxf(fminf(l0 - M, 0.f), -80.f));
  float e1 = __expf(fmaxf(fminf(l1 - M, 0.f), -80.f));
  float e2 = __expf(fmaxf(fminf(l2 - M, 0.f), -80.f));
  float e3 = __expf(fmaxf(fminf(l3 - M, 0.f), -80.f));
  float inv = 1.f / (e0 + e1 + e2 + e3);
  float o = e0 * bu2f(o_r[(base         )*128 + d]) + e1 * bu2f(o_r[(base +  4096)*128 + d])
          + e2 * bu2f(o_r[(base +  8192)*128 + d]) + e3 * bu2f(o_r[(base + 12288)*128 + d]);
  attnbf[((size_t)b * kT + t) * kDim + hh*128 + d] = f2bu(o * inv);
}

extern "C" void kernel_launch(void* const* d_in, const int* in_sizes, int n_in,
                              void* d_out, int out_size, void* d_ws, size_t ws_size,
                              hipStream_t stream) {
  (void)in_sizes; (void)n_in; (void)out_size; (void)ws_size;
  const void* x     = d_in[0];
  const void* ln1_g = d_in[1];
  const void* ln1_b = d_in[2];
  const void* Wqk   = d_in[3];
  const void* Wv    = d_in[4];
  const void* Wo    = d_in[5];
  const void* bo    = d_in[6];
  const void* ln2_g = d_in[7];
  const void* ln2_b = d_in[8];
  const void* W1    = d_in[9];
  const void* b1    = d_in[10];
  const void* W2    = d_in[11];
  const void* b2    = d_in[12];
  const void* rot   = d_in[13];

  char* w = (char*)d_ws;
  int*    flag = (int*)w;    w += 256;
  ushort* prm  = (ushort*)w; w += 131072;
  float* x1  = (float*)w;  w += 33554432;
  float* x2  = (float*)w;  w += 33554432;
  ushort* qkh = (ushort*)w; w += 16777216;
  ushort* qkl = (ushort*)w; w += 16777216;
  ushort* vbb = (ushort*)w; w += 16777216;
  ushort* xbf = (ushort*)w; w += 16777216;
  ushort* orb = (ushort*)w; w += 67108864;
  float* lse = (float*)w;  w += 1048576;
  int*   bkt = (int*)w;    w += 1048576;
  int*   stb = (int*)w;    w += 1048576;
  ushort* wtA = (ushort*)w; w += 2097152;
  ushort* wtB = (ushort*)w; w += 2097152;
  ushort* wtC = (ushort*)w; w += 2097152;
  ushort* wt1 = (ushort*)w; w += 8388608;
  ushort* wt2 = (ushort*)w; w += 8388608;
  ushort* rtT = (ushort*)w; w += 32768;

  ushort* pLN1G = prm + 0;     ushort* pLN1B = prm + 2048;
  ushort* pBO   = prm + 4096;  ushort* pLN2G = prm + 6144;
  ushort* pLN2B = prm + 8192;  ushort* pB1   = prm + 10240;
  ushort* pB2   = prm + 18432; ushort* pROT  = prm + 20480;

  k_detect<<<1, 256, 0, stream>>>((const unsigned*)x, flag);
  k_cvt<<<8,   256, 0, stream>>>(flag, ln1_g, pLN1G, 2048);
  k_cvt<<<8,   256, 0, stream>>>(flag, ln1_b, pLN1B, 2048);
  k_cvt<<<8,   256, 0, stream>>>(flag, bo,    pBO,   2048);
  k_cvt<<<8,   256, 0, stream>>>(flag, ln2_g, pLN2G, 2048);
  k_cvt<<<8,   256, 0, stream>>>(flag, ln2_b, pLN2B, 2048);
  k_cvt<<<32,  256, 0, stream>>>(flag, b1,    pB1,   8192);
  k_cvt<<<8,   256, 0, stream>>>(flag, b2,    pB2,   2048);
  k_cvt<<<128, 256, 0, stream>>>(flag, rot,   pROT,  32768);
  k_init_any<<<8192, 256, 0, stream>>>(flag, x, x1, x2);

  for (int d = 0; d < 2; d++) {
    k_transpose2<<<dim3(32, 32),  256, 0, stream>>>(flag,
        (const char*)Wqk + (size_t)d*1048576*2, (const char*)Wqk + (size_t)d*1048576*4, wtA, 1024, 1024);
    k_transpose2<<<dim3(32, 32),  256, 0, stream>>>(flag,
        (const char*)Wv  + (size_t)d*1048576*2, (const char*)Wv  + (size_t)d*1048576*4, wtB, 1024, 1024);
    k_transpose2<<<dim3(32, 32),  256, 0, stream>>>(flag,
        (const char*)Wo  + (size_t)d*1048576*2, (const char*)Wo  + (size_t)d*1048576*4, wtC, 1024, 1024);
    k_transpose2<<<dim3(128, 32), 256, 0, stream>>>(flag,
        (const char*)W1  + (size_t)d*4194304*2, (const char*)W1  + (size_t)d*4194304*4, wt1, 1024, 4096);
    k_transpose2<<<dim3(32, 128), 256, 0, stream>>>(flag,
        (const char*)W2  + (size_t)d*4194304*2, (const char*)W2  + (size_t)d*4194304*4, wt2, 4096, 1024);
    k_rot_t<<<1, 256, 0, stream>>>(pROT + (size_t)d * 16384, rtT);

    k_ln<<<8192, 256, 0, stream>>>(x2, pLN1G + d*1024, pLN1B + d*1024, xbf);
    k_gemm2<4><<<dim3(4, 64), 512, 0, stream>>>(xbf, wtA, nullptr, nullptr, qkh, qkl, 8192, 1024, 1024, 5);
    k_gemm2<4><<<dim3(4, 64), 512, 0, stream>>>(xbf, wtB, nullptr, nullptr, vbb, nullptr, 8192, 1024, 1024, 3);
    k_bucket_mfma<<<dim3(64, 16), 256, 0, stream>>>(qkh, qkl, rtT, bkt);
    k_sort<<<64, 256, 0, stream>>>(bkt, stb);
    k_attn<<<4096, 256, 0, stream>>>(qkh, vbb, stb, orb, lse);
    k_combine<<<32768, 256, 0, stream>>>(orb, lse, xbf);
    k_gemm2<4><<<dim3(4, 64), 512, 0, stream>>>(xbf, wtC, pBO + d*1024, x1, nullptr, nullptr, 8192, 1024, 1024, 1);
    k_ln<<<8192, 256, 0, stream>>>(x1, pLN2G + d*1024, pLN2B + d*1024, xbf);
    k_gemm2<8><<<dim3(16, 32), 512, 0, stream>>>(xbf, wt1, pB1 + d*4096, nullptr, orb, nullptr, 8192, 4096, 1024, 2);
    k_gemm2<4><<<dim3(4, 64), 512, 0, stream>>>(orb, wt2, pB2 + d*1024, x2, nullptr, nullptr, 8192, 1024, 4096, 1);
  }
  k_final_any<<<8192, 256, 0, stream>>>(flag, x1, x2, d_out);
}

// Round 5
// 1170.429 us; speedup vs baseline: 1.3289x; 1.0096x over previous
//
#include <hip/hip_runtime.h>
#include <hip/hip_bf16.h>
#include <cmath>

using bf16 = __hip_bfloat16;
typedef __attribute__((ext_vector_type(8))) short short8;
typedef __attribute__((ext_vector_type(4))) float floatx4;

__device__ __forceinline__ float bu2f(ushort u) { return __uint_as_float((unsigned)u << 16); }
__device__ __forceinline__ ushort f2bu(float f) {
  union { bf16 b; ushort u; } cv; cv.b = __float2bfloat16(f); return cv.u;
}
__device__ __forceinline__ void gl_lds16(const ushort* g, ushort* l) {
  __builtin_amdgcn_global_load_lds((const __attribute__((address_space(1))) unsigned*)g,
                                   (__attribute__((address_space(3))) unsigned*)l, 16, 0, 0);
}
// tanh-form GELU via hw exp; |err vs erf-GELU| ~2e-4, below bf16 output quantization
__device__ __forceinline__ float fast_gelu(float x) {
  float z = 0.7978845608028654f * (x + 0.044715f * x * x * x);
  z = fmaxf(fminf(z, 10.f), -10.f);
  float e = __expf(2.f * z);
  float t = (e - 1.f) / (e + 1.f);
  return 0.5f * x * (1.f + t);
}

static constexpr int kT   = 4096;
static constexpr int kDim = 1024;
static constexpr float kScale   = 0.08838834764831845f;  // 1/sqrt(128)
static constexpr float kSelfVal = -5.0e4f;

// ---------------- dtype detector: bf16 vs fp32 inputs ----------------
__device__ __forceinline__ int sane_v(float f) { float a = fabsf(f); return (a > 1e-4f && a < 1e4f) ? 1 : 0; }

__global__ __launch_bounds__(256) void k_detect(const unsigned* __restrict__ x, int* __restrict__ flag) {
  __shared__ int cnt;
  int tid = threadIdx.x;
  if (tid == 0) cnt = 0;
  __syncthreads();
  int my = 0;
  const uint4* p = (const uint4*)x;
  for (int q = 0; q < 16; q++) {
    uint4 u = p[tid * 16 + q];
    my += sane_v(__uint_as_float(u.x << 16)) + sane_v(__uint_as_float(u.x & 0xffff0000u));
    my += sane_v(__uint_as_float(u.y << 16)) + sane_v(__uint_as_float(u.y & 0xffff0000u));
    my += sane_v(__uint_as_float(u.z << 16)) + sane_v(__uint_as_float(u.z & 0xffff0000u));
    my += sane_v(__uint_as_float(u.w << 16)) + sane_v(__uint_as_float(u.w & 0xffff0000u));
  }
  atomicAdd(&cnt, my);
  __syncthreads();
  if (tid == 0) flag[0] = (cnt >= 24576) ? 1 : 0;
}

__global__ __launch_bounds__(256) void k_cvt(const int* __restrict__ flag, const void* __restrict__ src,
                                             ushort* __restrict__ dst, int n) {
  int i = blockIdx.x * 256 + threadIdx.x;
  if (i >= n) return;
  dst[i] = (*flag) ? ((const ushort*)src)[i] : f2bu(((const float*)src)[i]);
}

__global__ __launch_bounds__(256) void k_init_any(const int* __restrict__ flag, const void* __restrict__ x,
                                                  float* __restrict__ x1, float* __restrict__ x2) {
  int i = blockIdx.x * 1024 + threadIdx.x * 4;
  float4 f;
  if (*flag) {
    ushort4 u = *(const ushort4*)((const ushort*)x + i);
    f.x = bu2f(u.x); f.y = bu2f(u.y); f.z = bu2f(u.z); f.w = bu2f(u.w);
  } else {
    f = *(const float4*)((const float*)x + i);
  }
  *(float4*)(x1 + i) = f;
  *(float4*)(x2 + i) = f;
}

__global__ __launch_bounds__(256) void k_final_any(const int* __restrict__ flag, const float* __restrict__ x1,
                                                   const float* __restrict__ x2, void* __restrict__ out) {
  int i = blockIdx.x * 1024 + threadIdx.x * 4;
  float4 a = *(const float4*)(x1 + i);
  float4 b = *(const float4*)(x2 + i);
  float4 s; s.x = a.x + b.x; s.y = a.y + b.y; s.z = a.z + b.z; s.w = a.w + b.w;
  if (*flag) {
    ushort4 u; u.x = f2bu(s.x); u.y = f2bu(s.y); u.z = f2bu(s.z); u.w = f2bu(s.w);
    *(ushort4*)((ushort*)out + i) = u;
  } else {
    *(float4*)((float*)out + i) = s;
  }
}

// ---------------- layernorm: fp32 in -> bf16 out ----------------
__global__ __launch_bounds__(256) void k_ln(const float* __restrict__ x, const ushort* __restrict__ g,
                                            const ushort* __restrict__ be, ushort* __restrict__ out) {
  __shared__ float ws[4], ws2[4];
  int row = blockIdx.x, tid = threadIdx.x;
  const float* xr = x + (size_t)row * kDim + tid * 4;
  float4 v = *(const float4*)xr;
  float s  = v.x + v.y + v.z + v.w;
  float s2 = v.x*v.x + v.y*v.y + v.z*v.z + v.w*v.w;
  #pragma unroll
  for (int off = 32; off; off >>= 1) { s += __shfl_down(s, off); s2 += __shfl_down(s2, off); }
  int wave = tid >> 6, lane = tid & 63;
  if (lane == 0) { ws[wave] = s; ws2[wave] = s2; }
  __syncthreads();
  s  = ws[0] + ws[1] + ws[2] + ws[3];
  s2 = ws2[0] + ws2[1] + ws2[2] + ws2[3];
  float mean = s * (1.f/1024.f);
  float var  = fmaxf(s2 * (1.f/1024.f) - mean*mean, 0.f);
  float rstd = rsqrtf(var + 1e-5f);
  int cb = tid * 4;
  ushort* o = out + (size_t)row * kDim + cb;
  o[0] = f2bu((v.x - mean) * rstd * bu2f(g[cb+0]) + bu2f(be[cb+0]));
  o[1] = f2bu((v.y - mean) * rstd * bu2f(g[cb+1]) + bu2f(be[cb+1]));
  o[2] = f2bu((v.z - mean) * rstd * bu2f(g[cb+2]) + bu2f(be[cb+2]));
  o[3] = f2bu((v.w - mean) * rstd * bu2f(g[cb+3]) + bu2f(be[cb+3]));
}

// ---------------- dual-dtype weight transpose: in[K,N] -> out[N,K] ----------------
__global__ __launch_bounds__(256) void k_transpose2(const int* __restrict__ flag, const void* __restrict__ src_bf,
                                                    const void* __restrict__ src_f, ushort* __restrict__ out,
                                                    int K, int N) {
  __shared__ ushort tile[32][33];
  int isbf = *flag;
  int nb = blockIdx.x * 32, kb = blockIdx.y * 32;
  int tx = threadIdx.x & 31, ty = threadIdx.x >> 5;
  for (int r = ty; r < 32; r += 8) {
    size_t idx = (size_t)(kb + r) * N + nb + tx;
    tile[r][tx] = isbf ? ((const ushort*)src_bf)[idx] : f2bu(((const float*)src_f)[idx]);
  }
  __syncthreads();
  for (int r = ty; r < 32; r += 8) out[(size_t)(nb + r) * K + kb + tx] = tile[tx][r];
}

// ---------------- rot transpose: rot[k=128][n=128] -> rotT[n=128][k=128] ----------------
__global__ __launch_bounds__(256) void k_rot_t(const ushort* __restrict__ rot, ushort* __restrict__ rotT) {
  int tid = threadIdx.x;
  for (int idx = tid; idx < 16384; idx += 256) {
    int n = idx >> 7, k = idx & 127;
    rotT[idx] = rot[k * 128 + n];
  }
}

// ---------------- fine-phased pipelined GEMM (generic shapes) ----------------
// Round-3 structure + sched_barrier(0) after each LEADING barrier (rule 18:
// register-only MFMA clusters can hoist above s_barrier, collapsing the phase
// overlap; the pin forces {reads | barrier | MFMA | barrier} shape).
// Re-audited r5: vmcnt ledger, WAR windows (incl. async DMA landing windows),
// and addressing are all verified race/OOB-free.
template <int MW>
__global__ __launch_bounds__(512, 2) void k_gemm2(const ushort* __restrict__ A, const ushort* __restrict__ Bt,
                                                  const ushort* __restrict__ bias, float* __restrict__ Cf,
                                                  ushort* __restrict__ Cb, ushort* __restrict__ Cb2,
                                                  int M, int N, int K, int mode) {
  constexpr int BM  = MW * 32;       // 256 or 128
  constexpr int LA  = MW / 4;        // A-loads per thread per K-tile: 2 or 1
  constexpr int AHI = (MW == 8) ? 4 : 2;   // m-frags in phase A
  __shared__ alignas(16) ushort SAu[4 * BM * 32];    // 64 KB / 32 KB
  __shared__ alignas(16) ushort SBu[4 * 256 * 32];   // 64 KB

  const int tid  = threadIdx.x;
  const int lane = tid & 63, wave = tid >> 6;
  const int lr = lane & 15, g = lane >> 4;       // g = k-chunk index 0..3
  const int wm = wave >> 2, wn = wave & 3;

  // XCD-aware bijective block swizzle (all grids here have nwg % 8 == 0)
  const int nbx = gridDim.x;
  const int nwg = nbx * gridDim.y;
  const int bid = blockIdx.y * nbx + blockIdx.x;
  const int swz = (bid & 7) * (nwg >> 3) + (bid >> 3);
  const int m0 = (swz / nbx) * BM;
  const int n0 = (swz % nbx) * 256;

  const int NT = K >> 5;

  // per-thread staging sources (global col-chunk pre-swizzled, LDS dest linear)
  const ushort* srcA[LA];
  #pragma unroll
  for (int j = 0; j < LA; j++) {
    int chunk = wave * (64 * LA) + j * 64 + lane;
    int row = chunk >> 2, c = chunk & 3;
    int cs = c ^ ((row >> 1) & 3);
    srcA[j] = A + (size_t)(m0 + row) * K + cs * 8;
  }
  const ushort* srcB[2];
  #pragma unroll
  for (int j = 0; j < 2; j++) {
    int chunk = wave * 128 + j * 64 + lane;
    int row = chunk >> 2, c = chunk & 3;
    int cs = c ^ ((row >> 1) & 3);
    srcB[j] = Bt + (size_t)(n0 + row) * K + cs * 8;
  }

  // fragment read offsets (loop-invariant; ushort units)
  int offA[MW], offB[4];
  #pragma unroll
  for (int mi = 0; mi < MW; mi++) {
    int row = wm * (MW * 16) + mi * 16 + lr;
    offA[mi] = row * 32 + ((g ^ ((row >> 1) & 3)) * 8);
  }
  #pragma unroll
  for (int ni = 0; ni < 4; ni++) {
    int row = wn * 64 + ni * 16 + lr;
    offB[ni] = row * 32 + ((g ^ ((row >> 1) & 3)) * 8);
  }

  floatx4 acc[MW][4];
  #pragma unroll
  for (int mi = 0; mi < MW; mi++)
    #pragma unroll
    for (int ni = 0; ni < 4; ni++) acc[mi][ni] = (floatx4){0.f, 0.f, 0.f, 0.f};

  // prologue: stage K-tiles 0,1,2 (NT >= 32 always here)
  #pragma unroll
  for (int p = 0; p < 3; p++) {
    #pragma unroll
    for (int j = 0; j < LA; j++) gl_lds16(srcA[j] + p * 32, SAu + p * (BM * 32) + (wave * (64 * LA) + j * 64) * 8);
    #pragma unroll
    for (int j = 0; j < 2; j++)  gl_lds16(srcB[j] + p * 32, SBu + p * (256 * 32) + (wave * 128 + j * 64) * 8);
  }
  if constexpr (MW == 8) asm volatile("s_waitcnt vmcnt(8)" ::: "memory");
  else                   asm volatile("s_waitcnt vmcnt(6)" ::: "memory");
  __builtin_amdgcn_s_barrier();
  asm volatile("" ::: "memory");

  for (int kt = 0; kt < NT; kt++) {
    const ushort* sa = SAu + (kt & 3) * (BM * 32);
    const ushort* sb = SBu + (kt & 3) * (256 * 32);
    const bool pf = (kt + 3 < NT);
    const int kp = (kt + 3) * 32, pb = (kt + 3) & 3;

    // ---------- phase A ----------
    short8 aA[AHI], bb[4];
    #pragma unroll
    for (int i = 0; i < AHI; i++) aA[i] = *(const short8*)&sa[offA[i]];
    #pragma unroll
    for (int ni = 0; ni < 4; ni++) bb[ni] = *(const short8*)&sb[offB[ni]];
    if (pf) {
      if constexpr (MW == 8) {
        gl_lds16(srcA[0] + kp, SAu + pb * (BM * 32) + (wave * 128 + 0) * 8);
        gl_lds16(srcA[1] + kp, SAu + pb * (BM * 32) + (wave * 128 + 64) * 8);
      } else {
        gl_lds16(srcA[0] + kp, SAu + pb * (BM * 32) + (wave * 64) * 8);
        gl_lds16(srcB[0] + kp, SBu + pb * (256 * 32) + (wave * 128 + 0) * 8);
      }
    }
    __builtin_amdgcn_s_barrier();
    __builtin_amdgcn_sched_barrier(0);             // pin: MFMA cluster stays below leading barrier
    __builtin_amdgcn_s_setprio(1);
    #pragma unroll
    for (int mi = 0; mi < AHI; mi++)
      #pragma unroll
      for (int ni = 0; ni < 4; ni++)
        acc[mi][ni] = __builtin_amdgcn_mfma_f32_16x16x32_bf16(aA[mi], bb[ni], acc[mi][ni], 0, 0, 0);
    __builtin_amdgcn_s_setprio(0);
    __builtin_amdgcn_sched_barrier(0);
    __builtin_amdgcn_s_barrier();
    asm volatile("" ::: "memory");

    // ---------- phase B ----------
    short8 aB[MW - AHI];
    #pragma unroll
    for (int i = 0; i < MW - AHI; i++) aB[i] = *(const short8*)&sa[offA[AHI + i]];
    if (pf) {
      if constexpr (MW == 8) {
        gl_lds16(srcB[0] + kp, SBu + pb * (256 * 32) + (wave * 128 + 0) * 8);
        gl_lds16(srcB[1] + kp, SBu + pb * (256 * 32) + (wave * 128 + 64) * 8);
      } else {
        gl_lds16(srcB[1] + kp, SBu + pb * (256 * 32) + (wave * 128 + 64) * 8);
      }
    }
    // counted wait validating kt+1 (allowed = L*[kt+2<NT] + L*[kt+3<NT])
    if (kt + 3 < NT) {
      if constexpr (MW == 8) asm volatile("s_waitcnt vmcnt(8)" ::: "memory");
      else                   asm volatile("s_waitcnt vmcnt(6)" ::: "memory");
    } else if (kt + 2 < NT) {
      if constexpr (MW == 8) asm volatile("s_waitcnt vmcnt(4)" ::: "memory");
      else                   asm volatile("s_waitcnt vmcnt(3)" ::: "memory");
    } else if (kt + 1 < NT) {
      asm volatile("s_waitcnt vmcnt(0)" ::: "memory");
    }
    __builtin_amdgcn_s_barrier();
    __builtin_amdgcn_sched_barrier(0);             // pin: MFMA cluster stays below leading barrier
    __builtin_amdgcn_s_setprio(1);
    #pragma unroll
    for (int mi = 0; mi < MW - AHI; mi++)
      #pragma unroll
      for (int ni = 0; ni < 4; ni++)
        acc[AHI + mi][ni] = __builtin_amdgcn_mfma_f32_16x16x32_bf16(aB[mi], bb[ni], acc[AHI + mi][ni], 0, 0, 0);
    __builtin_amdgcn_s_setprio(0);
    __builtin_amdgcn_sched_barrier(0);
    __builtin_amdgcn_s_barrier();
    asm volatile("" ::: "memory");
  }

  const int hi4 = (lane >> 4) * 4;

  if (mode == 1) {
    // scalar float RMW (64 B contiguous per quarter-wave; was clean in baseline)
    #pragma unroll
    for (int mi = 0; mi < MW; mi++) {
      #pragma unroll
      for (int ni = 0; ni < 4; ni++) {
        int col = n0 + wn * 64 + ni * 16 + lr;
        float bv = bu2f(bias[col]);
        #pragma unroll
        for (int q = 0; q < 4; q++) {
          int r2 = m0 + wm * (MW * 16) + mi * 16 + hi4 + q;
          Cf[(size_t)r2 * N + col] += acc[mi][ni][q] + bv;
        }
      }
    }
  } else {
    // LDS-bounce epilogue: acc -> swizzled LDS -> coalesced dwordx4 stores.
    ushort* reg0 = (MW == 8) ? SAu : SBu;
    ushort* reg1 = SBu;
    #pragma unroll
    for (int mi = 0; mi < MW; mi++) {
      #pragma unroll
      for (int ni = 0; ni < 4; ni++) {
        int colw = wn * 64 + ni * 16 + lr;            // 0..255
        float bv = (mode == 2) ? bu2f(bias[n0 + colw]) : 0.f;
        #pragma unroll
        for (int q = 0; q < 4; q++) {
          int grow = wm * (MW * 16) + mi * 16 + hi4 + q;   // 0..BM-1
          ushort* reg = (grow < 128) ? reg0 : reg1;
          int rl = grow & 127;
          float val = acc[mi][ni][q];
          ushort h = (mode == 2) ? f2bu(fast_gelu(val + bv)) : f2bu(val);
          reg[rl * 256 + (((colw >> 3) ^ (rl & 7)) * 8) + (colw & 7)] = h;
        }
      }
    }
    __syncthreads();
    {
      const int j = tid & 31;
      const int rsub = tid >> 5;     // 0..15
      #pragma unroll
      for (int p = 0; p < BM / 16; p++) {
        int row = p * 16 + rsub;
        const ushort* reg = (row < 128) ? reg0 : reg1;
        int rl = row & 127;
        short8 v = *(const short8*)&reg[rl * 256 + ((j ^ (rl & 7)) * 8)];
        *(short8*)&Cb[(size_t)(m0 + row) * N + n0 + j * 8] = v;
      }
    }
    if (mode == 5) {
      __syncthreads();
      #pragma unroll
      for (int mi = 0; mi < MW; mi++) {
        #pragma unroll
        for (int ni = 0; ni < 4; ni++) {
          int colw = wn * 64 + ni * 16 + lr;
          #pragma unroll
          for (int q = 0; q < 4; q++) {
            int grow = wm * (MW * 16) + mi * 16 + hi4 + q;
            ushort* reg = (grow < 128) ? reg0 : reg1;
            int rl = grow & 127;
            float val = acc[mi][ni][q];
            ushort h = f2bu(val);
            reg[rl * 256 + (((colw >> 3) ^ (rl & 7)) * 8) + (colw & 7)] = f2bu(val - bu2f(h));
          }
        }
      }
      __syncthreads();
      const int j = tid & 31;
      const int rsub = tid >> 5;
      #pragma unroll
      for (int p = 0; p < BM / 16; p++) {
        int row = p * 16 + rsub;
        const ushort* reg = (row < 128) ? reg0 : reg1;
        int rl = row & 127;
        short8 v = *(const short8*)&reg[rl * 256 + ((j ^ (rl & 7)) * 8)];
        *(short8*)&Cb2[(size_t)(m0 + row) * N + n0 + j * 8] = v;
      }
    }
  }
  (void)M;
}

// ---------------- m201-style 8-phase 256x256/BK=64 GEMM (mode 2 only: bf16 gelu out) ----------------
// 512 thr = 8 waves (2M x 4N), per-wave 128x64 output. 2 LDS dbufs (dbuf d holds
// K-tile of parity d). Per K-tile 4 phases: P1: mi0-3 x kk0, P2: mi0-3 x kk1,
// P3: mi4-7 x kk0 (B kept in regs), P4: mi4-7 x kk1.
// A staged as row-quadrant pairs (q0 = rows {0-63,128-191} = mi0-3 of both wave bands;
// q1 = rows {64-127,192-255}); B staged as n-halves. Stage slots chosen so each target
// region was fully read >=1 barrier earlier:
//   ph1: B-h1(d1,kb+1)  ph2: A-q1(d1,kb+1)  ph3: A-q0(d0,kb+2)  ph4: B-h0(d0,kb+2)
//   ph5: B-h1(d0,kb+2)  ph6: A-q1(d0,kb+2)  ph7: A-q0(d1,kb+3)  ph8: B-h0(d1,kb+3)
// Counted vmcnt BEFORE the trailing barrier (cross-wave safe): ph4 vmcnt(6) [lands
// d1 B-h1 + prologue d1 A-q0/B-h0 for ph5]; ph6 vmcnt(8) [ph2's A-q1 for ph7];
// ph8 vmcnt(4) [all d0 kb+2 for next ph1-4]. Steady-state invariant: 4 outstanding.
// Tail stages past NT are address-clamped dummies into dead regions (uniform counts).
// LDS swizzle: slot c of row r holds global chunk c ^ (r&7); reads XOR the same.
__global__ __launch_bounds__(512, 2) void k_gemm3(const ushort* __restrict__ A, const ushort* __restrict__ Bt,
                                                  const ushort* __restrict__ bias, ushort* __restrict__ Cb,
                                                  int M, int N, int K) {
  __shared__ alignas(16) ushort SA[2 * 256 * 64];   // 64 KB
  __shared__ alignas(16) ushort SB[2 * 256 * 64];   // 64 KB
  const int tid  = threadIdx.x;
  const int lane = tid & 63, wave = tid >> 6;
  const int lr = lane & 15, g = lane >> 4;
  const int wm = wave >> 2, wn = wave & 3;

  const int nbx = gridDim.x;
  const int nwg = nbx * gridDim.y;
  const int bid = blockIdx.y * nbx + blockIdx.x;
  const int swz = (bid & 7) * (nwg >> 3) + (bid >> 3);
  const int m0 = (swz / nbx) * 256;
  const int n0 = (swz % nbx) * 256;
  const int NT = K >> 6;           // K-tiles of 64
  const int NI = NT >> 1;

  // staging sources (per-lane, source-side chunk swizzle)
  const int chAr = (wave * 64 + lane) >> 3;       // 0..63
  const int chAs = (wave * 64 + lane) & 7;
  const int swA  = (chAs ^ (chAr & 7)) * 8;
  const ushort* sAq[2][2];   // [q][j]: rows q*64 + j*128 + chAr
  #pragma unroll
  for (int q = 0; q < 2; q++)
    #pragma unroll
    for (int j = 0; j < 2; j++)
      sAq[q][j] = A + (size_t)(m0 + q * 64 + j * 128 + chAr) * K + swA;
  const int chBr = lane >> 3;                     // 0..7
  const int swB  = ((lane & 7) ^ chBr) * 8;
  const ushort* sBh[2][2];   // [h][j]: rows h*128 + wave*16 + j*8 + chBr
  #pragma unroll
  for (int h = 0; h < 2; h++)
    #pragma unroll
    for (int j = 0; j < 2; j++)
      sBh[h][j] = Bt + (size_t)(n0 + h * 128 + wave * 16 + j * 8 + chBr) * K + swB;

  // fragment read offsets
  int rA[8], rB[4], cK[2];
  #pragma unroll
  for (int mi = 0; mi < 8; mi++) rA[mi] = (wm * 128 + mi * 16 + lr) * 64;
  #pragma unroll
  for (int ni = 0; ni < 4; ni++) rB[ni] = (wn * 64 + ni * 16 + lr) * 64;
  cK[0] = ((0 * 4 + g) ^ (lr & 7)) * 8;
  cK[1] = ((1 * 4 + g) ^ (lr & 7)) * 8;

  floatx4 acc[8][4];
  #pragma unroll
  for (int mi = 0; mi < 8; mi++)
    #pragma unroll
    for (int ni = 0; ni < 4; ni++) acc[mi][ni] = (floatx4){0.f, 0.f, 0.f, 0.f};

#define G3_STG_A(d, q, kt) { int ko = ((kt) < NT ? (kt) : 0) << 6; \
    gl_lds16(sAq[q][0] + ko, SA + (d) * 16384 + ((q) * 64 + wave * 8) * 64); \
    gl_lds16(sAq[q][1] + ko, SA + (d) * 16384 + (128 + (q) * 64 + wave * 8) * 64); }
#define G3_STG_B(d, h, kt) { int ko = ((kt) < NT ? (kt) : 0) << 6; \
    gl_lds16(sBh[h][0] + ko, SB + (d) * 16384 + ((h) * 128 + wave * 16) * 64); \
    gl_lds16(sBh[h][1] + ko, SB + (d) * 16384 + ((h) * 128 + wave * 16 + 8) * 64); }
#define G3_RD_A(dst, d, kk, mb) { _Pragma("unroll") \
    for (int _m = 0; _m < 4; _m++) dst[_m] = *(const short8*)&SA[(d) * 16384 + rA[(mb) + _m] + cK[kk]]; }
#define G3_RD_B(dst, d, kk) { _Pragma("unroll") \
    for (int _n = 0; _n < 4; _n++) dst[_n] = *(const short8*)&SB[(d) * 16384 + rB[_n] + cK[kk]]; }
#define G3_MM(mb, af, bf) { \
    __builtin_amdgcn_s_setprio(1); \
    _Pragma("unroll") for (int _m = 0; _m < 4; _m++) \
      _Pragma("unroll") for (int _n = 0; _n < 4; _n++) \
        acc[(mb) + _m][_n] = __builtin_amdgcn_mfma_f32_16x16x32_bf16(af[_m], bf[_n], acc[(mb) + _m][_n], 0, 0, 0); \
    __builtin_amdgcn_s_setprio(0); }
#define G3_BAR()  __builtin_amdgcn_s_barrier()
#define G3_SB()   __builtin_amdgcn_sched_barrier(0)

  // prologue: K0 fully (A-q0, A-q1, B-h0, B-h1 -> d0), K1's A-q0, B-h0 -> d1
  G3_STG_A(0, 0, 0); G3_STG_A(0, 1, 0); G3_STG_B(0, 0, 0); G3_STG_B(0, 1, 0);
  G3_STG_A(1, 0, 1); G3_STG_B(1, 0, 1);
  asm volatile("s_waitcnt vmcnt(4)" ::: "memory");   // all K0 landed
  G3_BAR();
  asm volatile("" ::: "memory");

  for (int i = 0; i < NI; i++) {
    const int kb = 2 * i;
    short8 aA[4], bb0[4], bb1[4];
    // ph1: mi0-3 x kk0 (d0)
    G3_RD_A(aA, 0, 0, 0); G3_RD_B(bb0, 0, 0); G3_STG_B(1, 1, kb + 1);
    G3_BAR(); G3_SB();
    G3_MM(0, aA, bb0);
    G3_SB(); G3_BAR(); asm volatile("" ::: "memory");
    // ph2: mi0-3 x kk1 (d0)
    G3_RD_A(aA, 0, 1, 0); G3_RD_B(bb1, 0, 1); G3_STG_A(1, 1, kb + 1);
    G3_BAR(); G3_SB();
    G3_MM(0, aA, bb1);
    G3_SB(); G3_BAR(); asm volatile("" ::: "memory");
    // ph3: mi4-7 x kk0 (d0)
    G3_RD_A(aA, 0, 0, 4); G3_STG_A(0, 0, kb + 2);
    G3_BAR(); G3_SB();
    G3_MM(4, aA, bb0);
    G3_SB(); G3_BAR(); asm volatile("" ::: "memory");
    // ph4: mi4-7 x kk1 (d0); vmcnt(6) lands ph1's B-h1 + prologue d1 A-q0/B-h0 for ph5
    G3_RD_A(aA, 0, 1, 4); G3_STG_B(0, 0, kb + 2);
    G3_BAR(); G3_SB();
    G3_MM(4, aA, bb1);
    G3_SB();
    asm volatile("s_waitcnt vmcnt(6)" ::: "memory");
    G3_BAR(); asm volatile("" ::: "memory");
    // ph5: mi0-3 x kk0 (d1)
    G3_RD_A(aA, 1, 0, 0); G3_RD_B(bb0, 1, 0); G3_STG_B(0, 1, kb + 2);
    G3_BAR(); G3_SB();
    G3_MM(0, aA, bb0);
    G3_SB(); G3_BAR(); asm volatile("" ::: "memory");
    // ph6: mi0-3 x kk1 (d1); vmcnt(8) lands ph2's A-q1 for ph7
    G3_RD_A(aA, 1, 1, 0); G3_RD_B(bb1, 1, 1); G3_STG_A(0, 1, kb + 2);
    G3_BAR(); G3_SB();
    G3_MM(0, aA, bb1);
    G3_SB();
    asm volatile("s_waitcnt vmcnt(8)" ::: "memory");
    G3_BAR(); asm volatile("" ::: "memory");
    // ph7: mi4-7 x kk0 (d1)
    G3_RD_A(aA, 1, 0, 4); G3_STG_A(1, 0, kb + 3);
    G3_BAR(); G3_SB();
    G3_MM(4, aA, bb0);
    G3_SB(); G3_BAR(); asm volatile("" ::: "memory");
    // ph8: mi4-7 x kk1 (d1); vmcnt(4) lands all d0 (kb+2) for next ph1-4
    G3_RD_A(aA, 1, 1, 4); G3_STG_B(1, 0, kb + 3);
    G3_BAR(); G3_SB();
    G3_MM(4, aA, bb1);
    G3_SB();
    asm volatile("s_waitcnt vmcnt(4)" ::: "memory");
    G3_BAR(); asm volatile("" ::: "memory");
  }

  // drain dummy prefetches before reusing LDS
  asm volatile("s_waitcnt vmcnt(0)" ::: "memory");
  __syncthreads();

  // LDS-bounce epilogue (gelu(val + bias) -> bf16, coalesced stores)
  const int hi4 = (lane >> 4) * 4;
  ushort* reg0 = SA;
  ushort* reg1 = SB;
  #pragma unroll
  for (int mi = 0; mi < 8; mi++) {
    #pragma unroll
    for (int ni = 0; ni < 4; ni++) {
      int colw = wn * 64 + ni * 16 + lr;
      float bv = bu2f(bias[n0 + colw]);
      #pragma unroll
      for (int q = 0; q < 4; q++) {
        int grow = wm * 128 + mi * 16 + hi4 + q;
        ushort* reg = (grow < 128) ? reg0 : reg1;
        int rl = grow & 127;
        reg[rl * 256 + (((colw >> 3) ^ (rl & 7)) * 8) + (colw & 7)] = f2bu(fast_gelu(acc[mi][ni][q] + bv));
      }
    }
  }
  __syncthreads();
  {
    const int j = tid & 31;
    const int rsub = tid >> 5;
    #pragma unroll
    for (int p = 0; p < 16; p++) {
      int row = p * 16 + rsub;
      const ushort* reg = (row < 128) ? reg0 : reg1;
      int rl = row & 127;
      short8 v = *(const short8*)&reg[rl * 256 + ((j ^ (rl & 7)) * 8)];
      *(short8*)&Cb[(size_t)(m0 + row) * N + n0 + j * 8] = v;
    }
  }
  (void)M;
#undef G3_STG_A
#undef G3_STG_B
#undef G3_RD_A
#undef G3_RD_B
#undef G3_MM
#undef G3_BAR
#undef G3_SB
}

// ---------------- MFMA bucket: consumes qk hi/lo bf16 planes; in-register first-max argmax ----------------
__global__ __launch_bounds__(256) void k_bucket_mfma(const ushort* __restrict__ qkh, const ushort* __restrict__ qkl,
                                                     const ushort* __restrict__ rotT, int* __restrict__ bkt) {
  __shared__ alignas(16) ushort Bs[128*128];  // rotT [n][k]  32 KB
  __shared__ alignas(16) ushort Ah[64*128];   // Q hi         16 KB
  __shared__ alignas(16) ushort Al[64*128];   // Q lo         16 KB
  const int tid = threadIdx.x;
  const int lane = tid & 63, wave = tid >> 6;
  const int lr = lane & 15, lk = (lane >> 4) * 8;
  const int tt = blockIdx.x * 64;
  const int bh = blockIdx.y;
  const int b = bh >> 3, hh = bh & 7;

  {
    int r = tid >> 2, c0 = (tid & 3) * 32;
    size_t base = ((size_t)(b * kT + tt + r)) * kDim + hh * 128 + c0;
    const uint4* sh = (const uint4*)(qkh + base);
    const uint4* sl = (const uint4*)(qkl + base);
    uint4* dh = (uint4*)&Ah[r * 128 + c0];
    uint4* dl = (uint4*)&Al[r * 128 + c0];
    #pragma unroll
    for (int i = 0; i < 4; i++) { dh[i] = sh[i]; dl[i] = sl[i]; }
  }
  {
    const uint4* src = (const uint4*)rotT;
    uint4* dst = (uint4*)Bs;
    for (int i = tid; i < 2048; i += 256) dst[i] = src[i];
  }
  __syncthreads();

  floatx4 acc[4][2];
  #pragma unroll
  for (int mi = 0; mi < 4; mi++) { acc[mi][0] = (floatx4){0,0,0,0}; acc[mi][1] = (floatx4){0,0,0,0}; }
  #pragma unroll
  for (int ks = 0; ks < 4; ks++) {
    short8 a[4], bb[2];
    #pragma unroll
    for (int ni = 0; ni < 2; ni++) bb[ni] = *(const short8*)&Bs[(wave*32 + ni*16 + lr)*128 + ks*32 + lk];
    #pragma unroll
    for (int mi = 0; mi < 4; mi++) a[mi] = *(const short8*)&Ah[(mi*16 + lr)*128 + ks*32 + lk];
    #pragma unroll
    for (int mi = 0; mi < 4; mi++)
      #pragma unroll
      for (int ni = 0; ni < 2; ni++)
        acc[mi][ni] = __builtin_amdgcn_mfma_f32_16x16x32_bf16(a[mi], bb[ni], acc[mi][ni], 0, 0, 0);
  }
  #pragma unroll
  for (int ks = 0; ks < 4; ks++) {
    short8 a[4], bb[2];
    #pragma unroll
    for (int ni = 0; ni < 2; ni++) bb[ni] = *(const short8*)&Bs[(wave*32 + ni*16 + lr)*128 + ks*32 + lk];
    #pragma unroll
    for (int mi = 0; mi < 4; mi++) a[mi] = *(const short8*)&Al[(mi*16 + lr)*128 + ks*32 + lk];
    #pragma unroll
    for (int mi = 0; mi < 4; mi++)
      #pragma unroll
      for (int ni = 0; ni < 2; ni++)
        acc[mi][ni] = __builtin_amdgcn_mfma_f32_16x16x32_bf16(a[mi], bb[ni], acc[mi][ni], 0, 0, 0);
  }

  #pragma unroll
  for (int mi = 0; mi < 4; mi++) {
    #pragma unroll
    for (int q = 0; q < 4; q++) {
      float v0 = acc[mi][0][q];
      float v1 = acc[mi][1][q];
      float best = v0; int bidx = lr;
      if (v1  > best) { best = v1;  bidx = 16 + lr; }
      if (-v0 > best) { best = -v0; bidx = 32 + lr; }
      if (-v1 > best) { best = -v1; bidx = 48 + lr; }
      #pragma unroll
      for (int m = 1; m <= 8; m <<= 1) {
        float ov = __shfl_xor(best, m);
        int   oi = __shfl_xor(bidx, m);
        if (ov > best || (ov == best && oi < bidx)) { best = ov; bidx = oi; }
      }
      if (lr == 0) {
        int row = mi*16 + ((lane >> 4) & 3)*4 + q;
        bkt[(bh*4 + wave)*4096 + tt + row] = bidx;
      }
    }
  }
}

// ---------------- stable counting sort per (bh,hash) ----------------
__global__ __launch_bounds__(256) void k_sort(const int* __restrict__ bkt, int* __restrict__ st) {
  __shared__ unsigned char  hist[64*256];
  __shared__ unsigned short offs[64*256];
  __shared__ int base[64];
  int tid = threadIdx.x, grp = blockIdx.x;
  const int* bk = bkt + grp * 4096;
  for (int i = tid; i < 64*256; i += 256) hist[i] = 0;
  __syncthreads();
  int myb[16];
  #pragma unroll
  for (int j = 0; j < 16; j++) {
    myb[j] = bk[tid*16 + j];
    hist[myb[j]*256 + tid] += 1;
  }
  __syncthreads();
  if (tid < 64) {
    int run = 0;
    for (int t = 0; t < 256; t++) { offs[tid*256 + t] = (unsigned short)run; run += hist[tid*256 + t]; }
    base[tid] = run;
  }
  __syncthreads();
  if (tid == 0) {
    int run = 0;
    for (int b2 = 0; b2 < 64; b2++) { int c = base[b2]; base[b2] = run; run += c; }
  }
  __syncthreads();
  #pragma unroll
  for (int j = 0; j < 16; j++) {
    int b2 = myb[j];
    int r = 0;
    for (int jj = 0; jj < j; jj++) r += (myb[jj] == b2) ? 1 : 0;
    st[grp*4096 + base[b2] + (int)offs[b2*256 + tid] + r] = tid*16 + j;
  }
}

// ---------------- chunked LSH attention (bf16 qk hi-plane input) ----------------
__global__ __launch_bounds__(256) void k_attn(const ushort* __restrict__ qkh, const ushort* __restrict__ vbuf,
                                              const int* __restrict__ st, ushort* __restrict__ o_r,
                                              float* __restrict__ lse_r) {
  __shared__ alignas(16) ushort KV[128*136];
  __shared__ alignas(16) ushort Ps[64*136];
  __shared__ float rnorm[128];
  __shared__ int   kposs[128];
  __shared__ float red1[64*4];
  __shared__ float red2[64*4];
  __shared__ float lrow[64];

  const int tid = threadIdx.x;
  const int bid = blockIdx.x;
  const int bh = bid >> 8;
  const int c  = bid & 255;
  const int h  = c >> 6;
  const int cprev = (c + 255) & 255;
  const int b  = bh >> 3, hh = bh & 7;
  const int lane = tid & 63, wave = tid >> 6;
  const int lr = lane & 15, lk = (lane >> 4) * 8;

  {
    int j = tid >> 1, half = tid & 1;
    int slot = (j < 64) ? (c*64 + j) : (cprev*64 + (j - 64));
    int pos = st[bh*16384 + slot];
    if (half == 0) kposs[j] = pos;
    const ushort* src = qkh + ((size_t)(b * kT + pos)) * kDim + hh*128 + half*64;
    float ss = 0.f;
    #pragma unroll
    for (int i2 = 0; i2 < 64; i2 += 8) {
      uint4 u = *(const uint4*)(src + i2);
      *(uint4*)&KV[j*136 + half*64 + i2] = u;
      float f0 = bu2f((ushort)(u.x & 0xffffu)), f1 = bu2f((ushort)(u.x >> 16));
      float f2 = bu2f((ushort)(u.y & 0xffffu)), f3 = bu2f((ushort)(u.y >> 16));
      float f4 = bu2f((ushort)(u.z & 0xffffu)), f5 = bu2f((ushort)(u.z >> 16));
      float f6 = bu2f((ushort)(u.w & 0xffffu)), f7 = bu2f((ushort)(u.w >> 16));
      ss += f0*f0 + f1*f1 + f2*f2 + f3*f3 + f4*f4 + f5*f5 + f6*f6 + f7*f7;
    }
    ss += __shfl_xor(ss, 1);
    if (half == 0) rnorm[j] = 1.f / fmaxf(sqrtf(ss), 1e-12f);
  }
  __syncthreads();

  {
    floatx4 acc[4][2];
    #pragma unroll
    for (int mi = 0; mi < 4; mi++) { acc[mi][0] = (floatx4){0,0,0,0}; acc[mi][1] = (floatx4){0,0,0,0}; }
    #pragma unroll
    for (int ks = 0; ks < 4; ks++) {
      short8 a[4], bb[2];
      #pragma unroll
      for (int mi = 0; mi < 4; mi++) a[mi]  = *(const short8*)&KV[(mi*16 + lr)*136 + ks*32 + lk];
      #pragma unroll
      for (int ni = 0; ni < 2; ni++) bb[ni] = *(const short8*)&KV[(wave*32 + ni*16 + lr)*136 + ks*32 + lk];
      #pragma unroll
      for (int mi = 0; mi < 4; mi++)
        #pragma unroll
        for (int ni = 0; ni < 2; ni++)
          acc[mi][ni] = __builtin_amdgcn_mfma_f32_16x16x32_bf16(a[mi], bb[ni], acc[mi][ni], 0, 0, 0);
    }
    #pragma unroll
    for (int mi = 0; mi < 4; mi++) {
      #pragma unroll
      for (int ni = 0; ni < 2; ni++) {
        int col = wave*32 + ni*16 + lr;
        float rn = rnorm[col] * kScale;
        int cpos = kposs[col];
        #pragma unroll
        for (int q = 0; q < 4; q++) {
          int row = mi*16 + (lane >> 4)*4 + q;
          float val = acc[mi][ni][q] * rn;
          if (cpos == kposs[row]) val = kSelfVal;
          Ps[row*136 + col] = f2bu(val);
        }
      }
    }
  }
  __syncthreads();

  {
    int j = tid >> 1, half = tid & 1;
    int pos = kposs[j];
    const ushort* src = vbuf + ((size_t)(b * kT + pos)) * kDim + hh*128 + half*64;
    #pragma unroll
    for (int i2 = 0; i2 < 64; i2 += 8) {
      uint4 u = *(const uint4*)(src + i2);
      int d0 = half*64 + i2;
      KV[(d0+0)*136 + j] = (ushort)(u.x & 0xffffu); KV[(d0+1)*136 + j] = (ushort)(u.x >> 16);
      KV[(d0+2)*136 + j] = (ushort)(u.y & 0xffffu); KV[(d0+3)*136 + j] = (ushort)(u.y >> 16);
      KV[(d0+4)*136 + j] = (ushort)(u.z & 0xffffu); KV[(d0+5)*136 + j] = (ushort)(u.z >> 16);
      KV[(d0+6)*136 + j] = (ushort)(u.w & 0xffffu); KV[(d0+7)*136 + j] = (ushort)(u.w >> 16);
    }
  }

  {
    int i = tid >> 2, part = tid & 3;
    const int jb = part * 32;
    float m = -1e30f;
    for (int j2 = 0; j2 < 32; j2++) m = fmaxf(m, bu2f(Ps[i*136 + jb + j2]));
    red1[i*4 + part] = m;
    __syncthreads();
    m = fmaxf(fmaxf(red1[i*4+0], red1[i*4+1]), fmaxf(red1[i*4+2], red1[i*4+3]));
    float ssum = 0.f;
    for (int j2 = 0; j2 < 32; j2++) {
      float arg = fmaxf(fminf(bu2f(Ps[i*136 + jb + j2]) - m, 0.f), -80.f);
      float p = __expf(arg);
      ssum += p;
      Ps[i*136 + jb + j2] = f2bu(p);
    }
    red2[i*4 + part] = ssum;
    __syncthreads();
    if (part == 0) {
      float l = fmaxf(red2[i*4+0] + red2[i*4+1] + red2[i*4+2] + red2[i*4+3], 1e-20f);
      lrow[i] = 1.f / l;
      lse_r[(size_t)(bh*4 + h)*4096 + kposs[i]] = m + __logf(l);
    }
  }
  __syncthreads();

  {
    floatx4 acc[4][2];
    #pragma unroll
    for (int mi = 0; mi < 4; mi++) { acc[mi][0] = (floatx4){0,0,0,0}; acc[mi][1] = (floatx4){0,0,0,0}; }
    #pragma unroll
    for (int ks = 0; ks < 4; ks++) {
      short8 a[4], bb[2];
      #pragma unroll
      for (int mi = 0; mi < 4; mi++) a[mi]  = *(const short8*)&Ps[(mi*16 + lr)*136 + ks*32 + lk];
      #pragma unroll
      for (int ni = 0; ni < 2; ni++) bb[ni] = *(const short8*)&KV[(wave*32 + ni*16 + lr)*136 + ks*32 + lk];
      #pragma unroll
      for (int mi = 0; mi < 4; mi++)
        #pragma unroll
        for (int ni = 0; ni < 2; ni++)
          acc[mi][ni] = __builtin_amdgcn_mfma_f32_16x16x32_bf16(a[mi], bb[ni], acc[mi][ni], 0, 0, 0);
    }
    #pragma unroll
    for (int mi = 0; mi < 4; mi++) {
      #pragma unroll
      for (int ni = 0; ni < 2; ni++) {
        int d = wave*32 + ni*16 + lr;
        #pragma unroll
        for (int q = 0; q < 4; q++) {
          int row = mi*16 + (lane >> 4)*4 + q;
          float o = acc[mi][ni][q] * lrow[row];
          o_r[((size_t)(bh*4 + h)*4096 + kposs[row])*128 + d] = f2bu(o);
        }
      }
    }
  }
}

// ---------------- combine hash rounds ----------------
__global__ __launch_bounds__(256) void k_combine(const ushort* __restrict__ o_r, const float* __restrict__ lse_r,
                                                 ushort* __restrict__ attnbf) {
  int rid = blockIdx.x * 2 + (threadIdx.x >> 7);
  int d = threadIdx.x & 127;
  int bh = rid >> 12, t = rid & 4095;
  int b = bh >> 3, hh = bh & 7;
  size_t base = (size_t)bh * 16384 + t;
  float l0 = lse_r[base], l1 = lse_r[base + 4096], l2 = lse_r[base + 8192], l3 = lse_r[base + 12288];
  float M = fmaxf(fmaxf(l0, l1), fmaxf(l2, l3));
  float e0 = __expf(fmaxf(fminf(l0 - M, 0.f), -80.f));
  float e1 = __expf(fmaxf(fminf(l1 - M, 0.f), -80.f));
  float e2 = __expf(fmaxf(fminf(l2 - M, 0.f), -80.f));
  float e3 = __expf(fmaxf(fminf(l3 - M, 0.f), -80.f));
  float inv = 1.f / (e0 + e1 + e2 + e3);
  float o = e0 * bu2f(o_r[(base         )*128 + d]) + e1 * bu2f(o_r[(base +  4096)*128 + d])
          + e2 * bu2f(o_r[(base +  8192)*128 + d]) + e3 * bu2f(o_r[(base + 12288)*128 + d]);
  attnbf[((size_t)b * kT + t) * kDim + hh*128 + d] = f2bu(o * inv);
}

extern "C" void kernel_launch(void* const* d_in, const int* in_sizes, int n_in,
                              void* d_out, int out_size, void* d_ws, size_t ws_size,
                              hipStream_t stream) {
  (void)in_sizes; (void)n_in; (void)out_size; (void)ws_size;
  const void* x     = d_in[0];
  const void* ln1_g = d_in[1];
  const void* ln1_b = d_in[2];
  const void* Wqk   = d_in[3];
  const void* Wv    = d_in[4];
  const void* Wo    = d_in[5];
  const void* bo    = d_in[6];
  const void* ln2_g = d_in[7];
  const void* ln2_b = d_in[8];
  const void* W1    = d_in[9];
  const void* b1    = d_in[10];
  const void* W2    = d_in[11];
  const void* b2    = d_in[12];
  const void* rot   = d_in[13];

  char* w = (char*)d_ws;
  int*    flag = (int*)w;    w += 256;
  ushort* prm  = (ushort*)w; w += 131072;
  float* x1  = (float*)w;  w += 33554432;
  float* x2  = (float*)w;  w += 33554432;
  ushort* qkh = (ushort*)w; w += 16777216;
  ushort* qkl = (ushort*)w; w += 16777216;
  ushort* vbb = (ushort*)w; w += 16777216;
  ushort* xbf = (ushort*)w; w += 16777216;
  ushort* orb = (ushort*)w; w += 67108864;
  float* lse = (float*)w;  w += 1048576;
  int*   bkt = (int*)w;    w += 1048576;
  int*   stb = (int*)w;    w += 1048576;
  ushort* wtA = (ushort*)w; w += 2097152;
  ushort* wtB = (ushort*)w; w += 2097152;
  ushort* wtC = (ushort*)w; w += 2097152;
  ushort* wt1 = (ushort*)w; w += 8388608;
  ushort* wt2 = (ushort*)w; w += 8388608;
  ushort* rtT = (ushort*)w; w += 32768;

  ushort* pLN1G = prm + 0;     ushort* pLN1B = prm + 2048;
  ushort* pBO   = prm + 4096;  ushort* pLN2G = prm + 6144;
  ushort* pLN2B = prm + 8192;  ushort* pB1   = prm + 10240;
  ushort* pB2   = prm + 18432; ushort* pROT  = prm + 20480;

  k_detect<<<1, 256, 0, stream>>>((const unsigned*)x, flag);
  k_cvt<<<8,   256, 0, stream>>>(flag, ln1_g, pLN1G, 2048);
  k_cvt<<<8,   256, 0, stream>>>(flag, ln1_b, pLN1B, 2048);
  k_cvt<<<8,   256, 0, stream>>>(flag, bo,    pBO,   2048);
  k_cvt<<<8,   256, 0, stream>>>(flag, ln2_g, pLN2G, 2048);
  k_cvt<<<8,   256, 0, stream>>>(flag, ln2_b, pLN2B, 2048);
  k_cvt<<<32,  256, 0, stream>>>(flag, b1,    pB1,   8192);
  k_cvt<<<8,   256, 0, stream>>>(flag, b2,    pB2,   2048);
  k_cvt<<<128, 256, 0, stream>>>(flag, rot,   pROT,  32768);
  k_init_any<<<8192, 256, 0, stream>>>(flag, x, x1, x2);

  for (int d = 0; d < 2; d++) {
    k_transpose2<<<dim3(32, 32),  256, 0, stream>>>(flag,
        (const char*)Wqk + (size_t)d*1048576*2, (const char*)Wqk + (size_t)d*1048576*4, wtA, 1024, 1024);
    k_transpose2<<<dim3(32, 32),  256, 0, stream>>>(flag,
        (const char*)Wv  + (size_t)d*1048576*2, (const char*)Wv  + (size_t)d*1048576*4, wtB, 1024, 1024);
    k_transpose2<<<dim3(32, 32),  256, 0, stream>>>(flag,
        (const char*)Wo  + (size_t)d*1048576*2, (const char*)Wo  + (size_t)d*1048576*4, wtC, 1024, 1024);
    k_transpose2<<<dim3(128, 32), 256, 0, stream>>>(flag,
        (const char*)W1  + (size_t)d*4194304*2, (const char*)W1  + (size_t)d*4194304*4, wt1, 1024, 4096);
    k_transpose2<<<dim3(32, 128), 256, 0, stream>>>(flag,
        (const char*)W2  + (size_t)d*4194304*2, (const char*)W2  + (size_t)d*4194304*4, wt2, 4096, 1024);
    k_rot_t<<<1, 256, 0, stream>>>(pROT + (size_t)d * 16384, rtT);

    k_ln<<<8192, 256, 0, stream>>>(x2, pLN1G + d*1024, pLN1B + d*1024, xbf);
    k_gemm2<4><<<dim3(4, 64), 512, 0, stream>>>(xbf, wtA, nullptr, nullptr, qkh, qkl, 8192, 1024, 1024, 5);
    k_gemm2<4><<<dim3(4, 64), 512, 0, stream>>>(xbf, wtB, nullptr, nullptr, vbb, nullptr, 8192, 1024, 1024, 3);
    k_bucket_mfma<<<dim3(64, 16), 256, 0, stream>>>(qkh, qkl, rtT, bkt);
    k_sort<<<64, 256, 0, stream>>>(bkt, stb);
    k_attn<<<4096, 256, 0, stream>>>(qkh, vbb, stb, orb, lse);
    k_combine<<<32768, 256, 0, stream>>>(orb, lse, xbf);
    k_gemm2<4><<<dim3(4, 64), 512, 0, stream>>>(xbf, wtC, pBO + d*1024, x1, nullptr, nullptr, 8192, 1024, 1024, 1);
    k_ln<<<8192, 256, 0, stream>>>(x1, pLN2G + d*1024, pLN2B + d*1024, xbf);
    k_gemm3<<<dim3(16, 32), 512, 0, stream>>>(xbf, wt1, pB1 + d*4096, orb, 8192, 4096, 1024);
    k_gemm2<4><<<dim3(4, 64), 512, 0, stream>>>(orb, wt2, pB2 + d*1024, x2, nullptr, nullptr, 8192, 1024, 4096, 1);
  }
  k_final_any<<<8192, 256, 0, stream>>>(flag, x1, x2, d_out);
}

// Round 6
// 1111.196 us; speedup vs baseline: 1.3997x; 1.0533x over previous
//
#include <hip/hip_runtime.h>
#include <hip/hip_bf16.h>
#include <cmath>

using bf16 = __hip_bfloat16;
typedef __attribute__((ext_vector_type(8))) short short8;
typedef __attribute__((ext_vector_type(4))) float floatx4;

__device__ __forceinline__ float bu2f(ushort u) { return __uint_as_float((unsigned)u << 16); }
__device__ __forceinline__ ushort f2bu(float f) {
  union { bf16 b; ushort u; } cv; cv.b = __float2bfloat16(f); return cv.u;
}
__device__ __forceinline__ void gl_lds16(const ushort* g, ushort* l) {
  __builtin_amdgcn_global_load_lds((const __attribute__((address_space(1))) unsigned*)g,
                                   (__attribute__((address_space(3))) unsigned*)l, 16, 0, 0);
}
// tanh-form GELU via hw exp; |err vs erf-GELU| ~2e-4, below bf16 output quantization
__device__ __forceinline__ float fast_gelu(float x) {
  float z = 0.7978845608028654f * (x + 0.044715f * x * x * x);
  z = fmaxf(fminf(z, 10.f), -10.f);
  float e = __expf(2.f * z);
  float t = (e - 1.f) / (e + 1.f);
  return 0.5f * x * (1.f + t);
}

static constexpr int kT   = 4096;
static constexpr int kDim = 1024;
static constexpr float kScale   = 0.08838834764831845f;  // 1/sqrt(128)
static constexpr float kSelfVal = -5.0e4f;

// ---------------- dtype detector: bf16 vs fp32 inputs ----------------
__device__ __forceinline__ int sane_v(float f) { float a = fabsf(f); return (a > 1e-4f && a < 1e4f) ? 1 : 0; }

__global__ __launch_bounds__(256) void k_detect(const unsigned* __restrict__ x, int* __restrict__ flag) {
  __shared__ int cnt;
  int tid = threadIdx.x;
  if (tid == 0) cnt = 0;
  __syncthreads();
  int my = 0;
  const uint4* p = (const uint4*)x;
  for (int q = 0; q < 16; q++) {
    uint4 u = p[tid * 16 + q];
    my += sane_v(__uint_as_float(u.x << 16)) + sane_v(__uint_as_float(u.x & 0xffff0000u));
    my += sane_v(__uint_as_float(u.y << 16)) + sane_v(__uint_as_float(u.y & 0xffff0000u));
    my += sane_v(__uint_as_float(u.z << 16)) + sane_v(__uint_as_float(u.z & 0xffff0000u));
    my += sane_v(__uint_as_float(u.w << 16)) + sane_v(__uint_as_float(u.w & 0xffff0000u));
  }
  atomicAdd(&cnt, my);
  __syncthreads();
  if (tid == 0) flag[0] = (cnt >= 24576) ? 1 : 0;
}

__global__ __launch_bounds__(256) void k_cvt(const int* __restrict__ flag, const void* __restrict__ src,
                                             ushort* __restrict__ dst, int n) {
  int i = blockIdx.x * 256 + threadIdx.x;
  if (i >= n) return;
  dst[i] = (*flag) ? ((const ushort*)src)[i] : f2bu(((const float*)src)[i]);
}

__global__ __launch_bounds__(256) void k_init_any(const int* __restrict__ flag, const void* __restrict__ x,
                                                  float* __restrict__ x1, float* __restrict__ x2) {
  int i = blockIdx.x * 1024 + threadIdx.x * 4;
  float4 f;
  if (*flag) {
    ushort4 u = *(const ushort4*)((const ushort*)x + i);
    f.x = bu2f(u.x); f.y = bu2f(u.y); f.z = bu2f(u.z); f.w = bu2f(u.w);
  } else {
    f = *(const float4*)((const float*)x + i);
  }
  *(float4*)(x1 + i) = f;
  *(float4*)(x2 + i) = f;
}

__global__ __launch_bounds__(256) void k_final_any(const int* __restrict__ flag, const float* __restrict__ x1,
                                                   const float* __restrict__ x2, void* __restrict__ out) {
  int i = blockIdx.x * 1024 + threadIdx.x * 4;
  float4 a = *(const float4*)(x1 + i);
  float4 b = *(const float4*)(x2 + i);
  float4 s; s.x = a.x + b.x; s.y = a.y + b.y; s.z = a.z + b.z; s.w = a.w + b.w;
  if (*flag) {
    ushort4 u; u.x = f2bu(s.x); u.y = f2bu(s.y); u.z = f2bu(s.z); u.w = f2bu(s.w);
    *(ushort4*)((ushort*)out + i) = u;
  } else {
    *(float4*)((float*)out + i) = s;
  }
}

// ---------------- layernorm: fp32 in -> bf16 out ----------------
__global__ __launch_bounds__(256) void k_ln(const float* __restrict__ x, const ushort* __restrict__ g,
                                            const ushort* __restrict__ be, ushort* __restrict__ out) {
  __shared__ float ws[4], ws2[4];
  int row = blockIdx.x, tid = threadIdx.x;
  const float* xr = x + (size_t)row * kDim + tid * 4;
  float4 v = *(const float4*)xr;
  float s  = v.x + v.y + v.z + v.w;
  float s2 = v.x*v.x + v.y*v.y + v.z*v.z + v.w*v.w;
  #pragma unroll
  for (int off = 32; off; off >>= 1) { s += __shfl_down(s, off); s2 += __shfl_down(s2, off); }
  int wave = tid >> 6, lane = tid & 63;
  if (lane == 0) { ws[wave] = s; ws2[wave] = s2; }
  __syncthreads();
  s  = ws[0] + ws[1] + ws[2] + ws[3];
  s2 = ws2[0] + ws2[1] + ws2[2] + ws2[3];
  float mean = s * (1.f/1024.f);
  float var  = fmaxf(s2 * (1.f/1024.f) - mean*mean, 0.f);
  float rstd = rsqrtf(var + 1e-5f);
  int cb = tid * 4;
  ushort* o = out + (size_t)row * kDim + cb;
  o[0] = f2bu((v.x - mean) * rstd * bu2f(g[cb+0]) + bu2f(be[cb+0]));
  o[1] = f2bu((v.y - mean) * rstd * bu2f(g[cb+1]) + bu2f(be[cb+1]));
  o[2] = f2bu((v.z - mean) * rstd * bu2f(g[cb+2]) + bu2f(be[cb+2]));
  o[3] = f2bu((v.w - mean) * rstd * bu2f(g[cb+3]) + bu2f(be[cb+3]));
}

// ---------------- dual-dtype weight transpose: in[K,N] -> out[N,K] ----------------
__global__ __launch_bounds__(256) void k_transpose2(const int* __restrict__ flag, const void* __restrict__ src_bf,
                                                    const void* __restrict__ src_f, ushort* __restrict__ out,
                                                    int K, int N) {
  __shared__ ushort tile[32][33];
  int isbf = *flag;
  int nb = blockIdx.x * 32, kb = blockIdx.y * 32;
  int tx = threadIdx.x & 31, ty = threadIdx.x >> 5;
  for (int r = ty; r < 32; r += 8) {
    size_t idx = (size_t)(kb + r) * N + nb + tx;
    tile[r][tx] = isbf ? ((const ushort*)src_bf)[idx] : f2bu(((const float*)src_f)[idx]);
  }
  __syncthreads();
  for (int r = ty; r < 32; r += 8) out[(size_t)(nb + r) * K + kb + tx] = tile[tx][r];
}

// ---------------- rot transpose: rot[k=128][n=128] -> rotT[n=128][k=128] ----------------
__global__ __launch_bounds__(256) void k_rot_t(const ushort* __restrict__ rot, ushort* __restrict__ rotT) {
  int tid = threadIdx.x;
  for (int idx = tid; idx < 16384; idx += 256) {
    int n = idx >> 7, k = idx & 127;
    rotT[idx] = rot[k * 128 + n];
  }
}

// ---------------- k_gemm4: 128M x 256N, BK=64, 3-buffer rotating pipeline ----------------
// 512 thr = 8 waves (2M x 4N), wave tile 64x64. Grid (N/256, M/128) -> 256 wgs for the
// N=1024 shapes = exactly 1 block/CU (256^2 tiles would idle half the chip at N=1024).
// LDS: SA 3x[128][64] (48 KB) + SB 3x[256][64] (96 KB) = 144 KB (<=160 KB/CU, 1 block).
// Per K-tile (64): 2 phases (kk0, kk1), each {8 ds_read_b128 || 3 global_load_lds ->
// barrier -> sched_barrier -> setprio + 16 MFMA -> sched_barrier -> [vmcnt at ph_b] ->
// barrier} -> k_gemm3's MFMA-per-barrier density on the 1024-wide shapes.
// Ledger: stage kt+2 -> buf[(kt+2)%3] = buf[(kt-1)%3], fully read at end of kt-1,
// issued after kt-1 ph_b's trailing barrier (WAR-safe). vmcnt(6) before ph_b's
// TRAILING barrier validates kt+1's 6 loads (only kt's 6 newer remain; barrier then
// publishes to all waves -> cross-wave safe). Steady state: 6 outstanding. Tail stages
// past NT are address-clamped dummies into dead buffers (uniform counts); vmcnt(0) +
// syncthreads before epilogue LDS reuse. Source-side chunk swizzle: LDS slot s of row
// r holds global chunk s^(r&7); reads recover via the same XOR (2-way aliasing, free).
// mode 1: Cf += A@B + bias (scalar float RMW; measured clean, WRITE=out bytes)
// mode 3: Cb = bf16(A@B)   mode 5: Cb = hi(A@B), Cb2 = lo(A@B)  (LDS-bounce stores)
__global__ __launch_bounds__(512, 2) void k_gemm4(const ushort* __restrict__ A, const ushort* __restrict__ Bt,
                                                  const ushort* __restrict__ bias, float* __restrict__ Cf,
                                                  ushort* __restrict__ Cb, ushort* __restrict__ Cb2,
                                                  int M, int N, int K, int mode) {
  __shared__ alignas(16) ushort SA[3 * 128 * 64];   // 48 KB
  __shared__ alignas(16) ushort SB[3 * 256 * 64];   // 96 KB
  const int tid  = threadIdx.x;
  const int lane = tid & 63, wave = tid >> 6;
  const int lr = lane & 15, g = lane >> 4;
  const int wm = wave >> 2, wn = wave & 3;

  // XCD-aware bijective block swizzle (nwg = 256 here, % 8 == 0)
  const int nbx = gridDim.x;
  const int nwg = nbx * gridDim.y;
  const int bid = blockIdx.y * nbx + blockIdx.x;
  const int swz = (bid & 7) * (nwg >> 3) + (bid >> 3);
  const int m0 = (swz / nbx) * 128;
  const int n0 = (swz % nbx) * 256;
  const int NT = K >> 6;

  // staging sources: per-lane row/slot; source col chunk pre-swizzled so linear LDS
  // dest slot s receives global chunk s^(row&7)
  const int srow = (wave * 64 + lane) >> 3;           // 0..63 (local row within 64-row band)
  const int sc   = ((lane & 7) ^ (srow & 7)) * 8;     // swizzled source col (ushort units)
  const ushort* sA[2];
  #pragma unroll
  for (int j = 0; j < 2; j++) sA[j] = A + (size_t)(m0 + j * 64 + srow) * K + sc;
  const ushort* sB[4];
  #pragma unroll
  for (int h = 0; h < 4; h++) sB[h] = Bt + (size_t)(n0 + h * 64 + srow) * K + sc;

  // fragment read offsets (row&7 == lr&7 since wm*64, mi*16 are multiples of 8)
  int rA[4], rB[4], cK[2];
  #pragma unroll
  for (int mi = 0; mi < 4; mi++) rA[mi] = (wm * 64 + mi * 16 + lr) * 64;
  #pragma unroll
  for (int ni = 0; ni < 4; ni++) rB[ni] = (wn * 64 + ni * 16 + lr) * 64;
  cK[0] = ((0 * 4 + g) ^ (lr & 7)) * 8;
  cK[1] = ((1 * 4 + g) ^ (lr & 7)) * 8;

  floatx4 acc[4][4];
  #pragma unroll
  for (int mi = 0; mi < 4; mi++)
    #pragma unroll
    for (int ni = 0; ni < 4; ni++) acc[mi][ni] = (floatx4){0.f, 0.f, 0.f, 0.f};

#define G4_STG_A(bf, j, ko) gl_lds16(sA[j] + (ko), SA + (bf) * 8192  + ((j) * 64 + wave * 8) * 64)
#define G4_STG_B(bf, h, ko) gl_lds16(sB[h] + (ko), SB + (bf) * 16384 + ((h) * 64 + wave * 8) * 64)
#define G4_BAR()  __builtin_amdgcn_s_barrier()
#define G4_SB()   __builtin_amdgcn_sched_barrier(0)

  // prologue: stage K-tiles 0 and 1 fully (6 loads each)
  #pragma unroll
  for (int p = 0; p < 2; p++) {
    const int ko = p << 6;
    G4_STG_A(p, 0, ko); G4_STG_A(p, 1, ko);
    G4_STG_B(p, 0, ko); G4_STG_B(p, 1, ko); G4_STG_B(p, 2, ko); G4_STG_B(p, 3, ko);
  }
  asm volatile("s_waitcnt vmcnt(6)" ::: "memory");   // K-tile 0 landed
  G4_BAR();
  asm volatile("" ::: "memory");

  for (int kt = 0; kt < NT; kt++) {
    const int cur = kt % 3;
    const int pb  = (kt + 2) % 3;
    const int ko  = (kt + 2 < NT) ? ((kt + 2) << 6) : 0;   // dummy-clamp past NT
    const ushort* sa = SA + cur * 8192;
    const ushort* sb = SB + cur * 16384;
    short8 av[4], bv[4];

    // ---------- phase A (kk0): 16 MFMA ----------
    #pragma unroll
    for (int mi = 0; mi < 4; mi++) av[mi] = *(const short8*)&sa[rA[mi] + cK[0]];
    #pragma unroll
    for (int ni = 0; ni < 4; ni++) bv[ni] = *(const short8*)&sb[rB[ni] + cK[0]];
    G4_STG_A(pb, 0, ko); G4_STG_A(pb, 1, ko); G4_STG_B(pb, 0, ko);
    G4_BAR(); G4_SB();
    __builtin_amdgcn_s_setprio(1);
    #pragma unroll
    for (int mi = 0; mi < 4; mi++)
      #pragma unroll
      for (int ni = 0; ni < 4; ni++)
        acc[mi][ni] = __builtin_amdgcn_mfma_f32_16x16x32_bf16(av[mi], bv[ni], acc[mi][ni], 0, 0, 0);
    __builtin_amdgcn_s_setprio(0);
    G4_SB(); G4_BAR();
    asm volatile("" ::: "memory");

    // ---------- phase B (kk1): 16 MFMA; counted vmcnt validates kt+1 ----------
    #pragma unroll
    for (int mi = 0; mi < 4; mi++) av[mi] = *(const short8*)&sa[rA[mi] + cK[1]];
    #pragma unroll
    for (int ni = 0; ni < 4; ni++) bv[ni] = *(const short8*)&sb[rB[ni] + cK[1]];
    G4_STG_B(pb, 1, ko); G4_STG_B(pb, 2, ko); G4_STG_B(pb, 3, ko);
    G4_BAR(); G4_SB();
    __builtin_amdgcn_s_setprio(1);
    #pragma unroll
    for (int mi = 0; mi < 4; mi++)
      #pragma unroll
      for (int ni = 0; ni < 4; ni++)
        acc[mi][ni] = __builtin_amdgcn_mfma_f32_16x16x32_bf16(av[mi], bv[ni], acc[mi][ni], 0, 0, 0);
    __builtin_amdgcn_s_setprio(0);
    G4_SB();
    asm volatile("s_waitcnt vmcnt(6)" ::: "memory");   // kt's 6 may stay in flight
    G4_BAR();
    asm volatile("" ::: "memory");
  }

  // drain dummy prefetches before reusing LDS
  asm volatile("s_waitcnt vmcnt(0)" ::: "memory");
  __syncthreads();

  const int hi4 = (lane >> 4) * 4;

  if (mode == 1) {
    // scalar float RMW (64 B contiguous per quarter-wave; measured clean)
    #pragma unroll
    for (int mi = 0; mi < 4; mi++) {
      #pragma unroll
      for (int ni = 0; ni < 4; ni++) {
        int col = n0 + wn * 64 + ni * 16 + lr;
        float bv2 = bu2f(bias[col]);
        #pragma unroll
        for (int q = 0; q < 4; q++) {
          int r2 = m0 + wm * 64 + mi * 16 + hi4 + q;
          Cf[(size_t)r2 * N + col] += acc[mi][ni][q] + bv2;
        }
      }
    }
  } else {
    // LDS-bounce epilogue: acc -> swizzled SB (rows 0..127 x 256) -> coalesced stores
    #pragma unroll
    for (int mi = 0; mi < 4; mi++) {
      #pragma unroll
      for (int ni = 0; ni < 4; ni++) {
        int colw = wn * 64 + ni * 16 + lr;
        #pragma unroll
        for (int q = 0; q < 4; q++) {
          int grow = wm * 64 + mi * 16 + hi4 + q;   // 0..127
          SB[grow * 256 + (((colw >> 3) ^ (grow & 7)) * 8) + (colw & 7)] = f2bu(acc[mi][ni][q]);
        }
      }
    }
    __syncthreads();
    {
      const int j = tid & 31;
      const int rsub = tid >> 5;     // 0..15
      #pragma unroll
      for (int p = 0; p < 8; p++) {
        int row = p * 16 + rsub;
        short8 v = *(const short8*)&SB[row * 256 + ((j ^ (row & 7)) * 8)];
        *(short8*)&Cb[(size_t)(m0 + row) * N + n0 + j * 8] = v;
      }
    }
    if (mode == 5) {
      __syncthreads();
      // plane 1: residual lo = val - bu2f(hi)
      #pragma unroll
      for (int mi = 0; mi < 4; mi++) {
        #pragma unroll
        for (int ni = 0; ni < 4; ni++) {
          int colw = wn * 64 + ni * 16 + lr;
          #pragma unroll
          for (int q = 0; q < 4; q++) {
            int grow = wm * 64 + mi * 16 + hi4 + q;
            float val = acc[mi][ni][q];
            ushort h = f2bu(val);
            SB[grow * 256 + (((colw >> 3) ^ (grow & 7)) * 8) + (colw & 7)] = f2bu(val - bu2f(h));
          }
        }
      }
      __syncthreads();
      const int j = tid & 31;
      const int rsub = tid >> 5;
      #pragma unroll
      for (int p = 0; p < 8; p++) {
        int row = p * 16 + rsub;
        short8 v = *(const short8*)&SB[row * 256 + ((j ^ (row & 7)) * 8)];
        *(short8*)&Cb2[(size_t)(m0 + row) * N + n0 + j * 8] = v;
      }
    }
  }
  (void)M;
#undef G4_STG_A
#undef G4_STG_B
#undef G4_BAR
#undef G4_SB
}

// ---------------- m201-style 8-phase 256x256/BK=64 GEMM (mode 2 only: bf16 gelu out) ----------------
// 512 thr = 8 waves (2M x 4N), per-wave 128x64 output. 2 LDS dbufs (dbuf d holds
// K-tile of parity d). Per K-tile 4 phases: P1: mi0-3 x kk0, P2: mi0-3 x kk1,
// P3: mi4-7 x kk0 (B kept in regs), P4: mi4-7 x kk1.
// A staged as row-quadrant pairs (q0 = rows {0-63,128-191} = mi0-3 of both wave bands;
// q1 = rows {64-127,192-255}); B staged as n-halves. Stage slots chosen so each target
// region was fully read >=1 barrier earlier:
//   ph1: B-h1(d1,kb+1)  ph2: A-q1(d1,kb+1)  ph3: A-q0(d0,kb+2)  ph4: B-h0(d0,kb+2)
//   ph5: B-h1(d0,kb+2)  ph6: A-q1(d0,kb+2)  ph7: A-q0(d1,kb+3)  ph8: B-h0(d1,kb+3)
// Counted vmcnt BEFORE the trailing barrier (cross-wave safe): ph4 vmcnt(6) [lands
// d1 B-h1 + prologue d1 A-q0/B-h0 for ph5]; ph6 vmcnt(8) [ph2's A-q1 for ph7];
// ph8 vmcnt(4) [all d0 kb+2 for next ph1-4]. Steady-state invariant: 4 outstanding.
// Tail stages past NT are address-clamped dummies into dead regions (uniform counts).
// LDS swizzle: slot c of row r holds global chunk c ^ (r&7); reads XOR the same.
__global__ __launch_bounds__(512, 2) void k_gemm3(const ushort* __restrict__ A, const ushort* __restrict__ Bt,
                                                  const ushort* __restrict__ bias, ushort* __restrict__ Cb,
                                                  int M, int N, int K) {
  __shared__ alignas(16) ushort SA[2 * 256 * 64];   // 64 KB
  __shared__ alignas(16) ushort SB[2 * 256 * 64];   // 64 KB
  const int tid  = threadIdx.x;
  const int lane = tid & 63, wave = tid >> 6;
  const int lr = lane & 15, g = lane >> 4;
  const int wm = wave >> 2, wn = wave & 3;

  const int nbx = gridDim.x;
  const int nwg = nbx * gridDim.y;
  const int bid = blockIdx.y * nbx + blockIdx.x;
  const int swz = (bid & 7) * (nwg >> 3) + (bid >> 3);
  const int m0 = (swz / nbx) * 256;
  const int n0 = (swz % nbx) * 256;
  const int NT = K >> 6;           // K-tiles of 64
  const int NI = NT >> 1;

  // staging sources (per-lane, source-side chunk swizzle)
  const int chAr = (wave * 64 + lane) >> 3;       // 0..63
  const int chAs = (wave * 64 + lane) & 7;
  const int swA  = (chAs ^ (chAr & 7)) * 8;
  const ushort* sAq[2][2];   // [q][j]: rows q*64 + j*128 + chAr
  #pragma unroll
  for (int q = 0; q < 2; q++)
    #pragma unroll
    for (int j = 0; j < 2; j++)
      sAq[q][j] = A + (size_t)(m0 + q * 64 + j * 128 + chAr) * K + swA;
  const int chBr = lane >> 3;                     // 0..7
  const int swB  = ((lane & 7) ^ chBr) * 8;
  const ushort* sBh[2][2];   // [h][j]: rows h*128 + wave*16 + j*8 + chBr
  #pragma unroll
  for (int h = 0; h < 2; h++)
    #pragma unroll
    for (int j = 0; j < 2; j++)
      sBh[h][j] = Bt + (size_t)(n0 + h * 128 + wave * 16 + j * 8 + chBr) * K + swB;

  // fragment read offsets
  int rA[8], rB[4], cK[2];
  #pragma unroll
  for (int mi = 0; mi < 8; mi++) rA[mi] = (wm * 128 + mi * 16 + lr) * 64;
  #pragma unroll
  for (int ni = 0; ni < 4; ni++) rB[ni] = (wn * 64 + ni * 16 + lr) * 64;
  cK[0] = ((0 * 4 + g) ^ (lr & 7)) * 8;
  cK[1] = ((1 * 4 + g) ^ (lr & 7)) * 8;

  floatx4 acc[8][4];
  #pragma unroll
  for (int mi = 0; mi < 8; mi++)
    #pragma unroll
    for (int ni = 0; ni < 4; ni++) acc[mi][ni] = (floatx4){0.f, 0.f, 0.f, 0.f};

#define G3_STG_A(d, q, kt) { int ko = ((kt) < NT ? (kt) : 0) << 6; \
    gl_lds16(sAq[q][0] + ko, SA + (d) * 16384 + ((q) * 64 + wave * 8) * 64); \
    gl_lds16(sAq[q][1] + ko, SA + (d) * 16384 + (128 + (q) * 64 + wave * 8) * 64); }
#define G3_STG_B(d, h, kt) { int ko = ((kt) < NT ? (kt) : 0) << 6; \
    gl_lds16(sBh[h][0] + ko, SB + (d) * 16384 + ((h) * 128 + wave * 16) * 64); \
    gl_lds16(sBh[h][1] + ko, SB + (d) * 16384 + ((h) * 128 + wave * 16 + 8) * 64); }
#define G3_RD_A(dst, d, kk, mb) { _Pragma("unroll") \
    for (int _m = 0; _m < 4; _m++) dst[_m] = *(const short8*)&SA[(d) * 16384 + rA[(mb) + _m] + cK[kk]]; }
#define G3_RD_B(dst, d, kk) { _Pragma("unroll") \
    for (int _n = 0; _n < 4; _n++) dst[_n] = *(const short8*)&SB[(d) * 16384 + rB[_n] + cK[kk]]; }
#define G3_MM(mb, af, bf) { \
    __builtin_amdgcn_s_setprio(1); \
    _Pragma("unroll") for (int _m = 0; _m < 4; _m++) \
      _Pragma("unroll") for (int _n = 0; _n < 4; _n++) \
        acc[(mb) + _m][_n] = __builtin_amdgcn_mfma_f32_16x16x32_bf16(af[_m], bf[_n], acc[(mb) + _m][_n], 0, 0, 0); \
    __builtin_amdgcn_s_setprio(0); }
#define G3_BAR()  __builtin_amdgcn_s_barrier()
#define G3_SB()   __builtin_amdgcn_sched_barrier(0)

  // prologue: K0 fully (A-q0, A-q1, B-h0, B-h1 -> d0), K1's A-q0, B-h0 -> d1
  G3_STG_A(0, 0, 0); G3_STG_A(0, 1, 0); G3_STG_B(0, 0, 0); G3_STG_B(0, 1, 0);
  G3_STG_A(1, 0, 1); G3_STG_B(1, 0, 1);
  asm volatile("s_waitcnt vmcnt(4)" ::: "memory");   // all K0 landed
  G3_BAR();
  asm volatile("" ::: "memory");

  for (int i = 0; i < NI; i++) {
    const int kb = 2 * i;
    short8 aA[4], bb0[4], bb1[4];
    // ph1: mi0-3 x kk0 (d0)
    G3_RD_A(aA, 0, 0, 0); G3_RD_B(bb0, 0, 0); G3_STG_B(1, 1, kb + 1);
    G3_BAR(); G3_SB();
    G3_MM(0, aA, bb0);
    G3_SB(); G3_BAR(); asm volatile("" ::: "memory");
    // ph2: mi0-3 x kk1 (d0)
    G3_RD_A(aA, 0, 1, 0); G3_RD_B(bb1, 0, 1); G3_STG_A(1, 1, kb + 1);
    G3_BAR(); G3_SB();
    G3_MM(0, aA, bb1);
    G3_SB(); G3_BAR(); asm volatile("" ::: "memory");
    // ph3: mi4-7 x kk0 (d0)
    G3_RD_A(aA, 0, 0, 4); G3_STG_A(0, 0, kb + 2);
    G3_BAR(); G3_SB();
    G3_MM(4, aA, bb0);
    G3_SB(); G3_BAR(); asm volatile("" ::: "memory");
    // ph4: mi4-7 x kk1 (d0); vmcnt(6) lands ph1's B-h1 + prologue d1 A-q0/B-h0 for ph5
    G3_RD_A(aA, 0, 1, 4); G3_STG_B(0, 0, kb + 2);
    G3_BAR(); G3_SB();
    G3_MM(4, aA, bb1);
    G3_SB();
    asm volatile("s_waitcnt vmcnt(6)" ::: "memory");
    G3_BAR(); asm volatile("" ::: "memory");
    // ph5: mi0-3 x kk0 (d1)
    G3_RD_A(aA, 1, 0, 0); G3_RD_B(bb0, 1, 0); G3_STG_B(0, 1, kb + 2);
    G3_BAR(); G3_SB();
    G3_MM(0, aA, bb0);
    G3_SB(); G3_BAR(); asm volatile("" ::: "memory");
    // ph6: mi0-3 x kk1 (d1); vmcnt(8) lands ph2's A-q1 for ph7
    G3_RD_A(aA, 1, 1, 0); G3_RD_B(bb1, 1, 1); G3_STG_A(0, 1, kb + 2);
    G3_BAR(); G3_SB();
    G3_MM(0, aA, bb1);
    G3_SB();
    asm volatile("s_waitcnt vmcnt(8)" ::: "memory");
    G3_BAR(); asm volatile("" ::: "memory");
    // ph7: mi4-7 x kk0 (d1)
    G3_RD_A(aA, 1, 0, 4); G3_STG_A(1, 0, kb + 3);
    G3_BAR(); G3_SB();
    G3_MM(4, aA, bb0);
    G3_SB(); G3_BAR(); asm volatile("" ::: "memory");
    // ph8: mi4-7 x kk1 (d1); vmcnt(4) lands all d0 (kb+2) for next ph1-4
    G3_RD_A(aA, 1, 1, 4); G3_STG_B(1, 0, kb + 3);
    G3_BAR(); G3_SB();
    G3_MM(4, aA, bb1);
    G3_SB();
    asm volatile("s_waitcnt vmcnt(4)" ::: "memory");
    G3_BAR(); asm volatile("" ::: "memory");
  }

  // drain dummy prefetches before reusing LDS
  asm volatile("s_waitcnt vmcnt(0)" ::: "memory");
  __syncthreads();

  // LDS-bounce epilogue (gelu(val + bias) -> bf16, coalesced stores)
  const int hi4 = (lane >> 4) * 4;
  ushort* reg0 = SA;
  ushort* reg1 = SB;
  #pragma unroll
  for (int mi = 0; mi < 8; mi++) {
    #pragma unroll
    for (int ni = 0; ni < 4; ni++) {
      int colw = wn * 64 + ni * 16 + lr;
      float bv = bu2f(bias[n0 + colw]);
      #pragma unroll
      for (int q = 0; q < 4; q++) {
        int grow = wm * 128 + mi * 16 + hi4 + q;
        ushort* reg = (grow < 128) ? reg0 : reg1;
        int rl = grow & 127;
        reg[rl * 256 + (((colw >> 3) ^ (rl & 7)) * 8) + (colw & 7)] = f2bu(fast_gelu(acc[mi][ni][q] + bv));
      }
    }
  }
  __syncthreads();
  {
    const int j = tid & 31;
    const int rsub = tid >> 5;
    #pragma unroll
    for (int p = 0; p < 16; p++) {
      int row = p * 16 + rsub;
      const ushort* reg = (row < 128) ? reg0 : reg1;
      int rl = row & 127;
      short8 v = *(const short8*)&reg[rl * 256 + ((j ^ (rl & 7)) * 8)];
      *(short8*)&Cb[(size_t)(m0 + row) * N + n0 + j * 8] = v;
    }
  }
  (void)M;
#undef G3_STG_A
#undef G3_STG_B
#undef G3_RD_A
#undef G3_RD_B
#undef G3_MM
#undef G3_BAR
#undef G3_SB
}

// ---------------- MFMA bucket: consumes qk hi/lo bf16 planes; in-register first-max argmax ----------------
__global__ __launch_bounds__(256) void k_bucket_mfma(const ushort* __restrict__ qkh, const ushort* __restrict__ qkl,
                                                     const ushort* __restrict__ rotT, int* __restrict__ bkt) {
  __shared__ alignas(16) ushort Bs[128*128];  // rotT [n][k]  32 KB
  __shared__ alignas(16) ushort Ah[64*128];   // Q hi         16 KB
  __shared__ alignas(16) ushort Al[64*128];   // Q lo         16 KB
  const int tid = threadIdx.x;
  const int lane = tid & 63, wave = tid >> 6;
  const int lr = lane & 15, lk = (lane >> 4) * 8;
  const int tt = blockIdx.x * 64;
  const int bh = blockIdx.y;
  const int b = bh >> 3, hh = bh & 7;

  {
    int r = tid >> 2, c0 = (tid & 3) * 32;
    size_t base = ((size_t)(b * kT + tt + r)) * kDim + hh * 128 + c0;
    const uint4* sh = (const uint4*)(qkh + base);
    const uint4* sl = (const uint4*)(qkl + base);
    uint4* dh = (uint4*)&Ah[r * 128 + c0];
    uint4* dl = (uint4*)&Al[r * 128 + c0];
    #pragma unroll
    for (int i = 0; i < 4; i++) { dh[i] = sh[i]; dl[i] = sl[i]; }
  }
  {
    const uint4* src = (const uint4*)rotT;
    uint4* dst = (uint4*)Bs;
    for (int i = tid; i < 2048; i += 256) dst[i] = src[i];
  }
  __syncthreads();

  floatx4 acc[4][2];
  #pragma unroll
  for (int mi = 0; mi < 4; mi++) { acc[mi][0] = (floatx4){0,0,0,0}; acc[mi][1] = (floatx4){0,0,0,0}; }
  #pragma unroll
  for (int ks = 0; ks < 4; ks++) {
    short8 a[4], bb[2];
    #pragma unroll
    for (int ni = 0; ni < 2; ni++) bb[ni] = *(const short8*)&Bs[(wave*32 + ni*16 + lr)*128 + ks*32 + lk];
    #pragma unroll
    for (int mi = 0; mi < 4; mi++) a[mi] = *(const short8*)&Ah[(mi*16 + lr)*128 + ks*32 + lk];
    #pragma unroll
    for (int mi = 0; mi < 4; mi++)
      #pragma unroll
      for (int ni = 0; ni < 2; ni++)
        acc[mi][ni] = __builtin_amdgcn_mfma_f32_16x16x32_bf16(a[mi], bb[ni], acc[mi][ni], 0, 0, 0);
  }
  #pragma unroll
  for (int ks = 0; ks < 4; ks++) {
    short8 a[4], bb[2];
    #pragma unroll
    for (int ni = 0; ni < 2; ni++) bb[ni] = *(const short8*)&Bs[(wave*32 + ni*16 + lr)*128 + ks*32 + lk];
    #pragma unroll
    for (int mi = 0; mi < 4; mi++) a[mi] = *(const short8*)&Al[(mi*16 + lr)*128 + ks*32 + lk];
    #pragma unroll
    for (int mi = 0; mi < 4; mi++)
      #pragma unroll
      for (int ni = 0; ni < 2; ni++)
        acc[mi][ni] = __builtin_amdgcn_mfma_f32_16x16x32_bf16(a[mi], bb[ni], acc[mi][ni], 0, 0, 0);
  }

  #pragma unroll
  for (int mi = 0; mi < 4; mi++) {
    #pragma unroll
    for (int q = 0; q < 4; q++) {
      float v0 = acc[mi][0][q];
      float v1 = acc[mi][1][q];
      float best = v0; int bidx = lr;
      if (v1  > best) { best = v1;  bidx = 16 + lr; }
      if (-v0 > best) { best = -v0; bidx = 32 + lr; }
      if (-v1 > best) { best = -v1; bidx = 48 + lr; }
      #pragma unroll
      for (int m = 1; m <= 8; m <<= 1) {
        float ov = __shfl_xor(best, m);
        int   oi = __shfl_xor(bidx, m);
        if (ov > best || (ov == best && oi < bidx)) { best = ov; bidx = oi; }
      }
      if (lr == 0) {
        int row = mi*16 + ((lane >> 4) & 3)*4 + q;
        bkt[(bh*4 + wave)*4096 + tt + row] = bidx;
      }
    }
  }
}

// ---------------- stable counting sort per (bh,hash) ----------------
__global__ __launch_bounds__(256) void k_sort(const int* __restrict__ bkt, int* __restrict__ st) {
  __shared__ unsigned char  hist[64*256];
  __shared__ unsigned short offs[64*256];
  __shared__ int base[64];
  int tid = threadIdx.x, grp = blockIdx.x;
  const int* bk = bkt + grp * 4096;
  for (int i = tid; i < 64*256; i += 256) hist[i] = 0;
  __syncthreads();
  int myb[16];
  #pragma unroll
  for (int j = 0; j < 16; j++) {
    myb[j] = bk[tid*16 + j];
    hist[myb[j]*256 + tid] += 1;
  }
  __syncthreads();
  if (tid < 64) {
    int run = 0;
    for (int t = 0; t < 256; t++) { offs[tid*256 + t] = (unsigned short)run; run += hist[tid*256 + t]; }
    base[tid] = run;
  }
  __syncthreads();
  if (tid == 0) {
    int run = 0;
    for (int b2 = 0; b2 < 64; b2++) { int c = base[b2]; base[b2] = run; run += c; }
  }
  __syncthreads();
  #pragma unroll
  for (int j = 0; j < 16; j++) {
    int b2 = myb[j];
    int r = 0;
    for (int jj = 0; jj < j; jj++) r += (myb[jj] == b2) ? 1 : 0;
    st[grp*4096 + base[b2] + (int)offs[b2*256 + tid] + r] = tid*16 + j;
  }
}

// ---------------- chunked LSH attention (bf16 qk hi-plane input) ----------------
__global__ __launch_bounds__(256) void k_attn(const ushort* __restrict__ qkh, const ushort* __restrict__ vbuf,
                                              const int* __restrict__ st, ushort* __restrict__ o_r,
                                              float* __restrict__ lse_r) {
  __shared__ alignas(16) ushort KV[128*136];
  __shared__ alignas(16) ushort Ps[64*136];
  __shared__ float rnorm[128];
  __shared__ int   kposs[128];
  __shared__ float red1[64*4];
  __shared__ float red2[64*4];
  __shared__ float lrow[64];

  const int tid = threadIdx.x;
  const int bid = blockIdx.x;
  const int bh = bid >> 8;
  const int c  = bid & 255;
  const int h  = c >> 6;
  const int cprev = (c + 255) & 255;
  const int b  = bh >> 3, hh = bh & 7;
  const int lane = tid & 63, wave = tid >> 6;
  const int lr = lane & 15, lk = (lane >> 4) * 8;

  {
    int j = tid >> 1, half = tid & 1;
    int slot = (j < 64) ? (c*64 + j) : (cprev*64 + (j - 64));
    int pos = st[bh*16384 + slot];
    if (half == 0) kposs[j] = pos;
    const ushort* src = qkh + ((size_t)(b * kT + pos)) * kDim + hh*128 + half*64;
    float ss = 0.f;
    #pragma unroll
    for (int i2 = 0; i2 < 64; i2 += 8) {
      uint4 u = *(const uint4*)(src + i2);
      *(uint4*)&KV[j*136 + half*64 + i2] = u;
      float f0 = bu2f((ushort)(u.x & 0xffffu)), f1 = bu2f((ushort)(u.x >> 16));
      float f2 = bu2f((ushort)(u.y & 0xffffu)), f3 = bu2f((ushort)(u.y >> 16));
      float f4 = bu2f((ushort)(u.z & 0xffffu)), f5 = bu2f((ushort)(u.z >> 16));
      float f6 = bu2f((ushort)(u.w & 0xffffu)), f7 = bu2f((ushort)(u.w >> 16));
      ss += f0*f0 + f1*f1 + f2*f2 + f3*f3 + f4*f4 + f5*f5 + f6*f6 + f7*f7;
    }
    ss += __shfl_xor(ss, 1);
    if (half == 0) rnorm[j] = 1.f / fmaxf(sqrtf(ss), 1e-12f);
  }
  __syncthreads();

  {
    floatx4 acc[4][2];
    #pragma unroll
    for (int mi = 0; mi < 4; mi++) { acc[mi][0] = (floatx4){0,0,0,0}; acc[mi][1] = (floatx4){0,0,0,0}; }
    #pragma unroll
    for (int ks = 0; ks < 4; ks++) {
      short8 a[4], bb[2];
      #pragma unroll
      for (int mi = 0; mi < 4; mi++) a[mi]  = *(const short8*)&KV[(mi*16 + lr)*136 + ks*32 + lk];
      #pragma unroll
      for (int ni = 0; ni < 2; ni++) bb[ni] = *(const short8*)&KV[(wave*32 + ni*16 + lr)*136 + ks*32 + lk];
      #pragma unroll
      for (int mi = 0; mi < 4; mi++)
        #pragma unroll
        for (int ni = 0; ni < 2; ni++)
          acc[mi][ni] = __builtin_amdgcn_mfma_f32_16x16x32_bf16(a[mi], bb[ni], acc[mi][ni], 0, 0, 0);
    }
    #pragma unroll
    for (int mi = 0; mi < 4; mi++) {
      #pragma unroll
      for (int ni = 0; ni < 2; ni++) {
        int col = wave*32 + ni*16 + lr;
        float rn = rnorm[col] * kScale;
        int cpos = kposs[col];
        #pragma unroll
        for (int q = 0; q < 4; q++) {
          int row = mi*16 + (lane >> 4)*4 + q;
          float val = acc[mi][ni][q] * rn;
          if (cpos == kposs[row]) val = kSelfVal;
          Ps[row*136 + col] = f2bu(val);
        }
      }
    }
  }
  __syncthreads();

  {
    int j = tid >> 1, half = tid & 1;
    int pos = kposs[j];
    const ushort* src = vbuf + ((size_t)(b * kT + pos)) * kDim + hh*128 + half*64;
    #pragma unroll
    for (int i2 = 0; i2 < 64; i2 += 8) {
      uint4 u = *(const uint4*)(src + i2);
      int d0 = half*64 + i2;
      KV[(d0+0)*136 + j] = (ushort)(u.x & 0xffffu); KV[(d0+1)*136 + j] = (ushort)(u.x >> 16);
      KV[(d0+2)*136 + j] = (ushort)(u.y & 0xffffu); KV[(d0+3)*136 + j] = (ushort)(u.y >> 16);
      KV[(d0+4)*136 + j] = (ushort)(u.z & 0xffffu); KV[(d0+5)*136 + j] = (ushort)(u.z >> 16);
      KV[(d0+6)*136 + j] = (ushort)(u.w & 0xffffu); KV[(d0+7)*136 + j] = (ushort)(u.w >> 16);
    }
  }

  {
    int i = tid >> 2, part = tid & 3;
    const int jb = part * 32;
    float m = -1e30f;
    for (int j2 = 0; j2 < 32; j2++) m = fmaxf(m, bu2f(Ps[i*136 + jb + j2]));
    red1[i*4 + part] = m;
    __syncthreads();
    m = fmaxf(fmaxf(red1[i*4+0], red1[i*4+1]), fmaxf(red1[i*4+2], red1[i*4+3]));
    float ssum = 0.f;
    for (int j2 = 0; j2 < 32; j2++) {
      float arg = fmaxf(fminf(bu2f(Ps[i*136 + jb + j2]) - m, 0.f), -80.f);
      float p = __expf(arg);
      ssum += p;
      Ps[i*136 + jb + j2] = f2bu(p);
    }
    red2[i*4 + part] = ssum;
    __syncthreads();
    if (part == 0) {
      float l = fmaxf(red2[i*4+0] + red2[i*4+1] + red2[i*4+2] + red2[i*4+3], 1e-20f);
      lrow[i] = 1.f / l;
      lse_r[(size_t)(bh*4 + h)*4096 + kposs[i]] = m + __logf(l);
    }
  }
  __syncthreads();

  {
    floatx4 acc[4][2];
    #pragma unroll
    for (int mi = 0; mi < 4; mi++) { acc[mi][0] = (floatx4){0,0,0,0}; acc[mi][1] = (floatx4){0,0,0,0}; }
    #pragma unroll
    for (int ks = 0; ks < 4; ks++) {
      short8 a[4], bb[2];
      #pragma unroll
      for (int mi = 0; mi < 4; mi++) a[mi]  = *(const short8*)&Ps[(mi*16 + lr)*136 + ks*32 + lk];
      #pragma unroll
      for (int ni = 0; ni < 2; ni++) bb[ni] = *(const short8*)&KV[(wave*32 + ni*16 + lr)*136 + ks*32 + lk];
      #pragma unroll
      for (int mi = 0; mi < 4; mi++)
        #pragma unroll
        for (int ni = 0; ni < 2; ni++)
          acc[mi][ni] = __builtin_amdgcn_mfma_f32_16x16x32_bf16(a[mi], bb[ni], acc[mi][ni], 0, 0, 0);
    }
    #pragma unroll
    for (int mi = 0; mi < 4; mi++) {
      #pragma unroll
      for (int ni = 0; ni < 2; ni++) {
        int d = wave*32 + ni*16 + lr;
        #pragma unroll
        for (int q = 0; q < 4; q++) {
          int row = mi*16 + (lane >> 4)*4 + q;
          float o = acc[mi][ni][q] * lrow[row];
          o_r[((size_t)(bh*4 + h)*4096 + kposs[row])*128 + d] = f2bu(o);
        }
      }
    }
  }
}

// ---------------- combine hash rounds ----------------
__global__ __launch_bounds__(256) void k_combine(const ushort* __restrict__ o_r, const float* __restrict__ lse_r,
                                                 ushort* __restrict__ attnbf) {
  int rid = blockIdx.x * 2 + (threadIdx.x >> 7);
  int d = threadIdx.x & 127;
  int bh = rid >> 12, t = rid & 4095;
  int b = bh >> 3, hh = bh & 7;
  size_t base = (size_t)bh * 16384 + t;
  float l0 = lse_r[base], l1 = lse_r[base + 4096], l2 = lse_r[base + 8192], l3 = lse_r[base + 12288];
  float M = fmaxf(fmaxf(l0, l1), fmaxf(l2, l3));
  float e0 = __expf(fmaxf(fminf(l0 - M, 0.f), -80.f));
  float e1 = __expf(fmaxf(fminf(l1 - M, 0.f), -80.f));
  float e2 = __expf(fmaxf(fminf(l2 - M, 0.f), -80.f));
  float e3 = __expf(fmaxf(fminf(l3 - M, 0.f), -80.f));
  float inv = 1.f / (e0 + e1 + e2 + e3);
  float o = e0 * bu2f(o_r[(base         )*128 + d]) + e1 * bu2f(o_r[(base +  4096)*128 + d])
          + e2 * bu2f(o_r[(base +  8192)*128 + d]) + e3 * bu2f(o_r[(base + 12288)*128 + d]);
  attnbf[((size_t)b * kT + t) * kDim + hh*128 + d] = f2bu(o * inv);
}

extern "C" void kernel_launch(void* const* d_in, const int* in_sizes, int n_in,
                              void* d_out, int out_size, void* d_ws, size_t ws_size,
                              hipStream_t stream) {
  (void)in_sizes; (void)n_in; (void)out_size; (void)ws_size;
  const void* x     = d_in[0];
  const void* ln1_g = d_in[1];
  const void* ln1_b = d_in[2];
  const void* Wqk   = d_in[3];
  const void* Wv    = d_in[4];
  const void* Wo    = d_in[5];
  const void* bo    = d_in[6];
  const void* ln2_g = d_in[7];
  const void* ln2_b = d_in[8];
  const void* W1    = d_in[9];
  const void* b1    = d_in[10];
  const void* W2    = d_in[11];
  const void* b2    = d_in[12];
  const void* rot   = d_in[13];

  char* w = (char*)d_ws;
  int*    flag = (int*)w;    w += 256;
  ushort* prm  = (ushort*)w; w += 131072;
  float* x1  = (float*)w;  w += 33554432;
  float* x2  = (float*)w;  w += 33554432;
  ushort* qkh = (ushort*)w; w += 16777216;
  ushort* qkl = (ushort*)w; w += 16777216;
  ushort* vbb = (ushort*)w; w += 16777216;
  ushort* xbf = (ushort*)w; w += 16777216;
  ushort* orb = (ushort*)w; w += 67108864;
  float* lse = (float*)w;  w += 1048576;
  int*   bkt = (int*)w;    w += 1048576;
  int*   stb = (int*)w;    w += 1048576;
  ushort* wtA = (ushort*)w; w += 2097152;
  ushort* wtB = (ushort*)w; w += 2097152;
  ushort* wtC = (ushort*)w; w += 2097152;
  ushort* wt1 = (ushort*)w; w += 8388608;
  ushort* wt2 = (ushort*)w; w += 8388608;
  ushort* rtT = (ushort*)w; w += 32768;

  ushort* pLN1G = prm + 0;     ushort* pLN1B = prm + 2048;
  ushort* pBO   = prm + 4096;  ushort* pLN2G = prm + 6144;
  ushort* pLN2B = prm + 8192;  ushort* pB1   = prm + 10240;
  ushort* pB2   = prm + 18432; ushort* pROT  = prm + 20480;

  k_detect<<<1, 256, 0, stream>>>((const unsigned*)x, flag);
  k_cvt<<<8,   256, 0, stream>>>(flag, ln1_g, pLN1G, 2048);
  k_cvt<<<8,   256, 0, stream>>>(flag, ln1_b, pLN1B, 2048);
  k_cvt<<<8,   256, 0, stream>>>(flag, bo,    pBO,   2048);
  k_cvt<<<8,   256, 0, stream>>>(flag, ln2_g, pLN2G, 2048);
  k_cvt<<<8,   256, 0, stream>>>(flag, ln2_b, pLN2B, 2048);
  k_cvt<<<32,  256, 0, stream>>>(flag, b1,    pB1,   8192);
  k_cvt<<<8,   256, 0, stream>>>(flag, b2,    pB2,   2048);
  k_cvt<<<128, 256, 0, stream>>>(flag, rot,   pROT,  32768);
  k_init_any<<<8192, 256, 0, stream>>>(flag, x, x1, x2);

  for (int d = 0; d < 2; d++) {
    k_transpose2<<<dim3(32, 32),  256, 0, stream>>>(flag,
        (const char*)Wqk + (size_t)d*1048576*2, (const char*)Wqk + (size_t)d*1048576*4, wtA, 1024, 1024);
    k_transpose2<<<dim3(32, 32),  256, 0, stream>>>(flag,
        (const char*)Wv  + (size_t)d*1048576*2, (const char*)Wv  + (size_t)d*1048576*4, wtB, 1024, 1024);
    k_transpose2<<<dim3(32, 32),  256, 0, stream>>>(flag,
        (const char*)Wo  + (size_t)d*1048576*2, (const char*)Wo  + (size_t)d*1048576*4, wtC, 1024, 1024);
    k_transpose2<<<dim3(128, 32), 256, 0, stream>>>(flag,
        (const char*)W1  + (size_t)d*4194304*2, (const char*)W1  + (size_t)d*4194304*4, wt1, 1024, 4096);
    k_transpose2<<<dim3(32, 128), 256, 0, stream>>>(flag,
        (const char*)W2  + (size_t)d*4194304*2, (const char*)W2  + (size_t)d*4194304*4, wt2, 4096, 1024);
    k_rot_t<<<1, 256, 0, stream>>>(pROT + (size_t)d * 16384, rtT);

    k_ln<<<8192, 256, 0, stream>>>(x2, pLN1G + d*1024, pLN1B + d*1024, xbf);
    k_gemm4<<<dim3(4, 64), 512, 0, stream>>>(xbf, wtA, nullptr, nullptr, qkh, qkl, 8192, 1024, 1024, 5);
    k_gemm4<<<dim3(4, 64), 512, 0, stream>>>(xbf, wtB, nullptr, nullptr, vbb, nullptr, 8192, 1024, 1024, 3);
    k_bucket_mfma<<<dim3(64, 16), 256, 0, stream>>>(qkh, qkl, rtT, bkt);
    k_sort<<<64, 256, 0, stream>>>(bkt, stb);
    k_attn<<<4096, 256, 0, stream>>>(qkh, vbb, stb, orb, lse);
    k_combine<<<32768, 256, 0, stream>>>(orb, lse, xbf);
    k_gemm4<<<dim3(4, 64), 512, 0, stream>>>(xbf, wtC, pBO + d*1024, x1, nullptr, nullptr, 8192, 1024, 1024, 1);
    k_ln<<<8192, 256, 0, stream>>>(x1, pLN2G + d*1024, pLN2B + d*1024, xbf);
    k_gemm3<<<dim3(16, 32), 512, 0, stream>>>(xbf, wt1, pB1 + d*4096, orb, 8192, 4096, 1024);
    k_gemm4<<<dim3(4, 64), 512, 0, stream>>>(orb, wt2, pB2 + d*1024, x2, nullptr, nullptr, 8192, 1024, 4096, 1);
  }
  k_final_any<<<8192, 256, 0, stream>>>(flag, x1, x2, d_out);
}

// Round 7
// 1108.474 us; speedup vs baseline: 1.4032x; 1.0025x over previous
//
#include <hip/hip_runtime.h>
#include <hip/hip_bf16.h>
#include <cmath>

using bf16 = __hip_bfloat16;
typedef __attribute__((ext_vector_type(8))) short short8;
typedef __attribute__((ext_vector_type(4))) float floatx4;

__device__ __forceinline__ float bu2f(ushort u) { return __uint_as_float((unsigned)u << 16); }
__device__ __forceinline__ ushort f2bu(float f) {
  union { bf16 b; ushort u; } cv; cv.b = __float2bfloat16(f); return cv.u;
}
__device__ __forceinline__ void gl_lds16(const ushort* g, ushort* l) {
  __builtin_amdgcn_global_load_lds((const __attribute__((address_space(1))) unsigned*)g,
                                   (__attribute__((address_space(3))) unsigned*)l, 16, 0, 0);
}
// tanh-form GELU via hw exp; |err vs erf-GELU| ~2e-4, below bf16 output quantization
__device__ __forceinline__ float fast_gelu(float x) {
  float z = 0.7978845608028654f * (x + 0.044715f * x * x * x);
  z = fmaxf(fminf(z, 10.f), -10.f);
  float e = __expf(2.f * z);
  float t = (e - 1.f) / (e + 1.f);
  return 0.5f * x * (1.f + t);
}

static constexpr int kT   = 4096;
static constexpr int kDim = 1024;
static constexpr float kScale   = 0.08838834764831845f;  // 1/sqrt(128)
static constexpr float kSelfVal = -5.0e4f;

// ---------------- dtype detector: bf16 vs fp32 inputs ----------------
__device__ __forceinline__ int sane_v(float f) { float a = fabsf(f); return (a > 1e-4f && a < 1e4f) ? 1 : 0; }

__global__ __launch_bounds__(256) void k_detect(const unsigned* __restrict__ x, int* __restrict__ flag) {
  __shared__ int cnt;
  int tid = threadIdx.x;
  if (tid == 0) cnt = 0;
  __syncthreads();
  int my = 0;
  const uint4* p = (const uint4*)x;
  for (int q = 0; q < 16; q++) {
    uint4 u = p[tid * 16 + q];
    my += sane_v(__uint_as_float(u.x << 16)) + sane_v(__uint_as_float(u.x & 0xffff0000u));
    my += sane_v(__uint_as_float(u.y << 16)) + sane_v(__uint_as_float(u.y & 0xffff0000u));
    my += sane_v(__uint_as_float(u.z << 16)) + sane_v(__uint_as_float(u.z & 0xffff0000u));
    my += sane_v(__uint_as_float(u.w << 16)) + sane_v(__uint_as_float(u.w & 0xffff0000u));
  }
  atomicAdd(&cnt, my);
  __syncthreads();
  if (tid == 0) flag[0] = (cnt >= 24576) ? 1 : 0;
}

__global__ __launch_bounds__(256) void k_cvt(const int* __restrict__ flag, const void* __restrict__ src,
                                             ushort* __restrict__ dst, int n) {
  int i = blockIdx.x * 256 + threadIdx.x;
  if (i >= n) return;
  dst[i] = (*flag) ? ((const ushort*)src)[i] : f2bu(((const float*)src)[i]);
}

__global__ __launch_bounds__(256) void k_init_any(const int* __restrict__ flag, const void* __restrict__ x,
                                                  float* __restrict__ x1, float* __restrict__ x2) {
  int i = blockIdx.x * 1024 + threadIdx.x * 4;
  float4 f;
  if (*flag) {
    ushort4 u = *(const ushort4*)((const ushort*)x + i);
    f.x = bu2f(u.x); f.y = bu2f(u.y); f.z = bu2f(u.z); f.w = bu2f(u.w);
  } else {
    f = *(const float4*)((const float*)x + i);
  }
  *(float4*)(x1 + i) = f;
  *(float4*)(x2 + i) = f;
}

__global__ __launch_bounds__(256) void k_final_any(const int* __restrict__ flag, const float* __restrict__ x1,
                                                   const float* __restrict__ x2, void* __restrict__ out) {
  int i = blockIdx.x * 1024 + threadIdx.x * 4;
  float4 a = *(const float4*)(x1 + i);
  float4 b = *(const float4*)(x2 + i);
  float4 s; s.x = a.x + b.x; s.y = a.y + b.y; s.z = a.z + b.z; s.w = a.w + b.w;
  if (*flag) {
    ushort4 u; u.x = f2bu(s.x); u.y = f2bu(s.y); u.z = f2bu(s.z); u.w = f2bu(s.w);
    *(ushort4*)((ushort*)out + i) = u;
  } else {
    *(float4*)((float*)out + i) = s;
  }
}

// ---------------- layernorm: fp32 in -> bf16 out ----------------
__global__ __launch_bounds__(256) void k_ln(const float* __restrict__ x, const ushort* __restrict__ g,
                                            const ushort* __restrict__ be, ushort* __restrict__ out) {
  __shared__ float ws[4], ws2[4];
  int row = blockIdx.x, tid = threadIdx.x;
  const float* xr = x + (size_t)row * kDim + tid * 4;
  float4 v = *(const float4*)xr;
  float s  = v.x + v.y + v.z + v.w;
  float s2 = v.x*v.x + v.y*v.y + v.z*v.z + v.w*v.w;
  #pragma unroll
  for (int off = 32; off; off >>= 1) { s += __shfl_down(s, off); s2 += __shfl_down(s2, off); }
  int wave = tid >> 6, lane = tid & 63;
  if (lane == 0) { ws[wave] = s; ws2[wave] = s2; }
  __syncthreads();
  s  = ws[0] + ws[1] + ws[2] + ws[3];
  s2 = ws2[0] + ws2[1] + ws2[2] + ws2[3];
  float mean = s * (1.f/1024.f);
  float var  = fmaxf(s2 * (1.f/1024.f) - mean*mean, 0.f);
  float rstd = rsqrtf(var + 1e-5f);
  int cb = tid * 4;
  ushort* o = out + (size_t)row * kDim + cb;
  o[0] = f2bu((v.x - mean) * rstd * bu2f(g[cb+0]) + bu2f(be[cb+0]));
  o[1] = f2bu((v.y - mean) * rstd * bu2f(g[cb+1]) + bu2f(be[cb+1]));
  o[2] = f2bu((v.z - mean) * rstd * bu2f(g[cb+2]) + bu2f(be[cb+2]));
  o[3] = f2bu((v.w - mean) * rstd * bu2f(g[cb+3]) + bu2f(be[cb+3]));
}

// ---------------- dual-dtype weight transpose: in[K,N] -> out[N,K] ----------------
__global__ __launch_bounds__(256) void k_transpose2(const int* __restrict__ flag, const void* __restrict__ src_bf,
                                                    const void* __restrict__ src_f, ushort* __restrict__ out,
                                                    int K, int N) {
  __shared__ ushort tile[32][33];
  int isbf = *flag;
  int nb = blockIdx.x * 32, kb = blockIdx.y * 32;
  int tx = threadIdx.x & 31, ty = threadIdx.x >> 5;
  for (int r = ty; r < 32; r += 8) {
    size_t idx = (size_t)(kb + r) * N + nb + tx;
    tile[r][tx] = isbf ? ((const ushort*)src_bf)[idx] : f2bu(((const float*)src_f)[idx]);
  }
  __syncthreads();
  for (int r = ty; r < 32; r += 8) out[(size_t)(nb + r) * K + kb + tx] = tile[tx][r];
}

// ---------------- rot transpose: rot[k=128][n=128] -> rotT[n=128][k=128] ----------------
__global__ __launch_bounds__(256) void k_rot_t(const ushort* __restrict__ rot, ushort* __restrict__ rotT) {
  int tid = threadIdx.x;
  for (int idx = tid; idx < 16384; idx += 256) {
    int n = idx >> 7, k = idx & 127;
    rotT[idx] = rot[k * 128 + n];
  }
}

// ---------------- k_gemm5: single-barrier-per-phase pipelined GEMM ----------------
// BN=256, BK=32, 512 thr = 8 waves (2M x 4N). MW=4 -> BM=128 (wave 64x64, N=1024
// shapes + W2); MW=8 -> BM=256 (wave 128x64, W1). 4 LDS buffers.
// ONE barrier per phase (vs round-6's two + sched_barrier pins, which forced all 8
// waves into read-burst/MFMA-burst lockstep -> 26% MfmaUtil). MFMA is register-only:
// once fragments are loaded, buffer overwrite is safe; the only hazards are DMA-write
// vs ds_read, ordered by {per-wave counted vmcnt -> barrier -> reads}.
// Phase kt: { MW+4 ds_read_b128 (buf kt&3) | stage kt+PF (LD loads, buf (kt+PF)&3)
//             | setprio + MW*4 MFMA (compiler interleaves + emits fine lgkmcnt) }
//           -> s_waitcnt vmcnt((PF-1)*LD) -> s_barrier -> fence.
// MW=4: PF=3, LD=3, vmcnt(6) (load age >=2 phases). MW=8: PF=2, LD=4, vmcnt(4)
// (phase ~1242 cy covers latency). RAW: wait at end of kt-1 has in-flight tiles
// kt..kt+PF-1; leaving (PF-1)*LD lands tile kt before barrier -> all waves' reads
// safe. WAR: stage(kt) targets buf (kt+PF)&3 = buf(kt-(4-PF))&3, last read >=1
// barrier earlier; stage issued after that barrier in program order. Tail stages are
// address-clamped dummies into dead buffers (uniform counts); vmcnt(0)+sync before
// epilogue LDS reuse. Source-side chunk swizzle: LDS slot s of row r holds global
// chunk s^((r>>1)&3); reads recover via same XOR (2-way bank aliasing = free).
// mode 1: Cf += A@B + bias (scalar float RMW)  mode 2: Cb = bf16(gelu(A@B+bias))
// mode 3: Cb = bf16(A@B)   mode 5: Cb = hi(A@B), Cb2 = lo(A@B)   (LDS-bounce stores)
template <int MW>
__global__ __launch_bounds__(512, 2) void k_gemm5(const ushort* __restrict__ A, const ushort* __restrict__ Bt,
                                                  const ushort* __restrict__ bias, float* __restrict__ Cf,
                                                  ushort* __restrict__ Cb, ushort* __restrict__ Cb2,
                                                  int M, int N, int K, int mode) {
  constexpr int BM = MW * 32;            // 128 or 256
  constexpr int LA = MW / 4;             // A loads/thread/K-tile: 1 or 2
  constexpr int PF = (MW == 8) ? 2 : 3;  // prefetch distance
  __shared__ alignas(16) ushort SAu[4 * BM * 32];    // 32 KB / 64 KB
  __shared__ alignas(16) ushort SBu[4 * 256 * 32];   // 64 KB

  const int tid  = threadIdx.x;
  const int lane = tid & 63, wave = tid >> 6;
  const int lr = lane & 15, g = lane >> 4;
  const int wm = wave >> 2, wn = wave & 3;

  // XCD-aware bijective block swizzle (all grids here have nwg % 8 == 0)
  const int nbx = gridDim.x;
  const int nwg = nbx * gridDim.y;
  const int bid = blockIdx.y * nbx + blockIdx.x;
  const int swz = (bid & 7) * (nwg >> 3) + (bid >> 3);
  const int m0 = (swz / nbx) * BM;
  const int n0 = (swz % nbx) * 256;

  const int NT = K >> 5;

  // per-thread staging sources (global col-chunk pre-swizzled, LDS dest linear)
  const ushort* srcA[LA];
  #pragma unroll
  for (int j = 0; j < LA; j++) {
    int chunk = wave * (64 * LA) + j * 64 + lane;
    int row = chunk >> 2, c = chunk & 3;
    int cs = c ^ ((row >> 1) & 3);
    srcA[j] = A + (size_t)(m0 + row) * K + cs * 8;
  }
  const ushort* srcB[2];
  #pragma unroll
  for (int j = 0; j < 2; j++) {
    int chunk = wave * 128 + j * 64 + lane;
    int row = chunk >> 2, c = chunk & 3;
    int cs = c ^ ((row >> 1) & 3);
    srcB[j] = Bt + (size_t)(n0 + row) * K + cs * 8;
  }

  // fragment read offsets (loop-invariant; ushort units)
  int offA[MW], offB[4];
  #pragma unroll
  for (int mi = 0; mi < MW; mi++) {
    int row = wm * (MW * 16) + mi * 16 + lr;
    offA[mi] = row * 32 + ((g ^ ((row >> 1) & 3)) * 8);
  }
  #pragma unroll
  for (int ni = 0; ni < 4; ni++) {
    int row = wn * 64 + ni * 16 + lr;
    offB[ni] = row * 32 + ((g ^ ((row >> 1) & 3)) * 8);
  }

  floatx4 acc[MW][4];
  #pragma unroll
  for (int mi = 0; mi < MW; mi++)
    #pragma unroll
    for (int ni = 0; ni < 4; ni++) acc[mi][ni] = (floatx4){0.f, 0.f, 0.f, 0.f};

  // prologue: stage K-tiles 0..PF-1 (NT >= PF always here)
  #pragma unroll
  for (int p = 0; p < PF; p++) {
    #pragma unroll
    for (int j = 0; j < LA; j++) gl_lds16(srcA[j] + p * 32, SAu + p * (BM * 32) + (wave * (64 * LA) + j * 64) * 8);
    #pragma unroll
    for (int j = 0; j < 2; j++)  gl_lds16(srcB[j] + p * 32, SBu + p * (256 * 32) + (wave * 128 + j * 64) * 8);
  }
  if constexpr (MW == 8) asm volatile("s_waitcnt vmcnt(4)" ::: "memory");
  else                   asm volatile("s_waitcnt vmcnt(6)" ::: "memory");
  __builtin_amdgcn_s_barrier();
  asm volatile("" ::: "memory");

  for (int kt = 0; kt < NT; kt++) {
    const ushort* sa = SAu + (kt & 3) * (BM * 32);
    const ushort* sb = SBu + (kt & 3) * (256 * 32);
    const int kp = ((kt + PF < NT) ? (kt + PF) : 0) * 32;   // dummy-clamp past NT
    const int pb = (kt + PF) & 3;

    // fragment reads (buf kt&3; validated by previous phase's vmcnt+barrier)
    short8 a[MW], b[4];
    #pragma unroll
    for (int mi = 0; mi < MW; mi++) a[mi] = *(const short8*)&sa[offA[mi]];
    #pragma unroll
    for (int ni = 0; ni < 4; ni++)  b[ni] = *(const short8*)&sb[offB[ni]];

    // stage kt+PF into its (dead) buffer
    #pragma unroll
    for (int j = 0; j < LA; j++) gl_lds16(srcA[j] + kp, SAu + pb * (BM * 32) + (wave * (64 * LA) + j * 64) * 8);
    #pragma unroll
    for (int j = 0; j < 2; j++)  gl_lds16(srcB[j] + kp, SBu + pb * (256 * 32) + (wave * 128 + j * 64) * 8);

    // MFMA cluster (compiler interleaves reads/MFMA and emits fine lgkmcnt)
    __builtin_amdgcn_s_setprio(1);
    #pragma unroll
    for (int mi = 0; mi < MW; mi++)
      #pragma unroll
      for (int ni = 0; ni < 4; ni++)
        acc[mi][ni] = __builtin_amdgcn_mfma_f32_16x16x32_bf16(a[mi], b[ni], acc[mi][ni], 0, 0, 0);
    __builtin_amdgcn_s_setprio(0);

    // counted wait: leave kt+1..kt+PF-1's newest (PF-1)*LD in flight; lands tile kt+1
    if constexpr (MW == 8) asm volatile("s_waitcnt vmcnt(4)" ::: "memory");
    else                   asm volatile("s_waitcnt vmcnt(6)" ::: "memory");
    __builtin_amdgcn_s_barrier();
    asm volatile("" ::: "memory");
  }

  // drain dummy prefetches before reusing LDS
  asm volatile("s_waitcnt vmcnt(0)" ::: "memory");
  __syncthreads();

  const int hi4 = (lane >> 4) * 4;

  if (mode == 1) {
    // scalar float RMW (64 B contiguous per quarter-wave; measured clean)
    #pragma unroll
    for (int mi = 0; mi < MW; mi++) {
      #pragma unroll
      for (int ni = 0; ni < 4; ni++) {
        int col = n0 + wn * 64 + ni * 16 + lr;
        float bv = bu2f(bias[col]);
        #pragma unroll
        for (int q = 0; q < 4; q++) {
          int r2 = m0 + wm * (MW * 16) + mi * 16 + hi4 + q;
          Cf[(size_t)r2 * N + col] += acc[mi][ni][q] + bv;
        }
      }
    }
  } else {
    // LDS-bounce epilogue: acc -> swizzled LDS -> coalesced dwordx4 row stores
    ushort* reg0 = (MW == 8) ? SAu : SBu;
    ushort* reg1 = SBu;
    #pragma unroll
    for (int mi = 0; mi < MW; mi++) {
      #pragma unroll
      for (int ni = 0; ni < 4; ni++) {
        int colw = wn * 64 + ni * 16 + lr;            // 0..255
        float bv = (mode == 2) ? bu2f(bias[n0 + colw]) : 0.f;
        #pragma unroll
        for (int q = 0; q < 4; q++) {
          int grow = wm * (MW * 16) + mi * 16 + hi4 + q;   // 0..BM-1
          ushort* reg = (grow < 128) ? reg0 : reg1;
          int rl = grow & 127;
          float val = acc[mi][ni][q];
          ushort h = (mode == 2) ? f2bu(fast_gelu(val + bv)) : f2bu(val);
          reg[rl * 256 + (((colw >> 3) ^ (rl & 7)) * 8) + (colw & 7)] = h;
        }
      }
    }
    __syncthreads();
    {
      const int j = tid & 31;
      const int rsub = tid >> 5;     // 0..15
      #pragma unroll
      for (int p = 0; p < BM / 16; p++) {
        int row = p * 16 + rsub;
        const ushort* reg = (row < 128) ? reg0 : reg1;
        int rl = row & 127;
        short8 v = *(const short8*)&reg[rl * 256 + ((j ^ (rl & 7)) * 8)];
        *(short8*)&Cb[(size_t)(m0 + row) * N + n0 + j * 8] = v;
      }
    }
    if (mode == 5) {
      __syncthreads();
      // plane 1: residual lo = val - bu2f(hi)
      #pragma unroll
      for (int mi = 0; mi < MW; mi++) {
        #pragma unroll
        for (int ni = 0; ni < 4; ni++) {
          int colw = wn * 64 + ni * 16 + lr;
          #pragma unroll
          for (int q = 0; q < 4; q++) {
            int grow = wm * (MW * 16) + mi * 16 + hi4 + q;
            ushort* reg = (grow < 128) ? reg0 : reg1;
            int rl = grow & 127;
            float val = acc[mi][ni][q];
            ushort h = f2bu(val);
            reg[rl * 256 + (((colw >> 3) ^ (rl & 7)) * 8) + (colw & 7)] = f2bu(val - bu2f(h));
          }
        }
      }
      __syncthreads();
      const int j = tid & 31;
      const int rsub = tid >> 5;
      #pragma unroll
      for (int p = 0; p < BM / 16; p++) {
        int row = p * 16 + rsub;
        const ushort* reg = (row < 128) ? reg0 : reg1;
        int rl = row & 127;
        short8 v = *(const short8*)&reg[rl * 256 + ((j ^ (rl & 7)) * 8)];
        *(short8*)&Cb2[(size_t)(m0 + row) * N + n0 + j * 8] = v;
      }
    }
  }
  (void)M;
}

// ---------------- MFMA bucket: consumes qk hi/lo bf16 planes; in-register first-max argmax ----------------
__global__ __launch_bounds__(256) void k_bucket_mfma(const ushort* __restrict__ qkh, const ushort* __restrict__ qkl,
                                                     const ushort* __restrict__ rotT, int* __restrict__ bkt) {
  __shared__ alignas(16) ushort Bs[128*128];  // rotT [n][k]  32 KB
  __shared__ alignas(16) ushort Ah[64*128];   // Q hi         16 KB
  __shared__ alignas(16) ushort Al[64*128];   // Q lo         16 KB
  const int tid = threadIdx.x;
  const int lane = tid & 63, wave = tid >> 6;
  const int lr = lane & 15, lk = (lane >> 4) * 8;
  const int tt = blockIdx.x * 64;
  const int bh = blockIdx.y;
  const int b = bh >> 3, hh = bh & 7;

  {
    int r = tid >> 2, c0 = (tid & 3) * 32;
    size_t base = ((size_t)(b * kT + tt + r)) * kDim + hh * 128 + c0;
    const uint4* sh = (const uint4*)(qkh + base);
    const uint4* sl = (const uint4*)(qkl + base);
    uint4* dh = (uint4*)&Ah[r * 128 + c0];
    uint4* dl = (uint4*)&Al[r * 128 + c0];
    #pragma unroll
    for (int i = 0; i < 4; i++) { dh[i] = sh[i]; dl[i] = sl[i]; }
  }
  {
    const uint4* src = (const uint4*)rotT;
    uint4* dst = (uint4*)Bs;
    for (int i = tid; i < 2048; i += 256) dst[i] = src[i];
  }
  __syncthreads();

  floatx4 acc[4][2];
  #pragma unroll
  for (int mi = 0; mi < 4; mi++) { acc[mi][0] = (floatx4){0,0,0,0}; acc[mi][1] = (floatx4){0,0,0,0}; }
  #pragma unroll
  for (int ks = 0; ks < 4; ks++) {
    short8 a[4], bb[2];
    #pragma unroll
    for (int ni = 0; ni < 2; ni++) bb[ni] = *(const short8*)&Bs[(wave*32 + ni*16 + lr)*128 + ks*32 + lk];
    #pragma unroll
    for (int mi = 0; mi < 4; mi++) a[mi] = *(const short8*)&Ah[(mi*16 + lr)*128 + ks*32 + lk];
    #pragma unroll
    for (int mi = 0; mi < 4; mi++)
      #pragma unroll
      for (int ni = 0; ni < 2; ni++)
        acc[mi][ni] = __builtin_amdgcn_mfma_f32_16x16x32_bf16(a[mi], bb[ni], acc[mi][ni], 0, 0, 0);
  }
  #pragma unroll
  for (int ks = 0; ks < 4; ks++) {
    short8 a[4], bb[2];
    #pragma unroll
    for (int ni = 0; ni < 2; ni++) bb[ni] = *(const short8*)&Bs[(wave*32 + ni*16 + lr)*128 + ks*32 + lk];
    #pragma unroll
    for (int mi = 0; mi < 4; mi++) a[mi] = *(const short8*)&Al[(mi*16 + lr)*128 + ks*32 + lk];
    #pragma unroll
    for (int mi = 0; mi < 4; mi++)
      #pragma unroll
      for (int ni = 0; ni < 2; ni++)
        acc[mi][ni] = __builtin_amdgcn_mfma_f32_16x16x32_bf16(a[mi], bb[ni], acc[mi][ni], 0, 0, 0);
  }

  #pragma unroll
  for (int mi = 0; mi < 4; mi++) {
    #pragma unroll
    for (int q = 0; q < 4; q++) {
      float v0 = acc[mi][0][q];
      float v1 = acc[mi][1][q];
      float best = v0; int bidx = lr;
      if (v1  > best) { best = v1;  bidx = 16 + lr; }
      if (-v0 > best) { best = -v0; bidx = 32 + lr; }
      if (-v1 > best) { best = -v1; bidx = 48 + lr; }
      #pragma unroll
      for (int m = 1; m <= 8; m <<= 1) {
        float ov = __shfl_xor(best, m);
        int   oi = __shfl_xor(bidx, m);
        if (ov > best || (ov == best && oi < bidx)) { best = ov; bidx = oi; }
      }
      if (lr == 0) {
        int row = mi*16 + ((lane >> 4) & 3)*4 + q;
        bkt[(bh*4 + wave)*4096 + tt + row] = bidx;
      }
    }
  }
}

// ---------------- stable counting sort per (bh,hash) ----------------
__global__ __launch_bounds__(256) void k_sort(const int* __restrict__ bkt, int* __restrict__ st) {
  __shared__ unsigned char  hist[64*256];
  __shared__ unsigned short offs[64*256];
  __shared__ int base[64];
  int tid = threadIdx.x, grp = blockIdx.x;
  const int* bk = bkt + grp * 4096;
  for (int i = tid; i < 64*256; i += 256) hist[i] = 0;
  __syncthreads();
  int myb[16];
  #pragma unroll
  for (int j = 0; j < 16; j++) {
    myb[j] = bk[tid*16 + j];
    hist[myb[j]*256 + tid] += 1;
  }
  __syncthreads();
  if (tid < 64) {
    int run = 0;
    for (int t = 0; t < 256; t++) { offs[tid*256 + t] = (unsigned short)run; run += hist[tid*256 + t]; }
    base[tid] = run;
  }
  __syncthreads();
  if (tid == 0) {
    int run = 0;
    for (int b2 = 0; b2 < 64; b2++) { int c = base[b2]; base[b2] = run; run += c; }
  }
  __syncthreads();
  #pragma unroll
  for (int j = 0; j < 16; j++) {
    int b2 = myb[j];
    int r = 0;
    for (int jj = 0; jj < j; jj++) r += (myb[jj] == b2) ? 1 : 0;
    st[grp*4096 + base[b2] + (int)offs[b2*256 + tid] + r] = tid*16 + j;
  }
}

// ---------------- chunked LSH attention (bf16 qk hi-plane input) ----------------
__global__ __launch_bounds__(256) void k_attn(const ushort* __restrict__ qkh, const ushort* __restrict__ vbuf,
                                              const int* __restrict__ st, ushort* __restrict__ o_r,
                                              float* __restrict__ lse_r) {
  __shared__ alignas(16) ushort KV[128*136];
  __shared__ alignas(16) ushort Ps[64*136];
  __shared__ float rnorm[128];
  __shared__ int   kposs[128];
  __shared__ float red1[64*4];
  __shared__ float red2[64*4];
  __shared__ float lrow[64];

  const int tid = threadIdx.x;
  const int bid = blockIdx.x;
  const int bh = bid >> 8;
  const int c  = bid & 255;
  const int h  = c >> 6;
  const int cprev = (c + 255) & 255;
  const int b  = bh >> 3, hh = bh & 7;
  const int lane = tid & 63, wave = tid >> 6;
  const int lr = lane & 15, lk = (lane >> 4) * 8;

  {
    int j = tid >> 1, half = tid & 1;
    int slot = (j < 64) ? (c*64 + j) : (cprev*64 + (j - 64));
    int pos = st[bh*16384 + slot];
    if (half == 0) kposs[j] = pos;
    const ushort* src = qkh + ((size_t)(b * kT + pos)) * kDim + hh*128 + half*64;
    float ss = 0.f;
    #pragma unroll
    for (int i2 = 0; i2 < 64; i2 += 8) {
      uint4 u = *(const uint4*)(src + i2);
      *(uint4*)&KV[j*136 + half*64 + i2] = u;
      float f0 = bu2f((ushort)(u.x & 0xffffu)), f1 = bu2f((ushort)(u.x >> 16));
      float f2 = bu2f((ushort)(u.y & 0xffffu)), f3 = bu2f((ushort)(u.y >> 16));
      float f4 = bu2f((ushort)(u.z & 0xffffu)), f5 = bu2f((ushort)(u.z >> 16));
      float f6 = bu2f((ushort)(u.w & 0xffffu)), f7 = bu2f((ushort)(u.w >> 16));
      ss += f0*f0 + f1*f1 + f2*f2 + f3*f3 + f4*f4 + f5*f5 + f6*f6 + f7*f7;
    }
    ss += __shfl_xor(ss, 1);
    if (half == 0) rnorm[j] = 1.f / fmaxf(sqrtf(ss), 1e-12f);
  }
  __syncthreads();

  {
    floatx4 acc[4][2];
    #pragma unroll
    for (int mi = 0; mi < 4; mi++) { acc[mi][0] = (floatx4){0,0,0,0}; acc[mi][1] = (floatx4){0,0,0,0}; }
    #pragma unroll
    for (int ks = 0; ks < 4; ks++) {
      short8 a[4], bb[2];
      #pragma unroll
      for (int mi = 0; mi < 4; mi++) a[mi]  = *(const short8*)&KV[(mi*16 + lr)*136 + ks*32 + lk];
      #pragma unroll
      for (int ni = 0; ni < 2; ni++) bb[ni] = *(const short8*)&KV[(wave*32 + ni*16 + lr)*136 + ks*32 + lk];
      #pragma unroll
      for (int mi = 0; mi < 4; mi++)
        #pragma unroll
        for (int ni = 0; ni < 2; ni++)
          acc[mi][ni] = __builtin_amdgcn_mfma_f32_16x16x32_bf16(a[mi], bb[ni], acc[mi][ni], 0, 0, 0);
    }
    #pragma unroll
    for (int mi = 0; mi < 4; mi++) {
      #pragma unroll
      for (int ni = 0; ni < 2; ni++) {
        int col = wave*32 + ni*16 + lr;
        float rn = rnorm[col] * kScale;
        int cpos = kposs[col];
        #pragma unroll
        for (int q = 0; q < 4; q++) {
          int row = mi*16 + (lane >> 4)*4 + q;
          float val = acc[mi][ni][q] * rn;
          if (cpos == kposs[row]) val = kSelfVal;
          Ps[row*136 + col] = f2bu(val);
        }
      }
    }
  }
  __syncthreads();

  {
    int j = tid >> 1, half = tid & 1;
    int pos = kposs[j];
    const ushort* src = vbuf + ((size_t)(b * kT + pos)) * kDim + hh*128 + half*64;
    #pragma unroll
    for (int i2 = 0; i2 < 64; i2 += 8) {
      uint4 u = *(const uint4*)(src + i2);
      int d0 = half*64 + i2;
      KV[(d0+0)*136 + j] = (ushort)(u.x & 0xffffu); KV[(d0+1)*136 + j] = (ushort)(u.x >> 16);
      KV[(d0+2)*136 + j] = (ushort)(u.y & 0xffffu); KV[(d0+3)*136 + j] = (ushort)(u.y >> 16);
      KV[(d0+4)*136 + j] = (ushort)(u.z & 0xffffu); KV[(d0+5)*136 + j] = (ushort)(u.z >> 16);
      KV[(d0+6)*136 + j] = (ushort)(u.w & 0xffffu); KV[(d0+7)*136 + j] = (ushort)(u.w >> 16);
    }
  }

  {
    int i = tid >> 2, part = tid & 3;
    const int jb = part * 32;
    float m = -1e30f;
    for (int j2 = 0; j2 < 32; j2++) m = fmaxf(m, bu2f(Ps[i*136 + jb + j2]));
    red1[i*4 + part] = m;
    __syncthreads();
    m = fmaxf(fmaxf(red1[i*4+0], red1[i*4+1]), fmaxf(red1[i*4+2], red1[i*4+3]));
    float ssum = 0.f;
    for (int j2 = 0; j2 < 32; j2++) {
      float arg = fmaxf(fminf(bu2f(Ps[i*136 + jb + j2]) - m, 0.f), -80.f);
      float p = __expf(arg);
      ssum += p;
      Ps[i*136 + jb + j2] = f2bu(p);
    }
    red2[i*4 + part] = ssum;
    __syncthreads();
    if (part == 0) {
      float l = fmaxf(red2[i*4+0] + red2[i*4+1] + red2[i*4+2] + red2[i*4+3], 1e-20f);
      lrow[i] = 1.f / l;
      lse_r[(size_t)(bh*4 + h)*4096 + kposs[i]] = m + __logf(l);
    }
  }
  __syncthreads();

  {
    floatx4 acc[4][2];
    #pragma unroll
    for (int mi = 0; mi < 4; mi++) { acc[mi][0] = (floatx4){0,0,0,0}; acc[mi][1] = (floatx4){0,0,0,0}; }
    #pragma unroll
    for (int ks = 0; ks < 4; ks++) {
      short8 a[4], bb[2];
      #pragma unroll
      for (int mi = 0; mi < 4; mi++) a[mi]  = *(const short8*)&Ps[(mi*16 + lr)*136 + ks*32 + lk];
      #pragma unroll
      for (int ni = 0; ni < 2; ni++) bb[ni] = *(const short8*)&KV[(wave*32 + ni*16 + lr)*136 + ks*32 + lk];
      #pragma unroll
      for (int mi = 0; mi < 4; mi++)
        #pragma unroll
        for (int ni = 0; ni < 2; ni++)
          acc[mi][ni] = __builtin_amdgcn_mfma_f32_16x16x32_bf16(a[mi], bb[ni], acc[mi][ni], 0, 0, 0);
    }
    #pragma unroll
    for (int mi = 0; mi < 4; mi++) {
      #pragma unroll
      for (int ni = 0; ni < 2; ni++) {
        int d = wave*32 + ni*16 + lr;
        #pragma unroll
        for (int q = 0; q < 4; q++) {
          int row = mi*16 + (lane >> 4)*4 + q;
          float o = acc[mi][ni][q] * lrow[row];
          o_r[((size_t)(bh*4 + h)*4096 + kposs[row])*128 + d] = f2bu(o);
        }
      }
    }
  }
}

// ---------------- combine hash rounds ----------------
__global__ __launch_bounds__(256) void k_combine(const ushort* __restrict__ o_r, const float* __restrict__ lse_r,
                                                 ushort* __restrict__ attnbf) {
  int rid = blockIdx.x * 2 + (threadIdx.x >> 7);
  int d = threadIdx.x & 127;
  int bh = rid >> 12, t = rid & 4095;
  int b = bh >> 3, hh = bh & 7;
  size_t base = (size_t)bh * 16384 + t;
  float l0 = lse_r[base], l1 = lse_r[base + 4096], l2 = lse_r[base + 8192], l3 = lse_r[base + 12288];
  float M = fmaxf(fmaxf(l0, l1), fmaxf(l2, l3));
  float e0 = __expf(fmaxf(fminf(l0 - M, 0.f), -80.f));
  float e1 = __expf(fmaxf(fminf(l1 - M, 0.f), -80.f));
  float e2 = __expf(fmaxf(fminf(l2 - M, 0.f), -80.f));
  float e3 = __expf(fmaxf(fminf(l3 - M, 0.f), -80.f));
  float inv = 1.f / (e0 + e1 + e2 + e3);
  float o = e0 * bu2f(o_r[(base         )*128 + d]) + e1 * bu2f(o_r[(base +  4096)*128 + d])
          + e2 * bu2f(o_r[(base +  8192)*128 + d]) + e3 * bu2f(o_r[(base + 12288)*128 + d]);
  attnbf[((size_t)b * kT + t) * kDim + hh*128 + d] = f2bu(o * inv);
}

extern "C" void kernel_launch(void* const* d_in, const int* in_sizes, int n_in,
                              void* d_out, int out_size, void* d_ws, size_t ws_size,
                              hipStream_t stream) {
  (void)in_sizes; (void)n_in; (void)out_size; (void)ws_size;
  const void* x     = d_in[0];
  const void* ln1_g = d_in[1];
  const void* ln1_b = d_in[2];
  const void* Wqk   = d_in[3];
  const void* Wv    = d_in[4];
  const void* Wo    = d_in[5];
  const void* bo    = d_in[6];
  const void* ln2_g = d_in[7];
  const void* ln2_b = d_in[8];
  const void* W1    = d_in[9];
  const void* b1    = d_in[10];
  const void* W2    = d_in[11];
  const void* b2    = d_in[12];
  const void* rot   = d_in[13];

  char* w = (char*)d_ws;
  int*    flag = (int*)w;    w += 256;
  ushort* prm  = (ushort*)w; w += 131072;
  float* x1  = (float*)w;  w += 33554432;
  float* x2  = (float*)w;  w += 33554432;
  ushort* qkh = (ushort*)w; w += 16777216;
  ushort* qkl = (ushort*)w; w += 16777216;
  ushort* vbb = (ushort*)w; w += 16777216;
  ushort* xbf = (ushort*)w; w += 16777216;
  ushort* orb = (ushort*)w; w += 67108864;
  float* lse = (float*)w;  w += 1048576;
  int*   bkt = (int*)w;    w += 1048576;
  int*   stb = (int*)w;    w += 1048576;
  ushort* wtA = (ushort*)w; w += 2097152;
  ushort* wtB = (ushort*)w; w += 2097152;
  ushort* wtC = (ushort*)w; w += 2097152;
  ushort* wt1 = (ushort*)w; w += 8388608;
  ushort* wt2 = (ushort*)w; w += 8388608;
  ushort* rtT = (ushort*)w; w += 32768;

  ushort* pLN1G = prm + 0;     ushort* pLN1B = prm + 2048;
  ushort* pBO   = prm + 4096;  ushort* pLN2G = prm + 6144;
  ushort* pLN2B = prm + 8192;  ushort* pB1   = prm + 10240;
  ushort* pB2   = prm + 18432; ushort* pROT  = prm + 20480;

  k_detect<<<1, 256, 0, stream>>>((const unsigned*)x, flag);
  k_cvt<<<8,   256, 0, stream>>>(flag, ln1_g, pLN1G, 2048);
  k_cvt<<<8,   256, 0, stream>>>(flag, ln1_b, pLN1B, 2048);
  k_cvt<<<8,   256, 0, stream>>>(flag, bo,    pBO,   2048);
  k_cvt<<<8,   256, 0, stream>>>(flag, ln2_g, pLN2G, 2048);
  k_cvt<<<8,   256, 0, stream>>>(flag, ln2_b, pLN2B, 2048);
  k_cvt<<<32,  256, 0, stream>>>(flag, b1,    pB1,   8192);
  k_cvt<<<8,   256, 0, stream>>>(flag, b2,    pB2,   2048);
  k_cvt<<<128, 256, 0, stream>>>(flag, rot,   pROT,  32768);
  k_init_any<<<8192, 256, 0, stream>>>(flag, x, x1, x2);

  for (int d = 0; d < 2; d++) {
    k_transpose2<<<dim3(32, 32),  256, 0, stream>>>(flag,
        (const char*)Wqk + (size_t)d*1048576*2, (const char*)Wqk + (size_t)d*1048576*4, wtA, 1024, 1024);
    k_transpose2<<<dim3(32, 32),  256, 0, stream>>>(flag,
        (const char*)Wv  + (size_t)d*1048576*2, (const char*)Wv  + (size_t)d*1048576*4, wtB, 1024, 1024);
    k_transpose2<<<dim3(32, 32),  256, 0, stream>>>(flag,
        (const char*)Wo  + (size_t)d*1048576*2, (const char*)Wo  + (size_t)d*1048576*4, wtC, 1024, 1024);
    k_transpose2<<<dim3(128, 32), 256, 0, stream>>>(flag,
        (const char*)W1  + (size_t)d*4194304*2, (const char*)W1  + (size_t)d*4194304*4, wt1, 1024, 4096);
    k_transpose2<<<dim3(32, 128), 256, 0, stream>>>(flag,
        (const char*)W2  + (size_t)d*4194304*2, (const char*)W2  + (size_t)d*4194304*4, wt2, 4096, 1024);
    k_rot_t<<<1, 256, 0, stream>>>(pROT + (size_t)d * 16384, rtT);

    k_ln<<<8192, 256, 0, stream>>>(x2, pLN1G + d*1024, pLN1B + d*1024, xbf);
    k_gemm5<4><<<dim3(4, 64), 512, 0, stream>>>(xbf, wtA, nullptr, nullptr, qkh, qkl, 8192, 1024, 1024, 5);
    k_gemm5<4><<<dim3(4, 64), 512, 0, stream>>>(xbf, wtB, nullptr, nullptr, vbb, nullptr, 8192, 1024, 1024, 3);
    k_bucket_mfma<<<dim3(64, 16), 256, 0, stream>>>(qkh, qkl, rtT, bkt);
    k_sort<<<64, 256, 0, stream>>>(bkt, stb);
    k_attn<<<4096, 256, 0, stream>>>(qkh, vbb, stb, orb, lse);
    k_combine<<<32768, 256, 0, stream>>>(orb, lse, xbf);
    k_gemm5<4><<<dim3(4, 64), 512, 0, stream>>>(xbf, wtC, pBO + d*1024, x1, nullptr, nullptr, 8192, 1024, 1024, 1);
    k_ln<<<8192, 256, 0, stream>>>(x1, pLN2G + d*1024, pLN2B + d*1024, xbf);
    k_gemm5<8><<<dim3(16, 32), 512, 0, stream>>>(xbf, wt1, pB1 + d*4096, nullptr, orb, nullptr, 8192, 4096, 1024, 2);
    k_gemm5<4><<<dim3(4, 64), 512, 0, stream>>>(orb, wt2, pB2 + d*1024, x2, nullptr, nullptr, 8192, 1024, 4096, 1);
  }
  k_final_any<<<8192, 256, 0, stream>>>(flag, x1, x2, d_out);
}

// Round 8
// 1108.027 us; speedup vs baseline: 1.4037x; 1.0004x over previous
//
#include <hip/hip_runtime.h>
#include <hip/hip_bf16.h>
#include <cmath>

using bf16 = __hip_bfloat16;
typedef __attribute__((ext_vector_type(8))) short short8;
typedef __attribute__((ext_vector_type(4))) float floatx4;

__device__ __forceinline__ float bu2f(ushort u) { return __uint_as_float((unsigned)u << 16); }
__device__ __forceinline__ ushort f2bu(float f) {
  union { bf16 b; ushort u; } cv; cv.b = __float2bfloat16(f); return cv.u;
}
__device__ __forceinline__ void gl_lds16(const ushort* g, ushort* l) {
  __builtin_amdgcn_global_load_lds((const __attribute__((address_space(1))) unsigned*)g,
                                   (__attribute__((address_space(3))) unsigned*)l, 16, 0, 0);
}
// tanh-form GELU via hw exp; |err vs erf-GELU| ~2e-4, below bf16 output quantization
__device__ __forceinline__ float fast_gelu(float x) {
  float z = 0.7978845608028654f * (x + 0.044715f * x * x * x);
  z = fmaxf(fminf(z, 10.f), -10.f);
  float e = __expf(2.f * z);
  float t = (e - 1.f) / (e + 1.f);
  return 0.5f * x * (1.f + t);
}

static constexpr int kT   = 4096;
static constexpr int kDim = 1024;
static constexpr float kScale   = 0.08838834764831845f;  // 1/sqrt(128)
static constexpr float kSelfVal = -5.0e4f;

// ---------------- dtype detector: bf16 vs fp32 inputs ----------------
__device__ __forceinline__ int sane_v(float f) { float a = fabsf(f); return (a > 1e-4f && a < 1e4f) ? 1 : 0; }

__global__ __launch_bounds__(256) void k_detect(const unsigned* __restrict__ x, int* __restrict__ flag) {
  __shared__ int cnt;
  int tid = threadIdx.x;
  if (tid == 0) cnt = 0;
  __syncthreads();
  int my = 0;
  const uint4* p = (const uint4*)x;
  for (int q = 0; q < 16; q++) {
    uint4 u = p[tid * 16 + q];
    my += sane_v(__uint_as_float(u.x << 16)) + sane_v(__uint_as_float(u.x & 0xffff0000u));
    my += sane_v(__uint_as_float(u.y << 16)) + sane_v(__uint_as_float(u.y & 0xffff0000u));
    my += sane_v(__uint_as_float(u.z << 16)) + sane_v(__uint_as_float(u.z & 0xffff0000u));
    my += sane_v(__uint_as_float(u.w << 16)) + sane_v(__uint_as_float(u.w & 0xffff0000u));
  }
  atomicAdd(&cnt, my);
  __syncthreads();
  if (tid == 0) flag[0] = (cnt >= 24576) ? 1 : 0;
}

__global__ __launch_bounds__(256) void k_cvt(const int* __restrict__ flag, const void* __restrict__ src,
                                             ushort* __restrict__ dst, int n) {
  int i = blockIdx.x * 256 + threadIdx.x;
  if (i >= n) return;
  dst[i] = (*flag) ? ((const ushort*)src)[i] : f2bu(((const float*)src)[i]);
}

__global__ __launch_bounds__(256) void k_init_any(const int* __restrict__ flag, const void* __restrict__ x,
                                                  float* __restrict__ x1, float* __restrict__ x2) {
  int i = blockIdx.x * 1024 + threadIdx.x * 4;
  float4 f;
  if (*flag) {
    ushort4 u = *(const ushort4*)((const ushort*)x + i);
    f.x = bu2f(u.x); f.y = bu2f(u.y); f.z = bu2f(u.z); f.w = bu2f(u.w);
  } else {
    f = *(const float4*)((const float*)x + i);
  }
  *(float4*)(x1 + i) = f;
  *(float4*)(x2 + i) = f;
}

__global__ __launch_bounds__(256) void k_final_any(const int* __restrict__ flag, const float* __restrict__ x1,
                                                   const float* __restrict__ x2, void* __restrict__ out) {
  int i = blockIdx.x * 1024 + threadIdx.x * 4;
  float4 a = *(const float4*)(x1 + i);
  float4 b = *(const float4*)(x2 + i);
  float4 s; s.x = a.x + b.x; s.y = a.y + b.y; s.z = a.z + b.z; s.w = a.w + b.w;
  if (*flag) {
    ushort4 u; u.x = f2bu(s.x); u.y = f2bu(s.y); u.z = f2bu(s.z); u.w = f2bu(s.w);
    *(ushort4*)((ushort*)out + i) = u;
  } else {
    *(float4*)((float*)out + i) = s;
  }
}

// ---------------- layernorm: fp32 in -> bf16 out ----------------
__global__ __launch_bounds__(256) void k_ln(const float* __restrict__ x, const ushort* __restrict__ g,
                                            const ushort* __restrict__ be, ushort* __restrict__ out) {
  __shared__ float ws[4], ws2[4];
  int row = blockIdx.x, tid = threadIdx.x;
  const float* xr = x + (size_t)row * kDim + tid * 4;
  float4 v = *(const float4*)xr;
  float s  = v.x + v.y + v.z + v.w;
  float s2 = v.x*v.x + v.y*v.y + v.z*v.z + v.w*v.w;
  #pragma unroll
  for (int off = 32; off; off >>= 1) { s += __shfl_down(s, off); s2 += __shfl_down(s2, off); }
  int wave = tid >> 6, lane = tid & 63;
  if (lane == 0) { ws[wave] = s; ws2[wave] = s2; }
  __syncthreads();
  s  = ws[0] + ws[1] + ws[2] + ws[3];
  s2 = ws2[0] + ws2[1] + ws2[2] + ws2[3];
  float mean = s * (1.f/1024.f);
  float var  = fmaxf(s2 * (1.f/1024.f) - mean*mean, 0.f);
  float rstd = rsqrtf(var + 1e-5f);
  int cb = tid * 4;
  ushort* o = out + (size_t)row * kDim + cb;
  o[0] = f2bu((v.x - mean) * rstd * bu2f(g[cb+0]) + bu2f(be[cb+0]));
  o[1] = f2bu((v.y - mean) * rstd * bu2f(g[cb+1]) + bu2f(be[cb+1]));
  o[2] = f2bu((v.z - mean) * rstd * bu2f(g[cb+2]) + bu2f(be[cb+2]));
  o[3] = f2bu((v.w - mean) * rstd * bu2f(g[cb+3]) + bu2f(be[cb+3]));
}

// ---------------- dual-dtype weight transpose: in[K,N] -> out[N,K] ----------------
__global__ __launch_bounds__(256) void k_transpose2(const int* __restrict__ flag, const void* __restrict__ src_bf,
                                                    const void* __restrict__ src_f, ushort* __restrict__ out,
                                                    int K, int N) {
  __shared__ ushort tile[32][33];
  int isbf = *flag;
  int nb = blockIdx.x * 32, kb = blockIdx.y * 32;
  int tx = threadIdx.x & 31, ty = threadIdx.x >> 5;
  for (int r = ty; r < 32; r += 8) {
    size_t idx = (size_t)(kb + r) * N + nb + tx;
    tile[r][tx] = isbf ? ((const ushort*)src_bf)[idx] : f2bu(((const float*)src_f)[idx]);
  }
  __syncthreads();
  for (int r = ty; r < 32; r += 8) out[(size_t)(nb + r) * K + kb + tx] = tile[tx][r];
}

// ---------------- rot transpose: rot[k=128][n=128] -> rotT[n=128][k=128] ----------------
__global__ __launch_bounds__(256) void k_rot_t(const ushort* __restrict__ rot, ushort* __restrict__ rotT) {
  int tid = threadIdx.x;
  for (int idx = tid; idx < 16384; idx += 256) {
    int n = idx >> 7, k = idx & 127;
    rotT[idx] = rot[k * 128 + n];
  }
}

// ---------------- k_gemm6: occupancy-first pipelined GEMM (m97 regime + counted vmcnt) ----------------
// 128x128 tile, BK=32, 256 thr = 4 waves (2M x 2N), wave tile 64x64, 16 MFMA/phase.
// LDS: 3 rotating buffers x (128x32) for A and B = 24+24 = 48 KB -> **3 blocks/CU**
// (launch_bounds(256,3)). Rounds 2-7 ran 1 block/CU (96-144 KB LDS): every vmcnt/
// barrier stall was exposed (3750 cy/phase vs ~600 compute floor, MfmaUtil 26-29%).
// m97/m114 evidence: ~3 blocks/CU of implicit cross-block overlap is what buys
// 37%+ MfmaUtil / ~900 TF, more than any source-level schedule at 1 block/CU.
// Phase kt: { 8 ds_read_b128 (buf kt%3) | stage kt+2 (4 gl_lds -> buf (kt+2)%3)
//   | setprio + 16 MFMA } -> lgkmcnt(0) -> vmcnt(4) -> s_barrier -> fence.
// RAW: tile kt's loads validated by vmcnt(4) at end of kt-1 (outstanding kt,kt+1 ->
//   leave 4 = kt+1's -> kt landed; barrier publishes). WAR: stage target (kt+2)%3 =
//   (kt-1)%3, read in phase kt-1 and lgkm-drained before that phase's barrier; stage
//   issued after it. Steady state 8 in flight, wait to 4 (never 0). Tail stages are
//   clamped dummies into dead buffers (uniform counts); vmcnt(0)+sync before epilogue.
// Swizzle: LDS slot s of row r holds global chunk s^((r>>1)&3) (source-side XOR);
// reads recover with same XOR; quarter-wave aliasing 2-way = free (SQ_LDS_BANK_CONFLICT=0).
// mode 1: Cf += A@B + bias (scalar float RMW)  mode 2: Cb = bf16(gelu(A@B+bias))
// mode 3: Cb = bf16(A@B)   mode 5: Cb = hi(A@B), Cb2 = lo(A@B)  (LDS-bounce stores,
// split across SBu rows 0-95 / SAu rows 96-127).
__global__ __launch_bounds__(256, 3) void k_gemm6(const ushort* __restrict__ A, const ushort* __restrict__ Bt,
                                                  const ushort* __restrict__ bias, float* __restrict__ Cf,
                                                  ushort* __restrict__ Cb, ushort* __restrict__ Cb2,
                                                  int M, int N, int K, int mode) {
  __shared__ alignas(16) ushort SAu[3 * 128 * 32];   // 24 KB
  __shared__ alignas(16) ushort SBu[3 * 128 * 32];   // 24 KB
  const int tid  = threadIdx.x;
  const int lane = tid & 63, wave = tid >> 6;        // 4 waves
  const int lr = lane & 15, g = lane >> 4;
  const int wm = wave >> 1, wn = wave & 1;

  // XCD-aware bijective block swizzle (all grids here have nwg % 8 == 0)
  const int nbx = gridDim.x;
  const int nwg = nbx * gridDim.y;
  const int bid = blockIdx.y * nbx + blockIdx.x;
  const int swz = (bid & 7) * (nwg >> 3) + (bid >> 3);
  const int m0 = (swz / nbx) * 128;
  const int n0 = (swz % nbx) * 128;
  const int NT = K >> 5;

  // per-thread staging sources (source col-chunk pre-swizzled, LDS dest linear)
  const ushort* srcA[2];
  const ushort* srcB[2];
  #pragma unroll
  for (int j = 0; j < 2; j++) {
    int chunk = wave * 128 + j * 64 + lane;          // 0..511
    int row = chunk >> 2, c = chunk & 3;
    int cs = c ^ ((row >> 1) & 3);
    srcA[j] = A  + (size_t)(m0 + row) * K + cs * 8;
    srcB[j] = Bt + (size_t)(n0 + row) * K + cs * 8;
  }

  // fragment read offsets (loop-invariant; ushort units)
  int offA[4], offB[4];
  #pragma unroll
  for (int mi = 0; mi < 4; mi++) {
    int row = wm * 64 + mi * 16 + lr;
    offA[mi] = row * 32 + ((g ^ ((row >> 1) & 3)) * 8);
  }
  #pragma unroll
  for (int ni = 0; ni < 4; ni++) {
    int row = wn * 64 + ni * 16 + lr;
    offB[ni] = row * 32 + ((g ^ ((row >> 1) & 3)) * 8);
  }

  floatx4 acc[4][4];
  #pragma unroll
  for (int mi = 0; mi < 4; mi++)
    #pragma unroll
    for (int ni = 0; ni < 4; ni++) acc[mi][ni] = (floatx4){0.f, 0.f, 0.f, 0.f};

  // prologue: stage K-tiles 0,1 (NT >= 32 always here)
  #pragma unroll
  for (int p = 0; p < 2; p++) {
    #pragma unroll
    for (int j = 0; j < 2; j++) {
      gl_lds16(srcA[j] + p * 32, SAu + p * 4096 + (wave * 128 + j * 64) * 8);
      gl_lds16(srcB[j] + p * 32, SBu + p * 4096 + (wave * 128 + j * 64) * 8);
    }
  }
  asm volatile("s_waitcnt vmcnt(4)" ::: "memory");   // tile 0 landed
  __builtin_amdgcn_s_barrier();
  asm volatile("" ::: "memory");

  int cur = 0;
  for (int kt = 0; kt < NT; kt++) {
    const ushort* sa = SAu + cur * 4096;
    const ushort* sb = SBu + cur * 4096;
    int pb = cur + 2; if (pb >= 3) pb -= 3;
    const int kp = ((kt + 2 < NT) ? (kt + 2) : 0) * 32;   // dummy-clamp past NT

    // fragment reads (buf cur; validated by previous phase's vmcnt+barrier)
    short8 a[4], b[4];
    #pragma unroll
    for (int mi = 0; mi < 4; mi++) a[mi] = *(const short8*)&sa[offA[mi]];
    #pragma unroll
    for (int ni = 0; ni < 4; ni++) b[ni] = *(const short8*)&sb[offB[ni]];

    // stage tile kt+2 into its (dead, lgkm-drained) buffer
    #pragma unroll
    for (int j = 0; j < 2; j++) {
      gl_lds16(srcA[j] + kp, SAu + pb * 4096 + (wave * 128 + j * 64) * 8);
      gl_lds16(srcB[j] + kp, SBu + pb * 4096 + (wave * 128 + j * 64) * 8);
    }

    // MFMA cluster (compiler interleaves reads/MFMA and emits fine lgkmcnt)
    __builtin_amdgcn_s_setprio(1);
    #pragma unroll
    for (int mi = 0; mi < 4; mi++)
      #pragma unroll
      for (int ni = 0; ni < 4; ni++)
        acc[mi][ni] = __builtin_amdgcn_mfma_f32_16x16x32_bf16(a[mi], b[ni], acc[mi][ni], 0, 0, 0);
    __builtin_amdgcn_s_setprio(0);

    // drain own LDS reads (buffer recycle safety), then counted vmem wait
    asm volatile("s_waitcnt lgkmcnt(0)" ::: "memory");
    asm volatile("s_waitcnt vmcnt(4)" ::: "memory");   // tile kt+1 landed; kt+2 in flight
    __builtin_amdgcn_s_barrier();
    asm volatile("" ::: "memory");

    cur = (cur == 2) ? 0 : cur + 1;
  }

  // drain dummy prefetches before reusing LDS
  asm volatile("s_waitcnt vmcnt(0)" ::: "memory");
  __syncthreads();

  const int hi4 = (lane >> 4) * 4;

  if (mode == 1) {
    // scalar float RMW (64 B contiguous per quarter-wave; measured clean)
    #pragma unroll
    for (int mi = 0; mi < 4; mi++) {
      #pragma unroll
      for (int ni = 0; ni < 4; ni++) {
        int col = n0 + wn * 64 + ni * 16 + lr;
        float bv = bu2f(bias[col]);
        #pragma unroll
        for (int q = 0; q < 4; q++) {
          int r2 = m0 + wm * 64 + mi * 16 + hi4 + q;
          Cf[(size_t)r2 * N + col] += acc[mi][ni][q] + bv;
        }
      }
    }
  } else {
    // LDS-bounce epilogue: acc -> swizzled rows (0-95 in SBu, 96-127 in SAu) ->
    // coalesced dwordx4 row stores (256 B per 16-lane group).
    #pragma unroll
    for (int mi = 0; mi < 4; mi++) {
      #pragma unroll
      for (int ni = 0; ni < 4; ni++) {
        int colw = wn * 64 + ni * 16 + lr;            // 0..127
        float bv = (mode == 2) ? bu2f(bias[n0 + colw]) : 0.f;
        #pragma unroll
        for (int q = 0; q < 4; q++) {
          int rl = wm * 64 + mi * 16 + hi4 + q;       // 0..127
          ushort* rowp = (rl < 96) ? (SBu + rl * 128) : (SAu + (rl - 96) * 128);
          float val = acc[mi][ni][q];
          ushort h = (mode == 2) ? f2bu(fast_gelu(val + bv)) : f2bu(val);
          rowp[(((colw >> 3) ^ (rl & 7)) * 8) + (colw & 7)] = h;
        }
      }
    }
    __syncthreads();
    {
      const int j = tid & 15;
      const int rsub = tid >> 4;     // 0..15
      #pragma unroll
      for (int p = 0; p < 8; p++) {
        int row = p * 16 + rsub;
        const ushort* rowp = (row < 96) ? (SBu + row * 128) : (SAu + (row - 96) * 128);
        short8 v = *(const short8*)&rowp[(j ^ (row & 7)) * 8];
        *(short8*)&Cb[(size_t)(m0 + row) * N + n0 + j * 8] = v;
      }
    }
    if (mode == 5) {
      __syncthreads();
      // plane 1: residual lo = val - bu2f(hi)
      #pragma unroll
      for (int mi = 0; mi < 4; mi++) {
        #pragma unroll
        for (int ni = 0; ni < 4; ni++) {
          int colw = wn * 64 + ni * 16 + lr;
          #pragma unroll
          for (int q = 0; q < 4; q++) {
            int rl = wm * 64 + mi * 16 + hi4 + q;
            ushort* rowp = (rl < 96) ? (SBu + rl * 128) : (SAu + (rl - 96) * 128);
            float val = acc[mi][ni][q];
            ushort h = f2bu(val);
            rowp[(((colw >> 3) ^ (rl & 7)) * 8) + (colw & 7)] = f2bu(val - bu2f(h));
          }
        }
      }
      __syncthreads();
      const int j = tid & 15;
      const int rsub = tid >> 4;
      #pragma unroll
      for (int p = 0; p < 8; p++) {
        int row = p * 16 + rsub;
        const ushort* rowp = (row < 96) ? (SBu + row * 128) : (SAu + (row - 96) * 128);
        short8 v = *(const short8*)&rowp[(j ^ (row & 7)) * 8];
        *(short8*)&Cb2[(size_t)(m0 + row) * N + n0 + j * 8] = v;
      }
    }
  }
  (void)M;
}

// ---------------- MFMA bucket: consumes qk hi/lo bf16 planes; in-register first-max argmax ----------------
__global__ __launch_bounds__(256) void k_bucket_mfma(const ushort* __restrict__ qkh, const ushort* __restrict__ qkl,
                                                     const ushort* __restrict__ rotT, int* __restrict__ bkt) {
  __shared__ alignas(16) ushort Bs[128*128];  // rotT [n][k]  32 KB
  __shared__ alignas(16) ushort Ah[64*128];   // Q hi         16 KB
  __shared__ alignas(16) ushort Al[64*128];   // Q lo         16 KB
  const int tid = threadIdx.x;
  const int lane = tid & 63, wave = tid >> 6;
  const int lr = lane & 15, lk = (lane >> 4) * 8;
  const int tt = blockIdx.x * 64;
  const int bh = blockIdx.y;
  const int b = bh >> 3, hh = bh & 7;

  {
    int r = tid >> 2, c0 = (tid & 3) * 32;
    size_t base = ((size_t)(b * kT + tt + r)) * kDim + hh * 128 + c0;
    const uint4* sh = (const uint4*)(qkh + base);
    const uint4* sl = (const uint4*)(qkl + base);
    uint4* dh = (uint4*)&Ah[r * 128 + c0];
    uint4* dl = (uint4*)&Al[r * 128 + c0];
    #pragma unroll
    for (int i = 0; i < 4; i++) { dh[i] = sh[i]; dl[i] = sl[i]; }
  }
  {
    const uint4* src = (const uint4*)rotT;
    uint4* dst = (uint4*)Bs;
    for (int i = tid; i < 2048; i += 256) dst[i] = src[i];
  }
  __syncthreads();

  floatx4 acc[4][2];
  #pragma unroll
  for (int mi = 0; mi < 4; mi++) { acc[mi][0] = (floatx4){0,0,0,0}; acc[mi][1] = (floatx4){0,0,0,0}; }
  #pragma unroll
  for (int ks = 0; ks < 4; ks++) {
    short8 a[4], bb[2];
    #pragma unroll
    for (int ni = 0; ni < 2; ni++) bb[ni] = *(const short8*)&Bs[(wave*32 + ni*16 + lr)*128 + ks*32 + lk];
    #pragma unroll
    for (int mi = 0; mi < 4; mi++) a[mi] = *(const short8*)&Ah[(mi*16 + lr)*128 + ks*32 + lk];
    #pragma unroll
    for (int mi = 0; mi < 4; mi++)
      #pragma unroll
      for (int ni = 0; ni < 2; ni++)
        acc[mi][ni] = __builtin_amdgcn_mfma_f32_16x16x32_bf16(a[mi], bb[ni], acc[mi][ni], 0, 0, 0);
  }
  #pragma unroll
  for (int ks = 0; ks < 4; ks++) {
    short8 a[4], bb[2];
    #pragma unroll
    for (int ni = 0; ni < 2; ni++) bb[ni] = *(const short8*)&Bs[(wave*32 + ni*16 + lr)*128 + ks*32 + lk];
    #pragma unroll
    for (int mi = 0; mi < 4; mi++) a[mi] = *(const short8*)&Al[(mi*16 + lr)*128 + ks*32 + lk];
    #pragma unroll
    for (int mi = 0; mi < 4; mi++)
      #pragma unroll
      for (int ni = 0; ni < 2; ni++)
        acc[mi][ni] = __builtin_amdgcn_mfma_f32_16x16x32_bf16(a[mi], bb[ni], acc[mi][ni], 0, 0, 0);
  }

  #pragma unroll
  for (int mi = 0; mi < 4; mi++) {
    #pragma unroll
    for (int q = 0; q < 4; q++) {
      float v0 = acc[mi][0][q];
      float v1 = acc[mi][1][q];
      float best = v0; int bidx = lr;
      if (v1  > best) { best = v1;  bidx = 16 + lr; }
      if (-v0 > best) { best = -v0; bidx = 32 + lr; }
      if (-v1 > best) { best = -v1; bidx = 48 + lr; }
      #pragma unroll
      for (int m = 1; m <= 8; m <<= 1) {
        float ov = __shfl_xor(best, m);
        int   oi = __shfl_xor(bidx, m);
        if (ov > best || (ov == best && oi < bidx)) { best = ov; bidx = oi; }
      }
      if (lr == 0) {
        int row = mi*16 + ((lane >> 4) & 3)*4 + q;
        bkt[(bh*4 + wave)*4096 + tt + row] = bidx;
      }
    }
  }
}

// ---------------- stable counting sort per (bh,hash) ----------------
__global__ __launch_bounds__(256) void k_sort(const int* __restrict__ bkt, int* __restrict__ st) {
  __shared__ unsigned char  hist[64*256];
  __shared__ unsigned short offs[64*256];
  __shared__ int base[64];
  int tid = threadIdx.x, grp = blockIdx.x;
  const int* bk = bkt + grp * 4096;
  for (int i = tid; i < 64*256; i += 256) hist[i] = 0;
  __syncthreads();
  int myb[16];
  #pragma unroll
  for (int j = 0; j < 16; j++) {
    myb[j] = bk[tid*16 + j];
    hist[myb[j]*256 + tid] += 1;
  }
  __syncthreads();
  if (tid < 64) {
    int run = 0;
    for (int t = 0; t < 256; t++) { offs[tid*256 + t] = (unsigned short)run; run += hist[tid*256 + t]; }
    base[tid] = run;
  }
  __syncthreads();
  if (tid == 0) {
    int run = 0;
    for (int b2 = 0; b2 < 64; b2++) { int c = base[b2]; base[b2] = run; run += c; }
  }
  __syncthreads();
  #pragma unroll
  for (int j = 0; j < 16; j++) {
    int b2 = myb[j];
    int r = 0;
    for (int jj = 0; jj < j; jj++) r += (myb[jj] == b2) ? 1 : 0;
    st[grp*4096 + base[b2] + (int)offs[b2*256 + tid] + r] = tid*16 + j;
  }
}

// ---------------- chunked LSH attention (bf16 qk hi-plane input) ----------------
__global__ __launch_bounds__(256) void k_attn(const ushort* __restrict__ qkh, const ushort* __restrict__ vbuf,
                                              const int* __restrict__ st, ushort* __restrict__ o_r,
                                              float* __restrict__ lse_r) {
  __shared__ alignas(16) ushort KV[128*136];
  __shared__ alignas(16) ushort Ps[64*136];
  __shared__ float rnorm[128];
  __shared__ int   kposs[128];
  __shared__ float red1[64*4];
  __shared__ float red2[64*4];
  __shared__ float lrow[64];

  const int tid = threadIdx.x;
  const int bid = blockIdx.x;
  const int bh = bid >> 8;
  const int c  = bid & 255;
  const int h  = c >> 6;
  const int cprev = (c + 255) & 255;
  const int b  = bh >> 3, hh = bh & 7;
  const int lane = tid & 63, wave = tid >> 6;
  const int lr = lane & 15, lk = (lane >> 4) * 8;

  {
    int j = tid >> 1, half = tid & 1;
    int slot = (j < 64) ? (c*64 + j) : (cprev*64 + (j - 64));
    int pos = st[bh*16384 + slot];
    if (half == 0) kposs[j] = pos;
    const ushort* src = qkh + ((size_t)(b * kT + pos)) * kDim + hh*128 + half*64;
    float ss = 0.f;
    #pragma unroll
    for (int i2 = 0; i2 < 64; i2 += 8) {
      uint4 u = *(const uint4*)(src + i2);
      *(uint4*)&KV[j*136 + half*64 + i2] = u;
      float f0 = bu2f((ushort)(u.x & 0xffffu)), f1 = bu2f((ushort)(u.x >> 16));
      float f2 = bu2f((ushort)(u.y & 0xffffu)), f3 = bu2f((ushort)(u.y >> 16));
      float f4 = bu2f((ushort)(u.z & 0xffffu)), f5 = bu2f((ushort)(u.z >> 16));
      float f6 = bu2f((ushort)(u.w & 0xffffu)), f7 = bu2f((ushort)(u.w >> 16));
      ss += f0*f0 + f1*f1 + f2*f2 + f3*f3 + f4*f4 + f5*f5 + f6*f6 + f7*f7;
    }
    ss += __shfl_xor(ss, 1);
    if (half == 0) rnorm[j] = 1.f / fmaxf(sqrtf(ss), 1e-12f);
  }
  __syncthreads();

  {
    floatx4 acc[4][2];
    #pragma unroll
    for (int mi = 0; mi < 4; mi++) { acc[mi][0] = (floatx4){0,0,0,0}; acc[mi][1] = (floatx4){0,0,0,0}; }
    #pragma unroll
    for (int ks = 0; ks < 4; ks++) {
      short8 a[4], bb[2];
      #pragma unroll
      for (int mi = 0; mi < 4; mi++) a[mi]  = *(const short8*)&KV[(mi*16 + lr)*136 + ks*32 + lk];
      #pragma unroll
      for (int ni = 0; ni < 2; ni++) bb[ni] = *(const short8*)&KV[(wave*32 + ni*16 + lr)*136 + ks*32 + lk];
      #pragma unroll
      for (int mi = 0; mi < 4; mi++)
        #pragma unroll
        for (int ni = 0; ni < 2; ni++)
          acc[mi][ni] = __builtin_amdgcn_mfma_f32_16x16x32_bf16(a[mi], bb[ni], acc[mi][ni], 0, 0, 0);
    }
    #pragma unroll
    for (int mi = 0; mi < 4; mi++) {
      #pragma unroll
      for (int ni = 0; ni < 2; ni++) {
        int col = wave*32 + ni*16 + lr;
        float rn = rnorm[col] * kScale;
        int cpos = kposs[col];
        #pragma unroll
        for (int q = 0; q < 4; q++) {
          int row = mi*16 + (lane >> 4)*4 + q;
          float val = acc[mi][ni][q] * rn;
          if (cpos == kposs[row]) val = kSelfVal;
          Ps[row*136 + col] = f2bu(val);
        }
      }
    }
  }
  __syncthreads();

  {
    int j = tid >> 1, half = tid & 1;
    int pos = kposs[j];
    const ushort* src = vbuf + ((size_t)(b * kT + pos)) * kDim + hh*128 + half*64;
    #pragma unroll
    for (int i2 = 0; i2 < 64; i2 += 8) {
      uint4 u = *(const uint4*)(src + i2);
      int d0 = half*64 + i2;
      KV[(d0+0)*136 + j] = (ushort)(u.x & 0xffffu); KV[(d0+1)*136 + j] = (ushort)(u.x >> 16);
      KV[(d0+2)*136 + j] = (ushort)(u.y & 0xffffu); KV[(d0+3)*136 + j] = (ushort)(u.y >> 16);
      KV[(d0+4)*136 + j] = (ushort)(u.z & 0xffffu); KV[(d0+5)*136 + j] = (ushort)(u.z >> 16);
      KV[(d0+6)*136 + j] = (ushort)(u.w & 0xffffu); KV[(d0+7)*136 + j] = (ushort)(u.w >> 16);
    }
  }

  {
    int i = tid >> 2, part = tid & 3;
    const int jb = part * 32;
    float m = -1e30f;
    for (int j2 = 0; j2 < 32; j2++) m = fmaxf(m, bu2f(Ps[i*136 + jb + j2]));
    red1[i*4 + part] = m;
    __syncthreads();
    m = fmaxf(fmaxf(red1[i*4+0], red1[i*4+1]), fmaxf(red1[i*4+2], red1[i*4+3]));
    float ssum = 0.f;
    for (int j2 = 0; j2 < 32; j2++) {
      float arg = fmaxf(fminf(bu2f(Ps[i*136 + jb + j2]) - m, 0.f), -80.f);
      float p = __expf(arg);
      ssum += p;
      Ps[i*136 + jb + j2] = f2bu(p);
    }
    red2[i*4 + part] = ssum;
    __syncthreads();
    if (part == 0) {
      float l = fmaxf(red2[i*4+0] + red2[i*4+1] + red2[i*4+2] + red2[i*4+3], 1e-20f);
      lrow[i] = 1.f / l;
      lse_r[(size_t)(bh*4 + h)*4096 + kposs[i]] = m + __logf(l);
    }
  }
  __syncthreads();

  {
    floatx4 acc[4][2];
    #pragma unroll
    for (int mi = 0; mi < 4; mi++) { acc[mi][0] = (floatx4){0,0,0,0}; acc[mi][1] = (floatx4){0,0,0,0}; }
    #pragma unroll
    for (int ks = 0; ks < 4; ks++) {
      short8 a[4], bb[2];
      #pragma unroll
      for (int mi = 0; mi < 4; mi++) a[mi]  = *(const short8*)&Ps[(mi*16 + lr)*136 + ks*32 + lk];
      #pragma unroll
      for (int ni = 0; ni < 2; ni++) bb[ni] = *(const short8*)&KV[(wave*32 + ni*16 + lr)*136 + ks*32 + lk];
      #pragma unroll
      for (int mi = 0; mi < 4; mi++)
        #pragma unroll
        for (int ni = 0; ni < 2; ni++)
          acc[mi][ni] = __builtin_amdgcn_mfma_f32_16x16x32_bf16(a[mi], bb[ni], acc[mi][ni], 0, 0, 0);
    }
    #pragma unroll
    for (int mi = 0; mi < 4; mi++) {
      #pragma unroll
      for (int ni = 0; ni < 2; ni++) {
        int d = wave*32 + ni*16 + lr;
        #pragma unroll
        for (int q = 0; q < 4; q++) {
          int row = mi*16 + (lane >> 4)*4 + q;
          float o = acc[mi][ni][q] * lrow[row];
          o_r[((size_t)(bh*4 + h)*4096 + kposs[row])*128 + d] = f2bu(o);
        }
      }
    }
  }
}

// ---------------- combine hash rounds ----------------
__global__ __launch_bounds__(256) void k_combine(const ushort* __restrict__ o_r, const float* __restrict__ lse_r,
                                                 ushort* __restrict__ attnbf) {
  int rid = blockIdx.x * 2 + (threadIdx.x >> 7);
  int d = threadIdx.x & 127;
  int bh = rid >> 12, t = rid & 4095;
  int b = bh >> 3, hh = bh & 7;
  size_t base = (size_t)bh * 16384 + t;
  float l0 = lse_r[base], l1 = lse_r[base + 4096], l2 = lse_r[base + 8192], l3 = lse_r[base + 12288];
  float M = fmaxf(fmaxf(l0, l1), fmaxf(l2, l3));
  float e0 = __expf(fmaxf(fminf(l0 - M, 0.f), -80.f));
  float e1 = __expf(fmaxf(fminf(l1 - M, 0.f), -80.f));
  float e2 = __expf(fmaxf(fminf(l2 - M, 0.f), -80.f));
  float e3 = __expf(fmaxf(fminf(l3 - M, 0.f), -80.f));
  float inv = 1.f / (e0 + e1 + e2 + e3);
  float o = e0 * bu2f(o_r[(base         )*128 + d]) + e1 * bu2f(o_r[(base +  4096)*128 + d])
          + e2 * bu2f(o_r[(base +  8192)*128 + d]) + e3 * bu2f(o_r[(base + 12288)*128 + d]);
  attnbf[((size_t)b * kT + t) * kDim + hh*128 + d] = f2bu(o * inv);
}

extern "C" void kernel_launch(void* const* d_in, const int* in_sizes, int n_in,
                              void* d_out, int out_size, void* d_ws, size_t ws_size,
                              hipStream_t stream) {
  (void)in_sizes; (void)n_in; (void)out_size; (void)ws_size;
  const void* x     = d_in[0];
  const void* ln1_g = d_in[1];
  const void* ln1_b = d_in[2];
  const void* Wqk   = d_in[3];
  const void* Wv    = d_in[4];
  const void* Wo    = d_in[5];
  const void* bo    = d_in[6];
  const void* ln2_g = d_in[7];
  const void* ln2_b = d_in[8];
  const void* W1    = d_in[9];
  const void* b1    = d_in[10];
  const void* W2    = d_in[11];
  const void* b2    = d_in[12];
  const void* rot   = d_in[13];

  char* w = (char*)d_ws;
  int*    flag = (int*)w;    w += 256;
  ushort* prm  = (ushort*)w; w += 131072;
  float* x1  = (float*)w;  w += 33554432;
  float* x2  = (float*)w;  w += 33554432;
  ushort* qkh = (ushort*)w; w += 16777216;
  ushort* qkl = (ushort*)w; w += 16777216;
  ushort* vbb = (ushort*)w; w += 16777216;
  ushort* xbf = (ushort*)w; w += 16777216;
  ushort* orb = (ushort*)w; w += 67108864;
  float* lse = (float*)w;  w += 1048576;
  int*   bkt = (int*)w;    w += 1048576;
  int*   stb = (int*)w;    w += 1048576;
  ushort* wtA = (ushort*)w; w += 2097152;
  ushort* wtB = (ushort*)w; w += 2097152;
  ushort* wtC = (ushort*)w; w += 2097152;
  ushort* wt1 = (ushort*)w; w += 8388608;
  ushort* wt2 = (ushort*)w; w += 8388608;
  ushort* rtT = (ushort*)w; w += 32768;

  ushort* pLN1G = prm + 0;     ushort* pLN1B = prm + 2048;
  ushort* pBO   = prm + 4096;  ushort* pLN2G = prm + 6144;
  ushort* pLN2B = prm + 8192;  ushort* pB1   = prm + 10240;
  ushort* pB2   = prm + 18432; ushort* pROT  = prm + 20480;

  k_detect<<<1, 256, 0, stream>>>((const unsigned*)x, flag);
  k_cvt<<<8,   256, 0, stream>>>(flag, ln1_g, pLN1G, 2048);
  k_cvt<<<8,   256, 0, stream>>>(flag, ln1_b, pLN1B, 2048);
  k_cvt<<<8,   256, 0, stream>>>(flag, bo,    pBO,   2048);
  k_cvt<<<8,   256, 0, stream>>>(flag, ln2_g, pLN2G, 2048);
  k_cvt<<<8,   256, 0, stream>>>(flag, ln2_b, pLN2B, 2048);
  k_cvt<<<32,  256, 0, stream>>>(flag, b1,    pB1,   8192);
  k_cvt<<<8,   256, 0, stream>>>(flag, b2,    pB2,   2048);
  k_cvt<<<128, 256, 0, stream>>>(flag, rot,   pROT,  32768);
  k_init_any<<<8192, 256, 0, stream>>>(flag, x, x1, x2);

  for (int d = 0; d < 2; d++) {
    k_transpose2<<<dim3(32, 32),  256, 0, stream>>>(flag,
        (const char*)Wqk + (size_t)d*1048576*2, (const char*)Wqk + (size_t)d*1048576*4, wtA, 1024, 1024);
    k_transpose2<<<dim3(32, 32),  256, 0, stream>>>(flag,
        (const char*)Wv  + (size_t)d*1048576*2, (const char*)Wv  + (size_t)d*1048576*4, wtB, 1024, 1024);
    k_transpose2<<<dim3(32, 32),  256, 0, stream>>>(flag,
        (const char*)Wo  + (size_t)d*1048576*2, (const char*)Wo  + (size_t)d*1048576*4, wtC, 1024, 1024);
    k_transpose2<<<dim3(128, 32), 256, 0, stream>>>(flag,
        (const char*)W1  + (size_t)d*4194304*2, (const char*)W1  + (size_t)d*4194304*4, wt1, 1024, 4096);
    k_transpose2<<<dim3(32, 128), 256, 0, stream>>>(flag,
        (const char*)W2  + (size_t)d*4194304*2, (const char*)W2  + (size_t)d*4194304*4, wt2, 4096, 1024);
    k_rot_t<<<1, 256, 0, stream>>>(pROT + (size_t)d * 16384, rtT);

    k_ln<<<8192, 256, 0, stream>>>(x2, pLN1G + d*1024, pLN1B + d*1024, xbf);
    k_gemm6<<<dim3(8, 64), 256, 0, stream>>>(xbf, wtA, nullptr, nullptr, qkh, qkl, 8192, 1024, 1024, 5);
    k_gemm6<<<dim3(8, 64), 256, 0, stream>>>(xbf, wtB, nullptr, nullptr, vbb, nullptr, 8192, 1024, 1024, 3);
    k_bucket_mfma<<<dim3(64, 16), 256, 0, stream>>>(qkh, qkl, rtT, bkt);
    k_sort<<<64, 256, 0, stream>>>(bkt, stb);
    k_attn<<<4096, 256, 0, stream>>>(qkh, vbb, stb, orb, lse);
    k_combine<<<32768, 256, 0, stream>>>(orb, lse, xbf);
    k_gemm6<<<dim3(8, 64), 256, 0, stream>>>(xbf, wtC, pBO + d*1024, x1, nullptr, nullptr, 8192, 1024, 1024, 1);
    k_ln<<<8192, 256, 0, stream>>>(x1, pLN2G + d*1024, pLN2B + d*1024, xbf);
    k_gemm6<<<dim3(32, 64), 256, 0, stream>>>(xbf, wt1, pB1 + d*4096, nullptr, orb, nullptr, 8192, 4096, 1024, 2);
    k_gemm6<<<dim3(8, 64), 256, 0, stream>>>(orb, wt2, pB2 + d*1024, x2, nullptr, nullptr, 8192, 1024, 4096, 1);
  }
  k_final_any<<<8192, 256, 0, stream>>>(flag, x1, x2, d_out);
}